// Round 3
// baseline (1895.960 us; speedup 1.0000x reference)
//
#include <hip/hip_runtime.h>
#include <hip/hip_bf16.h>
#include <math.h>

typedef __hip_bfloat16 bf16;

#define NB 16
#define NC 256
#define NHW 1024
#define NG 32
#define CPG 8
#define NNE 256
#define NP (NB*NC*NHW)

__device__ __forceinline__ float b2f(bf16 v){ return __bfloat162float(v); }
__device__ __forceinline__ float u2f(unsigned short u){ return __uint_as_float(((unsigned)u)<<16); }

// ---------------- GroupNorm (+optional Swish), fp32 in/out ----------------
template<bool SWISH>
__global__ void gn_kernel(const float* __restrict__ src, const float* __restrict__ gamma,
                          const float* __restrict__ beta, float* __restrict__ dst){
  int b = blockIdx.x >> 5, g = blockIdx.x & 31;
  const int GSZ = CPG*NHW;
  size_t base = ((size_t)b*NC + g*CPG)*NHW;
  int tid = threadIdx.x;
  float s = 0.f, ss = 0.f;
  for (int i = tid; i < GSZ; i += 256){
    float v = src[base+i];
    s += v; ss += v*v;
  }
  __shared__ float rs[256], rq[256];
  rs[tid] = s; rq[tid] = ss;
  __syncthreads();
  for (int off=128; off>0; off>>=1){
    if (tid < off){ rs[tid]+=rs[tid+off]; rq[tid]+=rq[tid+off]; }
    __syncthreads();
  }
  float mean = rs[0] * (1.f/GSZ);
  float var  = rq[0] * (1.f/GSZ) - mean*mean;
  float inv  = rsqrtf(var + 1e-5f);
  for (int i = tid; i < GSZ; i += 256){
    int ch = g*CPG + (i>>10);
    float v = (src[base+i] - mean)*inv*gamma[ch] + beta[ch];
    if (SWISH) v = v / (1.f + __expf(-v));
    dst[base+i] = v;
  }
}

// ---------------- FeatureWiseAffine bias: na[b][c] ----------------
__global__ void noise_kernel(const float* __restrict__ emb, const float* __restrict__ w,
                             const float* __restrict__ bias, float* __restrict__ na){
  int b = blockIdx.x, c = threadIdx.x;
  __shared__ float e[NNE];
  e[c] = emb[b*NNE + c];
  __syncthreads();
  float acc = bias[c];
  for (int k=0;k<NNE;k++) acc += e[k]*w[c*NNE+k];
  na[b*NC + c] = acc;
}

// ---------------- conv3x3 SAME, block = (b, 4 out-channels) ----------------
__global__ __launch_bounds__(256)
void conv3_kernel(const float* __restrict__ in, const float* __restrict__ wf,
                  const float* __restrict__ bias, const float* __restrict__ bias_bc,
                  const float* __restrict__ addf, float* __restrict__ out){
  int b = blockIdx.y, co0 = blockIdx.x*4, tid = threadIdx.x;
  int xs = (tid&7)*4, y = tid>>3;
  __shared__ float pl[32*33];
  float acc[4][4] = {{0.f}};
  for (int ci=0; ci<NC; ++ci){
    __syncthreads();
    size_t ib = ((size_t)b*NC + ci)*NHW;
    #pragma unroll
    for (int k2=0;k2<4;k2++){
      int i = tid + k2*256;
      pl[(i>>5)*33 + (i&31)] = in[ib + i];
    }
    __syncthreads();
    float wr[4][9];
    const float* wp = wf + ((size_t)co0*NC + ci)*9;
    #pragma unroll
    for (int co=0;co<4;co++)
      #pragma unroll
      for (int t=0;t<9;t++) wr[co][t] = wp[(size_t)co*NC*9 + t];
    float row[3][6];
    #pragma unroll
    for (int dy=0;dy<3;dy++){
      int yy = y+dy-1;
      bool rv = ((unsigned)yy < 32u);
      #pragma unroll
      for (int j=0;j<6;j++){
        int xx = xs-1+j;
        row[dy][j] = (rv && ((unsigned)xx < 32u)) ? pl[yy*33+xx] : 0.f;
      }
    }
    #pragma unroll
    for (int co=0;co<4;co++)
      #pragma unroll
      for (int p=0;p<4;p++){
        float sacc = 0.f;
        #pragma unroll
        for (int dy=0;dy<3;dy++)
          #pragma unroll
          for (int dx=0;dx<3;dx++)
            sacc += row[dy][p+dx]*wr[co][dy*3+dx];
        acc[co][p] += sacc;
      }
  }
  int pxb = y*32 + xs;
  #pragma unroll
  for (int co=0;co<4;co++){
    float bb = bias[co0+co] + (bias_bc ? bias_bc[b*NC + co0+co] : 0.f);
    size_t ob = ((size_t)b*NC + co0+co)*NHW + pxb;
    #pragma unroll
    for (int p=0;p<4;p++){
      float v = acc[co][p] + bb;
      if (addf) v += addf[ob+p];
      out[ob+p] = v;
    }
  }
}

// ---------------- conv1x1, block = (b, 4 out-channels) ----------------
template<typename OutT>
__global__ __launch_bounds__(256)
void conv1x1_kernel(const float* __restrict__ in, const float* __restrict__ wf,
                    const float* __restrict__ bias, const float* __restrict__ addb,
                    OutT* __restrict__ out, int Cout){
  int b = blockIdx.y, co0 = blockIdx.x*4, tid = threadIdx.x;
  float acc[4][4] = {{0.f}};
  size_t inb = (size_t)b*NC*NHW;
  for (int ci=0; ci<NC; ++ci){
    float v[4];
    const float* ip = in + inb + (size_t)ci*NHW + tid;
    #pragma unroll
    for (int p=0;p<4;p++) v[p] = ip[p*256];
    #pragma unroll
    for (int co=0;co<4;co++){
      float wv = wf[(size_t)(co0+co)*NC + ci];
      #pragma unroll
      for (int p=0;p<4;p++) acc[co][p] += wv*v[p];
    }
  }
  #pragma unroll
  for (int co=0;co<4;co++){
    float bb = bias ? bias[co0+co] : 0.f;
    size_t ob = ((size_t)b*Cout + co0+co)*NHW + tid;
    #pragma unroll
    for (int p=0;p<4;p++){
      float v = acc[co][p] + bb;
      if (addb) v += addb[ob + p*256];
      out[ob + p*256] = (OutT)v;
    }
  }
}

// ---------------- fused attention: scores + softmax + PV ----------------
// qkv bf16 [b][3C][S]; output o_t fp32 [b][S][C] (transposed, coalesced stores)
__global__ __launch_bounds__(256)
void attn_kernel(const bf16* __restrict__ qkv, float* __restrict__ ot){
  int b = blockIdx.y, s0 = blockIdx.x*16, tid = threadIdx.x;
  const bf16* q = qkv + (size_t)b*3*NC*NHW;
  const bf16* k = q + (size_t)NC*NHW;
  const unsigned short* vus = (const unsigned short*)(k + (size_t)NC*NHW);
  __shared__ float ql[NC*16];             // 16 KB
  __shared__ unsigned short As[16][1024]; // 32 KB (attn rows, bf16)
  __shared__ float red[4];
  for (int i=tid;i<NC*16;i+=256){
    int cc = i>>4, r = i&15;
    ql[i] = b2f(q[(size_t)cc*NHW + s0 + r]);
  }
  __syncthreads();
  float acc[16][4] = {{0.f}};
  for (int cc=0;cc<NC;cc++){
    float kv[4];
    const bf16* kr = k + (size_t)cc*NHW + tid;
    #pragma unroll
    for (int p=0;p<4;p++) kv[p] = b2f(kr[p*256]);
    const float* qc = &ql[cc*16];
    #pragma unroll
    for (int r=0;r<16;r++){
      float qv = qc[r];
      #pragma unroll
      for (int p=0;p<4;p++) acc[r][p] += qv*kv[p];
    }
  }
  const float scale = 0.0625f;  // 1/sqrt(256)
  for (int r=0;r<16;r++){
    float lm = -1e30f;
    #pragma unroll
    for (int p=0;p<4;p++){ acc[r][p] *= scale; lm = fmaxf(lm, acc[r][p]); }
    #pragma unroll
    for (int o=1;o<64;o<<=1) lm = fmaxf(lm, __shfl_xor(lm, o, 64));
    if ((tid&63)==0) red[tid>>6] = lm;
    __syncthreads();
    float m = fmaxf(fmaxf(red[0],red[1]), fmaxf(red[2],red[3]));
    __syncthreads();
    float e[4]; float ls = 0.f;
    #pragma unroll
    for (int p=0;p<4;p++){ e[p] = __expf(acc[r][p]-m); ls += e[p]; }
    #pragma unroll
    for (int o=1;o<64;o<<=1) ls += __shfl_xor(ls, o, 64);
    if ((tid&63)==0) red[tid>>6] = ls;
    __syncthreads();
    float inv = 1.f/(red[0]+red[1]+red[2]+red[3]);
    #pragma unroll
    for (int p=0;p<4;p++){
      bf16 hv = (bf16)(e[p]*inv);
      As[r][tid + p*256] = *(unsigned short*)&hv;
    }
    __syncthreads();
  }
  // phase 2: o[s0+r][c] = sum_t As[r][t] * v[c][t]
  int lane = tid & 63, sg = tid >> 6;      // c = lane*4+j, s-rows = sg*4+i
  float acc2[4][4] = {{0.f}};
  for (int t4=0; t4<NHW; t4+=4){
    float a[4][4];
    #pragma unroll
    for (int i=0;i<4;i++){
      uint2 ra = *(const uint2*)&As[sg*4+i][t4];
      a[i][0]=u2f((unsigned short)(ra.x&0xffff)); a[i][1]=u2f((unsigned short)(ra.x>>16));
      a[i][2]=u2f((unsigned short)(ra.y&0xffff)); a[i][3]=u2f((unsigned short)(ra.y>>16));
    }
    float vv[4][4];
    #pragma unroll
    for (int j=0;j<4;j++){
      uint2 rv = *(const uint2*)(vus + (size_t)(lane*4+j)*NHW + t4);
      vv[j][0]=u2f((unsigned short)(rv.x&0xffff)); vv[j][1]=u2f((unsigned short)(rv.x>>16));
      vv[j][2]=u2f((unsigned short)(rv.y&0xffff)); vv[j][3]=u2f((unsigned short)(rv.y>>16));
    }
    #pragma unroll
    for (int i=0;i<4;i++)
      #pragma unroll
      for (int j=0;j<4;j++)
        #pragma unroll
        for (int tt=0;tt<4;tt++) acc2[i][j] += a[i][tt]*vv[j][tt];
  }
  #pragma unroll
  for (int i=0;i<4;i++){
    float* op = ot + ((size_t)b*NHW + s0 + sg*4+i)*NC + lane*4;
    float4 st; st.x=acc2[i][0]; st.y=acc2[i][1]; st.z=acc2[i][2]; st.w=acc2[i][3];
    *(float4*)op = st;
  }
}

// ---------------- out-proj: out[b][co][s] = W @ o_t^T + out_b + h ----------------
__global__ __launch_bounds__(256)
void outproj_kernel(const float* __restrict__ ot, const float* __restrict__ wo,
                    const float* __restrict__ obias, const float* __restrict__ h,
                    float* __restrict__ out){
  int b = blockIdx.z, c0 = blockIdx.y*64, s0 = blockIdx.x*64;
  __shared__ float Ws[64][17], Os[64][17];
  int tid = threadIdx.x, tx = tid&15, ty = tid>>4;
  float acc[4][4] = {{0.f}};
  const float* otb = ot + (size_t)b*NHW*NC;
  for (int t0=0;t0<NC;t0+=16){
    for (int i=tid;i<1024;i+=256){
      int row=i>>4, col=i&15;
      Ws[row][col] = wo[(size_t)(c0+row)*NC + t0+col];
      Os[row][col] = otb[(size_t)(s0+row)*NC + t0+col];
    }
    __syncthreads();
    #pragma unroll
    for (int kk=0;kk<16;kk++){
      float wv[4], av[4];
      #pragma unroll
      for (int i=0;i<4;i++){ wv[i]=Ws[ty*4+i][kk]; av[i]=Os[tx*4+i][kk]; }
      #pragma unroll
      for (int i=0;i<4;i++)
        #pragma unroll
        for (int j=0;j<4;j++) acc[i][j] += wv[i]*av[j];
    }
    __syncthreads();
  }
  #pragma unroll
  for (int i=0;i<4;i++){
    int c = c0 + ty*4 + i;
    float bb = obias[c];
    size_t base = ((size_t)b*NC + c)*NHW + s0 + tx*4;
    #pragma unroll
    for (int j=0;j<4;j++) out[base+j] = acc[i][j] + bb + h[base+j];
  }
}

extern "C" void kernel_launch(void* const* d_in, const int* in_sizes, int n_in,
                              void* d_out, int out_size, void* d_ws, size_t ws_size,
                              hipStream_t stream){
  const float* x        = (const float*)d_in[0];
  const float* time_emb = (const float*)d_in[1];
  const float* c_in     = (const float*)d_in[2];
  const float* gn1_g    = (const float*)d_in[3];
  const float* gn1_b    = (const float*)d_in[4];
  const float* conv1_w  = (const float*)d_in[5];
  const float* conv1_b  = (const float*)d_in[6];
  const float* noise_w  = (const float*)d_in[7];
  const float* noise_b  = (const float*)d_in[8];
  const float* gn2_g    = (const float*)d_in[9];
  const float* gn2_b    = (const float*)d_in[10];
  const float* conv2_w  = (const float*)d_in[11];
  const float* conv2_b  = (const float*)d_in[12];
  const float* cfunc_w  = (const float*)d_in[13];
  const float* cfunc_b  = (const float*)d_in[14];
  const float* agn_g    = (const float*)d_in[15];
  const float* agn_b    = (const float*)d_in[16];
  const float* qkv_w    = (const float*)d_in[17];
  const float* out_w    = (const float*)d_in[18];
  const float* out_b    = (const float*)d_in[19];
  float* outp = (float*)d_out;

  // ---- workspace layout (~59 MB) ----
  float* ws = (float*)d_ws;
  float* buf_h   = ws;                         // NP fp32
  float* buf_t   = buf_h + NP;                 // NP fp32 (gn out; later o_t)
  bf16*  buf_qkv = (bf16*)(buf_t + NP);        // 3*NP bf16
  float* buf_na  = (float*)(buf_qkv + (size_t)3*NP); // NB*NC fp32

  // ---- ResnetBlock ----
  gn_kernel<true><<<NB*NG, 256, 0, stream>>>(x, gn1_g, gn1_b, buf_t);
  noise_kernel<<<NB, 256, 0, stream>>>(time_emb, noise_w, noise_b, buf_na);
  conv3_kernel<<<dim3(NC/4, NB), 256, 0, stream>>>(buf_t, conv1_w, conv1_b, buf_na, nullptr, buf_h);
  gn_kernel<true><<<NB*NG, 256, 0, stream>>>(buf_h, gn2_g, gn2_b, buf_t);
  // buf_h <- conv1x1(c) + cfunc_b + x
  conv1x1_kernel<float><<<dim3(NC/4, NB), 256, 0, stream>>>(
      c_in, cfunc_w, cfunc_b, x, buf_h, NC);
  // buf_h += conv3(swish(gn2))
  conv3_kernel<<<dim3(NC/4, NB), 256, 0, stream>>>(buf_t, conv2_w, conv2_b, nullptr, buf_h, buf_h);
  // ---- Attention ----
  gn_kernel<false><<<NB*NG, 256, 0, stream>>>(buf_h, agn_g, agn_b, buf_t);
  conv1x1_kernel<bf16><<<dim3(3*NC/4, NB), 256, 0, stream>>>(
      buf_t, qkv_w, nullptr, nullptr, buf_qkv, 3*NC);
  attn_kernel<<<dim3(NHW/16, NB), 256, 0, stream>>>(buf_qkv, buf_t);
  outproj_kernel<<<dim3(NHW/64, NC/64, NB), 256, 0, stream>>>(buf_t, out_w, out_b, buf_h, outp);
}

// Round 4
// 1152.497 us; speedup vs baseline: 1.6451x; 1.6451x over previous
//
#include <hip/hip_runtime.h>
#include <hip/hip_bf16.h>
#include <math.h>

typedef __hip_bfloat16 bf16;
typedef short short8 __attribute__((ext_vector_type(8)));
typedef float floatx4 __attribute__((ext_vector_type(4)));

#define NB 16
#define NC 256
#define NHW 1024
#define NG 32
#define CPG 8
#define NNE 256
#define NP (NB*NC*NHW)

__device__ __forceinline__ unsigned short f2bu(float f){
  bf16 h = (bf16)f; return *(unsigned short*)&h;
}

// ---------------- GroupNorm (+optional Swish), fp32 in/out ----------------
template<bool SWISH>
__global__ void gn_kernel(const float* __restrict__ src, const float* __restrict__ gamma,
                          const float* __restrict__ beta, float* __restrict__ dst){
  int b = blockIdx.x >> 5, g = blockIdx.x & 31;
  const int GSZ = CPG*NHW;
  size_t base = ((size_t)b*NC + g*CPG)*NHW;
  int tid = threadIdx.x;
  float s = 0.f, ss = 0.f;
  for (int i = tid; i < GSZ; i += 256){
    float v = src[base+i];
    s += v; ss += v*v;
  }
  __shared__ float rs[256], rq[256];
  rs[tid] = s; rq[tid] = ss;
  __syncthreads();
  for (int off=128; off>0; off>>=1){
    if (tid < off){ rs[tid]+=rs[tid+off]; rq[tid]+=rq[tid+off]; }
    __syncthreads();
  }
  float mean = rs[0] * (1.f/GSZ);
  float var  = rq[0] * (1.f/GSZ) - mean*mean;
  float inv  = rsqrtf(var + 1e-5f);
  for (int i = tid; i < GSZ; i += 256){
    int ch = g*CPG + (i>>10);
    float v = (src[base+i] - mean)*inv*gamma[ch] + beta[ch];
    if (SWISH) v = v / (1.f + __expf(-v));
    dst[base+i] = v;
  }
}

// ---------------- FeatureWiseAffine bias: na[b][c] ----------------
__global__ void noise_kernel(const float* __restrict__ emb, const float* __restrict__ w,
                             const float* __restrict__ bias, float* __restrict__ na){
  int b = blockIdx.x, c = threadIdx.x;
  __shared__ float e[NNE];
  e[c] = emb[b*NNE + c];
  __syncthreads();
  float acc = bias[c];
  for (int k=0;k<NNE;k++) acc += e[k]*w[c*NNE+k];
  na[b*NC + c] = acc;
}

// ---------------- conv3x3 SAME, block = (b, 4 out-channels) ----------------
__global__ __launch_bounds__(256)
void conv3_kernel(const float* __restrict__ in, const float* __restrict__ wf,
                  const float* __restrict__ bias, const float* __restrict__ bias_bc,
                  const float* __restrict__ addf, float* __restrict__ out){
  int b = blockIdx.y, co0 = blockIdx.x*4, tid = threadIdx.x;
  int xs = (tid&7)*4, y = tid>>3;
  __shared__ float pl[32*33];
  float acc[4][4] = {{0.f}};
  for (int ci=0; ci<NC; ++ci){
    __syncthreads();
    size_t ib = ((size_t)b*NC + ci)*NHW;
    #pragma unroll
    for (int k2=0;k2<4;k2++){
      int i = tid + k2*256;
      pl[(i>>5)*33 + (i&31)] = in[ib + i];
    }
    __syncthreads();
    float wr[4][9];
    const float* wp = wf + ((size_t)co0*NC + ci)*9;
    #pragma unroll
    for (int co=0;co<4;co++)
      #pragma unroll
      for (int t=0;t<9;t++) wr[co][t] = wp[(size_t)co*NC*9 + t];
    float row[3][6];
    #pragma unroll
    for (int dy=0;dy<3;dy++){
      int yy = y+dy-1;
      bool rv = ((unsigned)yy < 32u);
      #pragma unroll
      for (int j=0;j<6;j++){
        int xx = xs-1+j;
        row[dy][j] = (rv && ((unsigned)xx < 32u)) ? pl[yy*33+xx] : 0.f;
      }
    }
    #pragma unroll
    for (int co=0;co<4;co++)
      #pragma unroll
      for (int p=0;p<4;p++){
        float sacc = 0.f;
        #pragma unroll
        for (int dy=0;dy<3;dy++)
          #pragma unroll
          for (int dx=0;dx<3;dx++)
            sacc += row[dy][p+dx]*wr[co][dy*3+dx];
        acc[co][p] += sacc;
      }
  }
  int pxb = y*32 + xs;
  #pragma unroll
  for (int co=0;co<4;co++){
    float bb = bias[co0+co] + (bias_bc ? bias_bc[b*NC + co0+co] : 0.f);
    size_t ob = ((size_t)b*NC + co0+co)*NHW + pxb;
    #pragma unroll
    for (int p=0;p<4;p++){
      float v = acc[co][p] + bb;
      if (addf) v += addf[ob+p];
      out[ob+p] = v;
    }
  }
}

// ---------------- conv1x1 fp32 (cfunc path) ----------------
__global__ __launch_bounds__(256)
void conv1x1_kernel(const float* __restrict__ in, const float* __restrict__ wf,
                    const float* __restrict__ bias, const float* __restrict__ addb,
                    float* __restrict__ out){
  int b = blockIdx.y, co0 = blockIdx.x*4, tid = threadIdx.x;
  float acc[4][4] = {{0.f}};
  size_t inb = (size_t)b*NC*NHW;
  for (int ci=0; ci<NC; ++ci){
    float v[4];
    const float* ip = in + inb + (size_t)ci*NHW + tid;
    #pragma unroll
    for (int p=0;p<4;p++) v[p] = ip[p*256];
    #pragma unroll
    for (int co=0;co<4;co++){
      float wv = wf[(size_t)(co0+co)*NC + ci];
      #pragma unroll
      for (int p=0;p<4;p++) acc[co][p] += wv*v[p];
    }
  }
  #pragma unroll
  for (int co=0;co<4;co++){
    float bb = bias ? bias[co0+co] : 0.f;
    size_t ob = ((size_t)b*NC + co0+co)*NHW + tid;
    #pragma unroll
    for (int p=0;p<4;p++){
      float v = acc[co][p] + bb;
      if (addb) v += addb[ob + p*256];
      out[ob + p*256] = v;
    }
  }
}

// ---------------- qkv conv1x1: writes q_t[s][c], k_t[t][c], v[c][t] (bf16) ----------------
__global__ __launch_bounds__(256)
void qkv_kernel(const float* __restrict__ in, const float* __restrict__ wf,
                short* __restrict__ qt, short* __restrict__ kt, short* __restrict__ vt){
  int b = blockIdx.y, co0 = blockIdx.x*4, tid = threadIdx.x;
  float acc[4][4] = {{0.f}};
  size_t inb = (size_t)b*NC*NHW;
  for (int ci=0; ci<NC; ++ci){
    float v[4];
    const float* ip = in + inb + (size_t)ci*NHW + tid;
    #pragma unroll
    for (int p=0;p<4;p++) v[p] = ip[p*256];
    #pragma unroll
    for (int co=0;co<4;co++){
      float wv = wf[(size_t)(co0+co)*NC + ci];
      #pragma unroll
      for (int p=0;p<4;p++) acc[co][p] += wv*v[p];
    }
  }
  int sec = co0 >> 8;         // 0=q, 1=k, 2=v
  int cc  = co0 & 255;
  if (sec < 2){
    short* dst = (sec==0) ? qt : kt;
    #pragma unroll
    for (int p=0;p<4;p++){
      int s = tid + p*256;
      unsigned short t0 = f2bu(acc[0][p]), t1 = f2bu(acc[1][p]);
      unsigned short t2 = f2bu(acc[2][p]), t3 = f2bu(acc[3][p]);
      uint2 w; w.x = ((unsigned)t1<<16)|t0; w.y = ((unsigned)t3<<16)|t2;
      *(uint2*)(dst + ((size_t)b*NHW + s)*NC + cc) = w;
    }
  } else {
    #pragma unroll
    for (int co=0;co<4;co++){
      size_t ob = ((size_t)b*NC + cc+co)*NHW + tid;
      #pragma unroll
      for (int p=0;p<4;p++)
        vt[ob + p*256] = (short)f2bu(acc[co][p]);
    }
  }
}

// ---------------- MFMA fused attention ----------------
// q_t[b][s][c], k_t[b][t][c], v[b][c][t] bf16; out o_t[b][s][c] fp32.
// block = (16 s-rows, b); wave w: scores cols [w*256,w*256+256), PV cols c in [w*64,w*64+64)
__global__ __launch_bounds__(256)
void attn_mfma_kernel(const short* __restrict__ qt, const short* __restrict__ kt,
                      const short* __restrict__ vv, float* __restrict__ ot){
  const int b = blockIdx.y, s0 = blockIdx.x*16;
  const int tid = threadIdx.x, wave = tid>>6, lane = tid&63;
  const int quad = lane>>4, lm = lane&15;
  __shared__ short P[16][1032];          // padded: stride 2064B -> b128 reads 2-way max
  __shared__ float redmax[16][4], redsum[16][4];

  // Q A-frags for full K=256 (8 k-steps), kept in registers
  short8 aq[8];
  const short* qrow = qt + ((size_t)b*NHW + s0 + lm)*NC + quad*8;
  #pragma unroll
  for (int kk=0;kk<8;kk++) aq[kk] = *(const short8*)(qrow + kk*32);

  // ---- phase 1: scores (this wave's 256-col span) ----
  floatx4 sc[16];
  #pragma unroll
  for (int ti=0;ti<16;ti++) sc[ti] = (floatx4){0.f,0.f,0.f,0.f};
  const short* kbase = kt + ((size_t)b*NHW + wave*256 + lm)*NC + quad*8;
  for (int ti=0;ti<16;ti++){
    const short* kr = kbase + (size_t)ti*16*NC;
    #pragma unroll
    for (int kk=0;kk<8;kk++){
      short8 bv = *(const short8*)(kr + kk*32);
      sc[ti] = __builtin_amdgcn_mfma_f32_16x16x32_bf16(aq[kk], bv, sc[ti], 0,0,0);
    }
  }
  const float scale = 0.0625f;  // 1/sqrt(256)
  float mx[4] = {-1e30f,-1e30f,-1e30f,-1e30f};
  #pragma unroll
  for (int ti=0;ti<16;ti++)
    #pragma unroll
    for (int r=0;r<4;r++){
      float v = sc[ti][r]*scale;
      sc[ti][r] = v;
      mx[r] = fmaxf(mx[r], v);
    }
  #pragma unroll
  for (int o=1;o<16;o<<=1)
    #pragma unroll
    for (int r=0;r<4;r++) mx[r] = fmaxf(mx[r], __shfl_xor(mx[r], o, 64));
  if (lm==0){
    #pragma unroll
    for (int r=0;r<4;r++) redmax[quad*4+r][wave] = mx[r];
  }
  __syncthreads();
  float fm[4];
  #pragma unroll
  for (int r=0;r<4;r++){
    int row = quad*4+r;
    fm[r] = fmaxf(fmaxf(redmax[row][0],redmax[row][1]),
                  fmaxf(redmax[row][2],redmax[row][3]));
  }
  float sm[4] = {0.f,0.f,0.f,0.f};
  #pragma unroll
  for (int ti=0;ti<16;ti++)
    #pragma unroll
    for (int r=0;r<4;r++){
      float e = __expf(sc[ti][r] - fm[r]);
      sc[ti][r] = e;
      sm[r] += e;
    }
  #pragma unroll
  for (int o=1;o<16;o<<=1)
    #pragma unroll
    for (int r=0;r<4;r++) sm[r] += __shfl_xor(sm[r], o, 64);
  if (lm==0){
    #pragma unroll
    for (int r=0;r<4;r++) redsum[quad*4+r][wave] = sm[r];
  }
  __syncthreads();
  float inv[4];
  #pragma unroll
  for (int r=0;r<4;r++){
    int row = quad*4+r;
    inv[r] = 1.f/(redsum[row][0]+redsum[row][1]+redsum[row][2]+redsum[row][3]);
  }
  #pragma unroll
  for (int ti=0;ti<16;ti++)
    #pragma unroll
    for (int r=0;r<4;r++)
      P[quad*4+r][wave*256 + ti*16 + lm] = (short)f2bu(sc[ti][r]*inv[r]);
  __syncthreads();

  // ---- phase 2: o[s][c] = P @ V^T over full t ----
  floatx4 oacc[4];
  #pragma unroll
  for (int nt=0;nt<4;nt++) oacc[nt] = (floatx4){0.f,0.f,0.f,0.f};
  const short* vbase = vv + ((size_t)b*NC + wave*64 + lm)*NHW + quad*8;
  for (int kk=0;kk<32;kk++){
    short8 av = *(const short8*)(&P[lm][kk*32 + quad*8]);
    #pragma unroll
    for (int nt=0;nt<4;nt++){
      short8 bvv = *(const short8*)(vbase + (size_t)nt*16*NHW + kk*32);
      oacc[nt] = __builtin_amdgcn_mfma_f32_16x16x32_bf16(av, bvv, oacc[nt], 0,0,0);
    }
  }
  #pragma unroll
  for (int nt=0;nt<4;nt++){
    int c = wave*64 + nt*16 + lm;
    #pragma unroll
    for (int r=0;r<4;r++){
      int s = s0 + quad*4 + r;
      ot[((size_t)b*NHW + s)*NC + c] = oacc[nt][r];
    }
  }
}

// ---------------- out-proj: out[b][co][s] = W @ o_t^T + out_b + h ----------------
__global__ __launch_bounds__(256)
void outproj_kernel(const float* __restrict__ ot, const float* __restrict__ wo,
                    const float* __restrict__ obias, const float* __restrict__ h,
                    float* __restrict__ out){
  int b = blockIdx.z, c0 = blockIdx.y*64, s0 = blockIdx.x*64;
  __shared__ float Ws[64][17], Os[64][17];
  int tid = threadIdx.x, tx = tid&15, ty = tid>>4;
  float acc[4][4] = {{0.f}};
  const float* otb = ot + (size_t)b*NHW*NC;
  for (int t0=0;t0<NC;t0+=16){
    for (int i=tid;i<1024;i+=256){
      int row=i>>4, col=i&15;
      Ws[row][col] = wo[(size_t)(c0+row)*NC + t0+col];
      Os[row][col] = otb[(size_t)(s0+row)*NC + t0+col];
    }
    __syncthreads();
    #pragma unroll
    for (int kk=0;kk<16;kk++){
      float wv[4], av[4];
      #pragma unroll
      for (int i=0;i<4;i++){ wv[i]=Ws[ty*4+i][kk]; av[i]=Os[tx*4+i][kk]; }
      #pragma unroll
      for (int i=0;i<4;i++)
        #pragma unroll
        for (int j=0;j<4;j++) acc[i][j] += wv[i]*av[j];
    }
    __syncthreads();
  }
  #pragma unroll
  for (int i=0;i<4;i++){
    int c = c0 + ty*4 + i;
    float bb = obias[c];
    size_t base = ((size_t)b*NC + c)*NHW + s0 + tx*4;
    #pragma unroll
    for (int j=0;j<4;j++) out[base+j] = acc[i][j] + bb + h[base+j];
  }
}

extern "C" void kernel_launch(void* const* d_in, const int* in_sizes, int n_in,
                              void* d_out, int out_size, void* d_ws, size_t ws_size,
                              hipStream_t stream){
  const float* x        = (const float*)d_in[0];
  const float* time_emb = (const float*)d_in[1];
  const float* c_in     = (const float*)d_in[2];
  const float* gn1_g    = (const float*)d_in[3];
  const float* gn1_b    = (const float*)d_in[4];
  const float* conv1_w  = (const float*)d_in[5];
  const float* conv1_b  = (const float*)d_in[6];
  const float* noise_w  = (const float*)d_in[7];
  const float* noise_b  = (const float*)d_in[8];
  const float* gn2_g    = (const float*)d_in[9];
  const float* gn2_b    = (const float*)d_in[10];
  const float* conv2_w  = (const float*)d_in[11];
  const float* conv2_b  = (const float*)d_in[12];
  const float* cfunc_w  = (const float*)d_in[13];
  const float* cfunc_b  = (const float*)d_in[14];
  const float* agn_g    = (const float*)d_in[15];
  const float* agn_b    = (const float*)d_in[16];
  const float* qkv_w    = (const float*)d_in[17];
  const float* out_w    = (const float*)d_in[18];
  const float* out_b    = (const float*)d_in[19];
  float* outp = (float*)d_out;

  // ---- workspace layout (~59 MB, same total as round 3) ----
  float* ws = (float*)d_ws;
  float* buf_h = ws;                     // NP fp32
  float* buf_t = buf_h + NP;             // NP fp32 (gn out; later o_t[s][c])
  short* qt    = (short*)(buf_t + NP);   // NP bf16  q_t[s][c]
  short* ktb   = qt + NP;                // NP bf16  k_t[t][c]
  short* vtb   = ktb + NP;               // NP bf16  v[c][t]
  float* buf_na = (float*)(vtb + NP);    // NB*NC fp32

  // ---- ResnetBlock ----
  gn_kernel<true><<<NB*NG, 256, 0, stream>>>(x, gn1_g, gn1_b, buf_t);
  noise_kernel<<<NB, 256, 0, stream>>>(time_emb, noise_w, noise_b, buf_na);
  conv3_kernel<<<dim3(NC/4, NB), 256, 0, stream>>>(buf_t, conv1_w, conv1_b, buf_na, nullptr, buf_h);
  gn_kernel<true><<<NB*NG, 256, 0, stream>>>(buf_h, gn2_g, gn2_b, buf_t);
  conv1x1_kernel<<<dim3(NC/4, NB), 256, 0, stream>>>(c_in, cfunc_w, cfunc_b, x, buf_h);
  conv3_kernel<<<dim3(NC/4, NB), 256, 0, stream>>>(buf_t, conv2_w, conv2_b, nullptr, buf_h, buf_h);
  // ---- Attention ----
  gn_kernel<false><<<NB*NG, 256, 0, stream>>>(buf_h, agn_g, agn_b, buf_t);
  qkv_kernel<<<dim3(3*NC/4, NB), 256, 0, stream>>>(buf_t, qkv_w, qt, ktb, vtb);
  attn_mfma_kernel<<<dim3(NHW/16, NB), 256, 0, stream>>>(qt, ktb, vtb, buf_t);
  outproj_kernel<<<dim3(NHW/64, NC/64, NB), 256, 0, stream>>>(buf_t, out_w, out_b, buf_h, outp);
}

// Round 5
// 654.077 us; speedup vs baseline: 2.8987x; 1.7620x over previous
//
#include <hip/hip_runtime.h>
#include <hip/hip_bf16.h>
#include <math.h>

typedef __hip_bfloat16 bf16;
typedef short short8 __attribute__((ext_vector_type(8)));
typedef float floatx4 __attribute__((ext_vector_type(4)));

#define NB 16
#define NC 256
#define NHW 1024
#define NG 32
#define CPG 8
#define NNE 256
#define NP (NB*NC*NHW)

__device__ __forceinline__ unsigned short f2bu(float f){
  bf16 h = (bf16)f; return *(unsigned short*)&h;
}

// ---------------- GroupNorm+Swish -> transposed bf16 X_t[b][hw][ci] ----------------
__global__ void gn_t_kernel(const float* __restrict__ src, const float* __restrict__ gamma,
                            const float* __restrict__ beta, short* __restrict__ xt){
  int b = blockIdx.x >> 5, g = blockIdx.x & 31;
  const int GSZ = CPG*NHW;
  size_t base = ((size_t)b*NC + g*CPG)*NHW;
  int tid = threadIdx.x;
  float s = 0.f, ss = 0.f;
  for (int i = tid; i < GSZ; i += 256){
    float v = src[base+i];
    s += v; ss += v*v;
  }
  __shared__ float rs[256], rq[256];
  rs[tid] = s; rq[tid] = ss;
  __syncthreads();
  for (int off=128; off>0; off>>=1){
    if (tid < off){ rs[tid]+=rs[tid+off]; rq[tid]+=rq[tid+off]; }
    __syncthreads();
  }
  float mean = rs[0] * (1.f/GSZ);
  float var  = rq[0] * (1.f/GSZ) - mean*mean;
  float inv  = rsqrtf(var + 1e-5f);
  float gm[8], bt[8];
  #pragma unroll
  for (int j=0;j<8;j++){ gm[j] = gamma[g*8+j]*inv; bt[j] = beta[g*8+j]; }
  for (int px = tid; px < NHW; px += 256){
    short8 pk;
    #pragma unroll
    for (int j=0;j<8;j++){
      float v = (src[base + j*NHW + px] - mean)*gm[j] + bt[j];
      v = v / (1.f + __expf(-v));
      pk[j] = (short)f2bu(v);
    }
    *(short8*)&xt[((size_t)b*NHW + px)*NC + g*8] = pk;
  }
}

// ---------------- GroupNorm (no swish), fp32 out (attention path) ----------------
__global__ void gn_kernel(const float* __restrict__ src, const float* __restrict__ gamma,
                          const float* __restrict__ beta, float* __restrict__ dst){
  int b = blockIdx.x >> 5, g = blockIdx.x & 31;
  const int GSZ = CPG*NHW;
  size_t base = ((size_t)b*NC + g*CPG)*NHW;
  int tid = threadIdx.x;
  float s = 0.f, ss = 0.f;
  for (int i = tid; i < GSZ; i += 256){
    float v = src[base+i];
    s += v; ss += v*v;
  }
  __shared__ float rs[256], rq[256];
  rs[tid] = s; rq[tid] = ss;
  __syncthreads();
  for (int off=128; off>0; off>>=1){
    if (tid < off){ rs[tid]+=rs[tid+off]; rq[tid]+=rq[tid+off]; }
    __syncthreads();
  }
  float mean = rs[0] * (1.f/GSZ);
  float var  = rq[0] * (1.f/GSZ) - mean*mean;
  float inv  = rsqrtf(var + 1e-5f);
  for (int i = tid; i < GSZ; i += 256){
    int ch = g*CPG + (i>>10);
    dst[base+i] = (src[base+i] - mean)*inv*gamma[ch] + beta[ch];
  }
}

// ---------------- weight prep: OIHW fp32 -> W_t[tap][co][ci] bf16 (both convs) ----------------
__global__ void wprep_kernel(const float* __restrict__ w1, const float* __restrict__ w2,
                             short* __restrict__ wt1, short* __restrict__ wt2){
  int co = blockIdx.x & 255;
  const float* w = (blockIdx.x < 256) ? w1 : w2;
  short* wt = (blockIdx.x < 256) ? wt1 : wt2;
  int tid = threadIdx.x;
  __shared__ float tmp[2304];
  for (int i=tid;i<2304;i+=256) tmp[i] = w[(size_t)co*2304 + i];   // [ci][tap]
  __syncthreads();
  for (int i=tid;i<2304;i+=256){
    int tap = i>>8, ci = i&255;
    wt[((size_t)tap*NC + co)*NC + ci] = (short)f2bu(tmp[ci*9 + tap]);
  }
}

// ---------------- FeatureWiseAffine bias: na[b][c] ----------------
__global__ void noise_kernel(const float* __restrict__ emb, const float* __restrict__ w,
                             const float* __restrict__ bias, float* __restrict__ na){
  int b = blockIdx.x, c = threadIdx.x;
  __shared__ float e[NNE];
  e[c] = emb[b*NNE + c];
  __syncthreads();
  float acc = bias[c];
  for (int k=0;k<NNE;k++) acc += e[k]*w[c*NNE+k];
  na[b*NC + c] = acc;
}

// ---------------- MFMA conv3x3: X_t[b][hw][ci] bf16, W_t[tap][co][ci] bf16 -> fp32 [b][co][hw] ----------------
// block = (y-tile of 2 rows, b); 4 waves: wave w handles co [w*64, w*64+64), all 64 px.
#define XSTR 264                 // padded ci-stride (shorts): 2-way-free b128 reads
__global__ __launch_bounds__(256)
void conv3_mfma_kernel(const short* __restrict__ xt, const short* __restrict__ wt,
                       const float* __restrict__ bias, const float* __restrict__ bias_bc,
                       const float* __restrict__ addf, float* __restrict__ out){
  const int b = blockIdx.y, y0 = blockIdx.x*2;
  const int tid = threadIdx.x, wave = tid>>6, lane = tid&63;
  const int quad = lane>>4, lm = lane&15;
  __shared__ short Xs[4*34*XSTR];      // 4 rows x 34 px x 264 ci = 71808 B

  // zero halo columns (x-slot 0 and 33)
  {
    int r = tid>>6, side = (tid>>5)&1, ck = tid&31;
    short8 z = {0,0,0,0,0,0,0,0};
    *(short8*)&Xs[((r*34) + side*33)*XSTR + ck*8] = z;
  }
  // stage 4 rows (y0-1 .. y0+2), 32 px, 256 ci
  for (int idx = tid; idx < 4096; idx += 256){
    int r = idx>>10, rem = idx&1023, x = rem>>5, ck = rem&31;
    int y = y0 - 1 + r;
    short8 v = {0,0,0,0,0,0,0,0};
    if ((unsigned)y < 32u)
      v = *(const short8*)(xt + (((size_t)b*NHW + y*32 + x)*NC + ck*8));
    *(short8*)&Xs[(r*34 + x + 1)*XSTR + ck*8] = v;
  }
  __syncthreads();

  floatx4 acc[4][4];
  #pragma unroll
  for (int mt=0;mt<4;mt++)
    #pragma unroll
    for (int nt=0;nt<4;nt++) acc[mt][nt] = (floatx4){0.f,0.f,0.f,0.f};

  const int co_w = wave*64;
  for (int tap=0; tap<9; ++tap){
    const int dy = tap/3, dxp = tap - dy*3;     // LDS row offset dy, x-slot offset dxp
    const short* wtap = wt + ((size_t)tap*NC + co_w + lm)*NC + quad*8;
    const int bB = (lm + dxp)*XSTR + quad*8;
    #pragma unroll
    for (int kk=0;kk<8;kk++){
      short8 af[4];
      #pragma unroll
      for (int mt=0;mt<4;mt++) af[mt] = *(const short8*)(wtap + (size_t)mt*16*NC + kk*32);
      short8 bf[4];
      #pragma unroll
      for (int nt=0;nt<4;nt++){
        int addr = ((nt>>1)+dy)*(34*XSTR) + (nt&1)*(16*XSTR) + bB + kk*32;
        bf[nt] = *(const short8*)&Xs[addr];
      }
      #pragma unroll
      for (int mt=0;mt<4;mt++)
        #pragma unroll
        for (int nt=0;nt<4;nt++)
          acc[mt][nt] = __builtin_amdgcn_mfma_f32_16x16x32_bf16(af[mt], bf[nt], acc[mt][nt], 0,0,0);
    }
  }

  // epilogue: C col=lm -> px, row=quad*4+r -> co
  const int hw0 = blockIdx.x*64;
  #pragma unroll
  for (int mt=0;mt<4;mt++){
    #pragma unroll
    for (int r=0;r<4;r++){
      int co = co_w + mt*16 + quad*4 + r;
      float bb = bias[co] + (bias_bc ? bias_bc[b*NC + co] : 0.f);
      size_t ob = ((size_t)b*NC + co)*NHW + hw0;
      #pragma unroll
      for (int nt=0;nt<4;nt++){
        size_t oi = ob + nt*16 + lm;
        float v = acc[mt][nt][r] + bb;
        if (addf) v += addf[oi];
        out[oi] = v;
      }
    }
  }
}

// ---------------- conv1x1 fp32 (cfunc path) ----------------
__global__ __launch_bounds__(256)
void conv1x1_kernel(const float* __restrict__ in, const float* __restrict__ wf,
                    const float* __restrict__ bias, const float* __restrict__ addb,
                    float* __restrict__ out){
  int b = blockIdx.y, co0 = blockIdx.x*4, tid = threadIdx.x;
  float acc[4][4] = {{0.f}};
  size_t inb = (size_t)b*NC*NHW;
  for (int ci=0; ci<NC; ++ci){
    float v[4];
    const float* ip = in + inb + (size_t)ci*NHW + tid;
    #pragma unroll
    for (int p=0;p<4;p++) v[p] = ip[p*256];
    #pragma unroll
    for (int co=0;co<4;co++){
      float wv = wf[(size_t)(co0+co)*NC + ci];
      #pragma unroll
      for (int p=0;p<4;p++) acc[co][p] += wv*v[p];
    }
  }
  #pragma unroll
  for (int co=0;co<4;co++){
    float bb = bias ? bias[co0+co] : 0.f;
    size_t ob = ((size_t)b*NC + co0+co)*NHW + tid;
    #pragma unroll
    for (int p=0;p<4;p++){
      float v = acc[co][p] + bb;
      if (addb) v += addb[ob + p*256];
      out[ob + p*256] = v;
    }
  }
}

// ---------------- qkv conv1x1: writes q_t[s][c], k_t[t][c], v[c][t] (bf16) ----------------
__global__ __launch_bounds__(256)
void qkv_kernel(const float* __restrict__ in, const float* __restrict__ wf,
                short* __restrict__ qt, short* __restrict__ kt, short* __restrict__ vt){
  int b = blockIdx.y, co0 = blockIdx.x*4, tid = threadIdx.x;
  float acc[4][4] = {{0.f}};
  size_t inb = (size_t)b*NC*NHW;
  for (int ci=0; ci<NC; ++ci){
    float v[4];
    const float* ip = in + inb + (size_t)ci*NHW + tid;
    #pragma unroll
    for (int p=0;p<4;p++) v[p] = ip[p*256];
    #pragma unroll
    for (int co=0;co<4;co++){
      float wv = wf[(size_t)(co0+co)*NC + ci];
      #pragma unroll
      for (int p=0;p<4;p++) acc[co][p] += wv*v[p];
    }
  }
  int sec = co0 >> 8;         // 0=q, 1=k, 2=v
  int cc  = co0 & 255;
  if (sec < 2){
    short* dst = (sec==0) ? qt : kt;
    #pragma unroll
    for (int p=0;p<4;p++){
      int s = tid + p*256;
      unsigned short t0 = f2bu(acc[0][p]), t1 = f2bu(acc[1][p]);
      unsigned short t2 = f2bu(acc[2][p]), t3 = f2bu(acc[3][p]);
      uint2 w; w.x = ((unsigned)t1<<16)|t0; w.y = ((unsigned)t3<<16)|t2;
      *(uint2*)(dst + ((size_t)b*NHW + s)*NC + cc) = w;
    }
  } else {
    #pragma unroll
    for (int co=0;co<4;co++){
      size_t ob = ((size_t)b*NC + cc+co)*NHW + tid;
      #pragma unroll
      for (int p=0;p<4;p++)
        vt[ob + p*256] = (short)f2bu(acc[co][p]);
    }
  }
}

// ---------------- MFMA fused attention ----------------
__global__ __launch_bounds__(256)
void attn_mfma_kernel(const short* __restrict__ qt, const short* __restrict__ kt,
                      const short* __restrict__ vv, float* __restrict__ ot){
  const int b = blockIdx.y, s0 = blockIdx.x*16;
  const int tid = threadIdx.x, wave = tid>>6, lane = tid&63;
  const int quad = lane>>4, lm = lane&15;
  __shared__ short P[16][1032];
  __shared__ float redmax[16][4], redsum[16][4];

  short8 aq[8];
  const short* qrow = qt + ((size_t)b*NHW + s0 + lm)*NC + quad*8;
  #pragma unroll
  for (int kk=0;kk<8;kk++) aq[kk] = *(const short8*)(qrow + kk*32);

  floatx4 sc[16];
  #pragma unroll
  for (int ti=0;ti<16;ti++) sc[ti] = (floatx4){0.f,0.f,0.f,0.f};
  const short* kbase = kt + ((size_t)b*NHW + wave*256 + lm)*NC + quad*8;
  for (int ti=0;ti<16;ti++){
    const short* kr = kbase + (size_t)ti*16*NC;
    #pragma unroll
    for (int kk=0;kk<8;kk++){
      short8 bv = *(const short8*)(kr + kk*32);
      sc[ti] = __builtin_amdgcn_mfma_f32_16x16x32_bf16(aq[kk], bv, sc[ti], 0,0,0);
    }
  }
  const float scale = 0.0625f;
  float mx[4] = {-1e30f,-1e30f,-1e30f,-1e30f};
  #pragma unroll
  for (int ti=0;ti<16;ti++)
    #pragma unroll
    for (int r=0;r<4;r++){
      float v = sc[ti][r]*scale;
      sc[ti][r] = v;
      mx[r] = fmaxf(mx[r], v);
    }
  #pragma unroll
  for (int o=1;o<16;o<<=1)
    #pragma unroll
    for (int r=0;r<4;r++) mx[r] = fmaxf(mx[r], __shfl_xor(mx[r], o, 64));
  if (lm==0){
    #pragma unroll
    for (int r=0;r<4;r++) redmax[quad*4+r][wave] = mx[r];
  }
  __syncthreads();
  float fm[4];
  #pragma unroll
  for (int r=0;r<4;r++){
    int row = quad*4+r;
    fm[r] = fmaxf(fmaxf(redmax[row][0],redmax[row][1]),
                  fmaxf(redmax[row][2],redmax[row][3]));
  }
  float sm[4] = {0.f,0.f,0.f,0.f};
  #pragma unroll
  for (int ti=0;ti<16;ti++)
    #pragma unroll
    for (int r=0;r<4;r++){
      float e = __expf(sc[ti][r] - fm[r]);
      sc[ti][r] = e;
      sm[r] += e;
    }
  #pragma unroll
  for (int o=1;o<16;o<<=1)
    #pragma unroll
    for (int r=0;r<4;r++) sm[r] += __shfl_xor(sm[r], o, 64);
  if (lm==0){
    #pragma unroll
    for (int r=0;r<4;r++) redsum[quad*4+r][wave] = sm[r];
  }
  __syncthreads();
  float inv[4];
  #pragma unroll
  for (int r=0;r<4;r++){
    int row = quad*4+r;
    inv[r] = 1.f/(redsum[row][0]+redsum[row][1]+redsum[row][2]+redsum[row][3]);
  }
  #pragma unroll
  for (int ti=0;ti<16;ti++)
    #pragma unroll
    for (int r=0;r<4;r++)
      P[quad*4+r][wave*256 + ti*16 + lm] = (short)f2bu(sc[ti][r]*inv[r]);
  __syncthreads();

  floatx4 oacc[4];
  #pragma unroll
  for (int nt=0;nt<4;nt++) oacc[nt] = (floatx4){0.f,0.f,0.f,0.f};
  const short* vbase = vv + ((size_t)b*NC + wave*64 + lm)*NHW + quad*8;
  for (int kk=0;kk<32;kk++){
    short8 av = *(const short8*)(&P[lm][kk*32 + quad*8]);
    #pragma unroll
    for (int nt=0;nt<4;nt++){
      short8 bvv = *(const short8*)(vbase + (size_t)nt*16*NHW + kk*32);
      oacc[nt] = __builtin_amdgcn_mfma_f32_16x16x32_bf16(av, bvv, oacc[nt], 0,0,0);
    }
  }
  #pragma unroll
  for (int nt=0;nt<4;nt++){
    int c = wave*64 + nt*16 + lm;
    #pragma unroll
    for (int r=0;r<4;r++){
      int s = s0 + quad*4 + r;
      ot[((size_t)b*NHW + s)*NC + c] = oacc[nt][r];
    }
  }
}

// ---------------- out-proj: out[b][co][s] = W @ o_t^T + out_b + h ----------------
__global__ __launch_bounds__(256)
void outproj_kernel(const float* __restrict__ ot, const float* __restrict__ wo,
                    const float* __restrict__ obias, const float* __restrict__ h,
                    float* __restrict__ out){
  int b = blockIdx.z, c0 = blockIdx.y*64, s0 = blockIdx.x*64;
  __shared__ float Ws[64][17], Os[64][17];
  int tid = threadIdx.x, tx = tid&15, ty = tid>>4;
  float acc[4][4] = {{0.f}};
  const float* otb = ot + (size_t)b*NHW*NC;
  for (int t0=0;t0<NC;t0+=16){
    for (int i=tid;i<1024;i+=256){
      int row=i>>4, col=i&15;
      Ws[row][col] = wo[(size_t)(c0+row)*NC + t0+col];
      Os[row][col] = otb[(size_t)(s0+row)*NC + t0+col];
    }
    __syncthreads();
    #pragma unroll
    for (int kk=0;kk<16;kk++){
      float wv[4], av[4];
      #pragma unroll
      for (int i=0;i<4;i++){ wv[i]=Ws[ty*4+i][kk]; av[i]=Os[tx*4+i][kk]; }
      #pragma unroll
      for (int i=0;i<4;i++)
        #pragma unroll
        for (int j=0;j<4;j++) acc[i][j] += wv[i]*av[j];
    }
    __syncthreads();
  }
  #pragma unroll
  for (int i=0;i<4;i++){
    int c = c0 + ty*4 + i;
    float bb = obias[c];
    size_t base = ((size_t)b*NC + c)*NHW + s0 + tx*4;
    #pragma unroll
    for (int j=0;j<4;j++) out[base+j] = acc[i][j] + bb + h[base+j];
  }
}

extern "C" void kernel_launch(void* const* d_in, const int* in_sizes, int n_in,
                              void* d_out, int out_size, void* d_ws, size_t ws_size,
                              hipStream_t stream){
  const float* x        = (const float*)d_in[0];
  const float* time_emb = (const float*)d_in[1];
  const float* c_in     = (const float*)d_in[2];
  const float* gn1_g    = (const float*)d_in[3];
  const float* gn1_b    = (const float*)d_in[4];
  const float* conv1_w  = (const float*)d_in[5];
  const float* conv1_b  = (const float*)d_in[6];
  const float* noise_w  = (const float*)d_in[7];
  const float* noise_b  = (const float*)d_in[8];
  const float* gn2_g    = (const float*)d_in[9];
  const float* gn2_b    = (const float*)d_in[10];
  const float* conv2_w  = (const float*)d_in[11];
  const float* conv2_b  = (const float*)d_in[12];
  const float* cfunc_w  = (const float*)d_in[13];
  const float* cfunc_b  = (const float*)d_in[14];
  const float* agn_g    = (const float*)d_in[15];
  const float* agn_b    = (const float*)d_in[16];
  const float* qkv_w    = (const float*)d_in[17];
  const float* out_w    = (const float*)d_in[18];
  const float* out_b    = (const float*)d_in[19];
  float* outp = (float*)d_out;

  // ---- workspace layout (~59 MB; X_t/W_t alias the q/k/v slabs) ----
  float* ws = (float*)d_ws;
  float* buf_h = ws;                     // NP fp32
  float* buf_t = buf_h + NP;             // NP fp32
  short* qt    = (short*)(buf_t + NP);   // NP bf16: X_t, then q_t[s][c]
  short* ktb   = qt + NP;                // NP bf16: W_t1, then k_t[t][c]
  short* vtb   = ktb + NP;               // NP bf16: W_t2, then v[c][t]
  float* buf_na = (float*)(vtb + NP);    // NB*NC fp32
  short* xtb = qt;                       // alias
  short* wt1 = ktb;                      // alias (1.18 MB of 8.4 MB slab)
  short* wt2 = vtb;                      // alias

  // ---- ResnetBlock ----
  wprep_kernel<<<512, 256, 0, stream>>>(conv1_w, conv2_w, wt1, wt2);
  gn_t_kernel<<<NB*NG, 256, 0, stream>>>(x, gn1_g, gn1_b, xtb);
  noise_kernel<<<NB, 256, 0, stream>>>(time_emb, noise_w, noise_b, buf_na);
  conv3_mfma_kernel<<<dim3(16, NB), 256, 0, stream>>>(xtb, wt1, conv1_b, buf_na, nullptr, buf_h);
  gn_t_kernel<<<NB*NG, 256, 0, stream>>>(buf_h, gn2_g, gn2_b, xtb);
  conv1x1_kernel<<<dim3(NC/4, NB), 256, 0, stream>>>(c_in, cfunc_w, cfunc_b, x, buf_h);
  conv3_mfma_kernel<<<dim3(16, NB), 256, 0, stream>>>(xtb, wt2, conv2_b, nullptr, buf_h, buf_h);
  // ---- Attention ----
  gn_kernel<<<NB*NG, 256, 0, stream>>>(buf_h, agn_g, agn_b, buf_t);
  qkv_kernel<<<dim3(3*NC/4, NB), 256, 0, stream>>>(buf_t, qkv_w, qt, ktb, vtb);
  attn_mfma_kernel<<<dim3(NHW/16, NB), 256, 0, stream>>>(qt, ktb, vtb, buf_t);
  outproj_kernel<<<dim3(NHW/64, NC/64, NB), 256, 0, stream>>>(buf_t, out_w, out_b, buf_h, outp);
}

// Round 6
// 478.589 us; speedup vs baseline: 3.9616x; 1.3667x over previous
//
#include <hip/hip_runtime.h>
#include <hip/hip_bf16.h>
#include <math.h>

typedef __hip_bfloat16 bf16;
typedef short short8 __attribute__((ext_vector_type(8)));
typedef float floatx4 __attribute__((ext_vector_type(4)));

#define NB 16
#define NC 256
#define NHW 1024
#define NNE 256
#define NP (NB*NC*NHW)

__device__ __forceinline__ unsigned short f2bu(float f){
  bf16 h = (bf16)f; return *(unsigned short*)&h;
}

// ---------------- GroupNorm (+opt Swish) -> packed bf16 x_p[b][cc][px][32] ----------------
template<bool SWISH>
__global__ void gn_t_kernel(const float* __restrict__ src, const float* __restrict__ gamma,
                            const float* __restrict__ beta, short* __restrict__ xp){
  int b = blockIdx.x >> 5, g = blockIdx.x & 31;
  const int GSZ = 8*NHW;
  size_t base = ((size_t)b*NC + g*8)*NHW;
  int tid = threadIdx.x;
  float s = 0.f, ss = 0.f;
  for (int i = tid; i < GSZ; i += 256){
    float v = src[base+i];
    s += v; ss += v*v;
  }
  __shared__ float rs[256], rq[256];
  rs[tid] = s; rq[tid] = ss;
  __syncthreads();
  for (int off=128; off>0; off>>=1){
    if (tid < off){ rs[tid]+=rs[tid+off]; rq[tid]+=rq[tid+off]; }
    __syncthreads();
  }
  float mean = rs[0] * (1.f/GSZ);
  float var  = rq[0] * (1.f/GSZ) - mean*mean;
  float inv  = rsqrtf(var + 1e-5f);
  float gm[8], bt[8];
  #pragma unroll
  for (int j=0;j<8;j++){ gm[j] = gamma[g*8+j]*inv; bt[j] = beta[g*8+j]; }
  short* dst = xp + (((size_t)b*8 + (g>>2))*NHW)*32 + (g&3)*8;
  for (int px = tid; px < NHW; px += 256){
    short8 pk;
    #pragma unroll
    for (int j=0;j<8;j++){
      float v = (src[base + j*NHW + px] - mean)*gm[j] + bt[j];
      if (SWISH) v = v / (1.f + __expf(-v));
      pk[j] = (short)f2bu(v);
    }
    *(short8*)(dst + (size_t)px*32) = pk;
  }
}

// ---------------- conv3 weight prep: OIHW fp32 -> w_p[tap][cc][co][32] bf16 ----------------
__global__ void wprep3_kernel(const float* __restrict__ w1, const float* __restrict__ w2,
                              short* __restrict__ wp1, short* __restrict__ wp2){
  int co = blockIdx.x & 255;
  const float* w = (blockIdx.x < 256) ? w1 : w2;
  short* wp = (blockIdx.x < 256) ? wp1 : wp2;
  int tid = threadIdx.x;
  __shared__ float tmp[2304];
  for (int i=tid;i<2304;i+=256) tmp[i] = w[(size_t)co*2304 + i];   // [ci][tap]
  __syncthreads();
  for (int j=tid;j<2304;j+=256){
    int tap = j>>8, ci = j&255;
    wp[(((size_t)tap*8 + (ci>>5))*NC + co)*32 + (ci&31)] = (short)f2bu(tmp[ci*9 + tap]);
  }
}

// ---------------- 1x1 weight prep: [co][ci] fp32 -> [cc][co][32] bf16 (qkv:768, cfunc:256) ----------------
__global__ void wprep1_kernel(const float* __restrict__ wq, const float* __restrict__ wc,
                              short* __restrict__ wqp, short* __restrict__ wcp){
  int blk = blockIdx.x, tid = threadIdx.x;
  if (blk < 768){
    float v = wq[(size_t)blk*256 + tid];
    wqp[(((size_t)(tid>>5))*768 + blk)*32 + (tid&31)] = (short)f2bu(v);
  } else {
    int co = blk - 768;
    float v = wc[(size_t)co*256 + tid];
    wcp[(((size_t)(tid>>5))*256 + co)*32 + (tid&31)] = (short)f2bu(v);
  }
}

// ---------------- c_in fp32 [b][ci][hw] -> cp[b][cc][px][32] bf16 ----------------
__global__ void cvtc_kernel(const float* __restrict__ c_in, short* __restrict__ cp){
  int pxc = blockIdx.x, cc = blockIdx.y, b = blockIdx.z, tid = threadIdx.x;
  __shared__ float ld[32][257];
  size_t gbase = ((size_t)b*NC + cc*32)*NHW + pxc*256;
  for (int j=0;j<32;j++) ld[j][tid] = c_in[gbase + (size_t)j*NHW + tid];
  __syncthreads();
  short* dst = cp + (((size_t)b*8 + cc)*NHW + pxc*256)*32;
  for (int it=0;it<4;it++){
    int pxl = it*64 + (tid>>2), ckl = tid&3;
    short8 pk;
    #pragma unroll
    for (int e=0;e<8;e++) pk[e] = (short)f2bu(ld[ckl*8+e][pxl]);
    *(short8*)(dst + (size_t)pxl*32 + ckl*8) = pk;
  }
}

// ---------------- FeatureWiseAffine bias: na[b][c] ----------------
__global__ void noise_kernel(const float* __restrict__ emb, const float* __restrict__ w,
                             const float* __restrict__ bias, float* __restrict__ na){
  int b = blockIdx.x, c = threadIdx.x;
  __shared__ float e[NNE];
  e[c] = emb[b*NNE + c];
  __syncthreads();
  float acc = bias[c];
  for (int k=0;k<NNE;k++) acc += e[k]*w[c*NNE+k];
  na[b*NC + c] = acc;
}

// ---------------- MFMA conv3x3 ----------------
#define XSTR 264
__global__ __launch_bounds__(256)
void conv3_mfma_kernel(const short* __restrict__ xp, const short* __restrict__ wp,
                       const float* __restrict__ bias, const float* __restrict__ bias_bc,
                       const float* __restrict__ addf, float* __restrict__ out){
  const int b = blockIdx.y, y0 = blockIdx.x*2;
  const int tid = threadIdx.x, wave = tid>>6, lane = tid&63;
  const int quad = lane>>4, lm = lane&15;
  __shared__ short Xs[4*34*XSTR];

  { // zero halo columns
    int r = tid>>6, side = (tid>>5)&1, ck = tid&31;
    short8 z = {0,0,0,0,0,0,0,0};
    *(short8*)&Xs[((r*34) + side*33)*XSTR + ck*8] = z;
  }
  // stage 4 rows x 32 px x 256 ci from packed x_p (dense 1KB/instr)
  for (int it=0; it<16; ++it){
    int idx = it*256 + tid;
    int r = idx>>10, rem = idx&1023;
    int cc = rem>>7, x = (rem>>2)&31, ckl = rem&3;
    int y = y0 - 1 + r;
    short8 v = {0,0,0,0,0,0,0,0};
    if ((unsigned)y < 32u)
      v = *(const short8*)(xp + (((size_t)b*8 + cc)*NHW + y*32 + x)*32 + ckl*8);
    *(short8*)&Xs[(r*34 + x + 1)*XSTR + (cc*4 + ckl)*8] = v;
  }
  __syncthreads();

  floatx4 acc[4][4];
  #pragma unroll
  for (int mt=0;mt<4;mt++)
    #pragma unroll
    for (int nt=0;nt<4;nt++) acc[mt][nt] = (floatx4){0.f,0.f,0.f,0.f};

  const int co_w = wave*64;
  for (int tap=0; tap<9; ++tap){
    const int dy = tap/3, dxp = tap - dy*3;
    const int bB = (lm + dxp)*XSTR + quad*8;
    #pragma unroll
    for (int kk=0;kk<8;kk++){
      short8 af[4];
      #pragma unroll
      for (int mt=0;mt<4;mt++)
        af[mt] = *(const short8*)(wp + (((size_t)tap*8 + kk)*NC + co_w + mt*16 + lm)*32 + quad*8);
      short8 bfr[4];
      #pragma unroll
      for (int nt=0;nt<4;nt++){
        int addr = ((nt>>1)+dy)*(34*XSTR) + (nt&1)*(16*XSTR) + bB + kk*32;
        bfr[nt] = *(const short8*)&Xs[addr];
      }
      #pragma unroll
      for (int mt=0;mt<4;mt++)
        #pragma unroll
        for (int nt=0;nt<4;nt++)
          acc[mt][nt] = __builtin_amdgcn_mfma_f32_16x16x32_bf16(af[mt], bfr[nt], acc[mt][nt], 0,0,0);
    }
  }

  const int hw0 = blockIdx.x*64;
  #pragma unroll
  for (int mt=0;mt<4;mt++){
    #pragma unroll
    for (int r=0;r<4;r++){
      int co = co_w + mt*16 + quad*4 + r;
      float bb = bias[co] + (bias_bc ? bias_bc[b*NC + co] : 0.f);
      size_t ob = ((size_t)b*NC + co)*NHW + hw0;
      #pragma unroll
      for (int nt=0;nt<4;nt++){
        size_t oi = ob + nt*16 + lm;
        float v = acc[mt][nt][r] + bb;
        if (addf) v += addf[oi];
        out[oi] = v;
      }
    }
  }
}

// ---------------- MFMA GEMM: cfunc(c) + bias + x -> fp32 [b][co][hw] ----------------
__global__ __launch_bounds__(256)
void gemm_cfunc_kernel(const short* __restrict__ cp, const short* __restrict__ wcp,
                       const float* __restrict__ bias, const float* __restrict__ xres,
                       float* __restrict__ out){
  const int b = blockIdx.z;
  const int tid = threadIdx.x, wave = tid>>6, lane = tid&63;
  const int quad = lane>>4, lm = lane&15;
  const int M0 = blockIdx.y*128 + (wave>>1)*64;
  const int N0 = blockIdx.x*128 + (wave&1)*64;
  floatx4 acc[4][4];
  #pragma unroll
  for (int mt=0;mt<4;mt++)
    #pragma unroll
    for (int nt=0;nt<4;nt++) acc[mt][nt] = (floatx4){0.f,0.f,0.f,0.f};
  #pragma unroll
  for (int kk=0;kk<8;kk++){
    short8 af[4], bfr[4];
    #pragma unroll
    for (int mt=0;mt<4;mt++)
      af[mt] = *(const short8*)(wcp + ((size_t)kk*256 + M0 + mt*16 + lm)*32 + quad*8);
    #pragma unroll
    for (int nt=0;nt<4;nt++)
      bfr[nt] = *(const short8*)(cp + (((size_t)b*8 + kk)*NHW + N0 + nt*16 + lm)*32 + quad*8);
    #pragma unroll
    for (int mt=0;mt<4;mt++)
      #pragma unroll
      for (int nt=0;nt<4;nt++)
        acc[mt][nt] = __builtin_amdgcn_mfma_f32_16x16x32_bf16(af[mt], bfr[nt], acc[mt][nt], 0,0,0);
  }
  #pragma unroll
  for (int mt=0;mt<4;mt++){
    #pragma unroll
    for (int r=0;r<4;r++){
      int co = M0 + mt*16 + quad*4 + r;
      float bb = bias[co];
      size_t ob = ((size_t)b*NC + co)*NHW + N0;
      #pragma unroll
      for (int nt=0;nt<4;nt++){
        size_t oi = ob + nt*16 + lm;
        out[oi] = acc[mt][nt][r] + bb + xres[oi];
      }
    }
  }
}

// ---------------- MFMA GEMM qkv: n_t(x_p) x wq -> q_p/k_p (packed), v_p ----------------
__global__ __launch_bounds__(256)
void gemm_qkv_kernel(const short* __restrict__ ntp, const short* __restrict__ wqp,
                     short* __restrict__ qp, short* __restrict__ kp, short* __restrict__ vp){
  const int b = blockIdx.z;
  const int tid = threadIdx.x, wave = tid>>6, lane = tid&63;
  const int quad = lane>>4, lm = lane&15;
  const int M0 = blockIdx.y*128 + (wave>>1)*64;
  const int N0 = blockIdx.x*128 + (wave&1)*64;
  floatx4 acc[4][4];
  #pragma unroll
  for (int mt=0;mt<4;mt++)
    #pragma unroll
    for (int nt=0;nt<4;nt++) acc[mt][nt] = (floatx4){0.f,0.f,0.f,0.f};
  #pragma unroll
  for (int kk=0;kk<8;kk++){
    short8 af[4], bfr[4];
    #pragma unroll
    for (int mt=0;mt<4;mt++)
      af[mt] = *(const short8*)(wqp + ((size_t)kk*768 + M0 + mt*16 + lm)*32 + quad*8);
    #pragma unroll
    for (int nt=0;nt<4;nt++)
      bfr[nt] = *(const short8*)(ntp + (((size_t)b*8 + kk)*NHW + N0 + nt*16 + lm)*32 + quad*8);
    #pragma unroll
    for (int mt=0;mt<4;mt++)
      #pragma unroll
      for (int nt=0;nt<4;nt++)
        acc[mt][nt] = __builtin_amdgcn_mfma_f32_16x16x32_bf16(af[mt], bfr[nt], acc[mt][nt], 0,0,0);
  }
  #pragma unroll
  for (int mt=0;mt<4;mt++){
    int co_base = M0 + mt*16 + quad*4;
    int sec = co_base >> 8;           // wave-uniform per mt
    int c = co_base & 255;
    #pragma unroll
    for (int nt=0;nt<4;nt++){
      int s = N0 + nt*16 + lm;
      if (sec < 2){
        unsigned short t0 = f2bu(acc[mt][nt][0]), t1 = f2bu(acc[mt][nt][1]);
        unsigned short t2 = f2bu(acc[mt][nt][2]), t3 = f2bu(acc[mt][nt][3]);
        uint2 w2; w2.x = ((unsigned)t1<<16)|t0; w2.y = ((unsigned)t3<<16)|t2;
        short* dst = (sec==0) ? qp : kp;
        *(uint2*)(dst + (((size_t)b*8 + (c>>5))*NHW + s)*32 + (c&31)) = w2;
      } else {
        #pragma unroll
        for (int r=0;r<4;r++)
          vp[(((size_t)b*32 + (s>>5))*NC + c + r)*32 + (s&31)] = (short)f2bu(acc[mt][nt][r]);
      }
    }
  }
}

// ---------------- MFMA fused attention (dense packed frags + reg prefetch) ----------------
// q_p/k_p[b][cc][t][32], v_p[b][tc][c][32]; out ot[b][s][c] fp32.
__global__ __launch_bounds__(256)
void attn_mfma_kernel(const short* __restrict__ qp, const short* __restrict__ kp,
                      const short* __restrict__ vp, float* __restrict__ ot){
  const int b = blockIdx.y, s0 = blockIdx.x*16;
  const int tid = threadIdx.x, wave = tid>>6, lane = tid&63;
  const int quad = lane>>4, lm = lane&15;
  __shared__ short P[16][1032];
  __shared__ float redmax[16][4], redsum[16][4];

  // Q A-frags (dense)
  short8 aq[8];
  #pragma unroll
  for (int kk=0;kk<8;kk++)
    aq[kk] = *(const short8*)(qp + (((size_t)b*8 + kk)*NHW + s0 + lm)*32 + quad*8);

  // ---- phase 1: scores, ping-pong prefetch halves of 4 ----
  floatx4 sc[16];
  #pragma unroll
  for (int ti=0;ti<16;ti++) sc[ti] = (floatx4){0.f,0.f,0.f,0.f};
  const size_t kbq = quad*8;
  const int trow0 = wave*256 + lm;
  short8 kfA[4], kfB[4];
  #pragma unroll
  for (int j=0;j<4;j++)
    kfA[j] = *(const short8*)(kp + (((size_t)b*8 + j)*NHW + trow0)*32 + kbq);
  #pragma unroll
  for (int ti=0;ti<16;ti++){
    #pragma unroll
    for (int j=0;j<4;j++)
      kfB[j] = *(const short8*)(kp + (((size_t)b*8 + 4+j)*NHW + trow0 + ti*16)*32 + kbq);
    #pragma unroll
    for (int j=0;j<4;j++)
      sc[ti] = __builtin_amdgcn_mfma_f32_16x16x32_bf16(aq[j], kfA[j], sc[ti], 0,0,0);
    if (ti < 15){
      #pragma unroll
      for (int j=0;j<4;j++)
        kfA[j] = *(const short8*)(kp + (((size_t)b*8 + j)*NHW + trow0 + (ti+1)*16)*32 + kbq);
    }
    #pragma unroll
    for (int j=0;j<4;j++)
      sc[ti] = __builtin_amdgcn_mfma_f32_16x16x32_bf16(aq[4+j], kfB[j], sc[ti], 0,0,0);
  }

  const float scale = 0.0625f;
  float mx[4] = {-1e30f,-1e30f,-1e30f,-1e30f};
  #pragma unroll
  for (int ti=0;ti<16;ti++)
    #pragma unroll
    for (int r=0;r<4;r++){
      float v = sc[ti][r]*scale;
      sc[ti][r] = v;
      mx[r] = fmaxf(mx[r], v);
    }
  #pragma unroll
  for (int o=1;o<16;o<<=1)
    #pragma unroll
    for (int r=0;r<4;r++) mx[r] = fmaxf(mx[r], __shfl_xor(mx[r], o, 64));
  if (lm==0){
    #pragma unroll
    for (int r=0;r<4;r++) redmax[quad*4+r][wave] = mx[r];
  }
  __syncthreads();
  float fm[4];
  #pragma unroll
  for (int r=0;r<4;r++){
    int row = quad*4+r;
    fm[r] = fmaxf(fmaxf(redmax[row][0],redmax[row][1]),
                  fmaxf(redmax[row][2],redmax[row][3]));
  }
  float sm[4] = {0.f,0.f,0.f,0.f};
  #pragma unroll
  for (int ti=0;ti<16;ti++)
    #pragma unroll
    for (int r=0;r<4;r++){
      float e = __expf(sc[ti][r] - fm[r]);
      sc[ti][r] = e;
      sm[r] += e;
    }
  #pragma unroll
  for (int o=1;o<16;o<<=1)
    #pragma unroll
    for (int r=0;r<4;r++) sm[r] += __shfl_xor(sm[r], o, 64);
  if (lm==0){
    #pragma unroll
    for (int r=0;r<4;r++) redsum[quad*4+r][wave] = sm[r];
  }
  __syncthreads();
  float inv[4];
  #pragma unroll
  for (int r=0;r<4;r++){
    int row = quad*4+r;
    inv[r] = 1.f/(redsum[row][0]+redsum[row][1]+redsum[row][2]+redsum[row][3]);
  }
  #pragma unroll
  for (int ti=0;ti<16;ti++)
    #pragma unroll
    for (int r=0;r<4;r++)
      P[quad*4+r][wave*256 + ti*16 + lm] = (short)f2bu(sc[ti][r]*inv[r]);
  __syncthreads();

  // ---- phase 2: PV with ping-pong prefetch ----
  floatx4 oacc[4];
  #pragma unroll
  for (int nt=0;nt<4;nt++) oacc[nt] = (floatx4){0.f,0.f,0.f,0.f};
  const int crow = wave*64 + lm;
  short8 vfA[4], vfB[4], pfA, pfB;
  #pragma unroll
  for (int nt=0;nt<4;nt++)
    vfA[nt] = *(const short8*)(vp + (((size_t)b*32 + 0)*NC + crow + nt*16)*32 + quad*8);
  pfA = *(const short8*)(&P[lm][quad*8]);
  #pragma unroll
  for (int kk=0;kk<32;kk++){
    if (kk & 1){
      if (kk < 31){
        #pragma unroll
        for (int nt=0;nt<4;nt++)
          vfA[nt] = *(const short8*)(vp + (((size_t)b*32 + kk+1)*NC + crow + nt*16)*32 + quad*8);
        pfA = *(const short8*)(&P[lm][(kk+1)*32 + quad*8]);
      }
      #pragma unroll
      for (int nt=0;nt<4;nt++)
        oacc[nt] = __builtin_amdgcn_mfma_f32_16x16x32_bf16(pfB, vfB[nt], oacc[nt], 0,0,0);
    } else {
      #pragma unroll
      for (int nt=0;nt<4;nt++)
        vfB[nt] = *(const short8*)(vp + (((size_t)b*32 + kk+1)*NC + crow + nt*16)*32 + quad*8);
      pfB = *(const short8*)(&P[lm][(kk+1)*32 + quad*8]);
      #pragma unroll
      for (int nt=0;nt<4;nt++)
        oacc[nt] = __builtin_amdgcn_mfma_f32_16x16x32_bf16(pfA, vfA[nt], oacc[nt], 0,0,0);
    }
  }
  #pragma unroll
  for (int nt=0;nt<4;nt++){
    int c = wave*64 + nt*16 + lm;
    #pragma unroll
    for (int r=0;r<4;r++){
      int s = s0 + quad*4 + r;
      ot[((size_t)b*NHW + s)*NC + c] = oacc[nt][r];
    }
  }
}

// ---------------- out-proj: out[b][co][s] = W @ o_t^T + out_b + h ----------------
__global__ __launch_bounds__(256)
void outproj_kernel(const float* __restrict__ ot, const float* __restrict__ wo,
                    const float* __restrict__ obias, const float* __restrict__ h,
                    float* __restrict__ out){
  int b = blockIdx.z, c0 = blockIdx.y*64, s0 = blockIdx.x*64;
  __shared__ float Ws[64][17], Os[64][17];
  int tid = threadIdx.x, tx = tid&15, ty = tid>>4;
  float acc[4][4] = {{0.f}};
  const float* otb = ot + (size_t)b*NHW*NC;
  for (int t0=0;t0<NC;t0+=16){
    for (int i=tid;i<1024;i+=256){
      int row=i>>4, col=i&15;
      Ws[row][col] = wo[(size_t)(c0+row)*NC + t0+col];
      Os[row][col] = otb[(size_t)(s0+row)*NC + t0+col];
    }
    __syncthreads();
    #pragma unroll
    for (int kk=0;kk<16;kk++){
      float wv[4], av[4];
      #pragma unroll
      for (int i=0;i<4;i++){ wv[i]=Ws[ty*4+i][kk]; av[i]=Os[tx*4+i][kk]; }
      #pragma unroll
      for (int i=0;i<4;i++)
        #pragma unroll
        for (int j=0;j<4;j++) acc[i][j] += wv[i]*av[j];
    }
    __syncthreads();
  }
  #pragma unroll
  for (int i=0;i<4;i++){
    int c = c0 + ty*4 + i;
    float bb = obias[c];
    size_t base = ((size_t)b*NC + c)*NHW + s0 + tx*4;
    #pragma unroll
    for (int j=0;j<4;j++) out[base+j] = acc[i][j] + bb + h[base+j];
  }
}

extern "C" void kernel_launch(void* const* d_in, const int* in_sizes, int n_in,
                              void* d_out, int out_size, void* d_ws, size_t ws_size,
                              hipStream_t stream){
  const float* x        = (const float*)d_in[0];
  const float* time_emb = (const float*)d_in[1];
  const float* c_in     = (const float*)d_in[2];
  const float* gn1_g    = (const float*)d_in[3];
  const float* gn1_b    = (const float*)d_in[4];
  const float* conv1_w  = (const float*)d_in[5];
  const float* conv1_b  = (const float*)d_in[6];
  const float* noise_w  = (const float*)d_in[7];
  const float* noise_b  = (const float*)d_in[8];
  const float* gn2_g    = (const float*)d_in[9];
  const float* gn2_b    = (const float*)d_in[10];
  const float* conv2_w  = (const float*)d_in[11];
  const float* conv2_b  = (const float*)d_in[12];
  const float* cfunc_w  = (const float*)d_in[13];
  const float* cfunc_b  = (const float*)d_in[14];
  const float* agn_g    = (const float*)d_in[15];
  const float* agn_b    = (const float*)d_in[16];
  const float* qkv_w    = (const float*)d_in[17];
  const float* out_w    = (const float*)d_in[18];
  const float* out_b    = (const float*)d_in[19];
  float* outp = (float*)d_out;

  // ---- workspace layout (~70 MB) ----
  float* ws = (float*)d_ws;
  float* buf_h = ws;                       // NP fp32
  float* buf_t = buf_h + NP;               // NP fp32 (o_t; front half aliased as cp)
  short* xpb   = (short*)(buf_t + NP);     // NP bf16 packed x_p / n_t
  short* qp    = xpb + NP;                 // NP bf16
  short* kp    = qp + NP;                  // NP bf16
  short* vp    = kp + NP;                  // NP bf16
  short* wp1   = vp + NP;                  // 589824
  short* wp2   = wp1 + 589824;             // 589824
  short* wqp   = wp2 + 589824;             // 196608
  short* wcp   = wqp + 196608;             // 65536
  float* na    = (float*)(wcp + 65536);    // NB*NC
  short* cp    = (short*)buf_t;            // alias: c_in packed bf16 (consumed before o_t written)

  // ---- prep ----
  wprep3_kernel<<<512, 256, 0, stream>>>(conv1_w, conv2_w, wp1, wp2);
  wprep1_kernel<<<1024, 256, 0, stream>>>(qkv_w, cfunc_w, wqp, wcp);
  cvtc_kernel<<<dim3(4,8,NB), 256, 0, stream>>>(c_in, cp);
  noise_kernel<<<NB, 256, 0, stream>>>(time_emb, noise_w, noise_b, na);
  // ---- ResnetBlock ----
  gn_t_kernel<true><<<NB*32, 256, 0, stream>>>(x, gn1_g, gn1_b, xpb);
  conv3_mfma_kernel<<<dim3(16, NB), 256, 0, stream>>>(xpb, wp1, conv1_b, na, nullptr, buf_h);
  gn_t_kernel<true><<<NB*32, 256, 0, stream>>>(buf_h, gn2_g, gn2_b, xpb);
  gemm_cfunc_kernel<<<dim3(8,2,NB), 256, 0, stream>>>(cp, wcp, cfunc_b, x, buf_h);
  conv3_mfma_kernel<<<dim3(16, NB), 256, 0, stream>>>(xpb, wp2, conv2_b, nullptr, buf_h, buf_h);
  // ---- Attention ----
  gn_t_kernel<false><<<NB*32, 256, 0, stream>>>(buf_h, agn_g, agn_b, xpb);
  gemm_qkv_kernel<<<dim3(8,6,NB), 256, 0, stream>>>(xpb, wqp, qp, kp, vp);
  attn_mfma_kernel<<<dim3(NHW/16, NB), 256, 0, stream>>>(qp, kp, vp, buf_t);
  outproj_kernel<<<dim3(NHW/64, NC/64, NB), 256, 0, stream>>>(buf_t, out_w, out_b, buf_h, outp);
}

// Round 7
// 477.176 us; speedup vs baseline: 3.9733x; 1.0030x over previous
//
#include <hip/hip_runtime.h>
#include <hip/hip_bf16.h>
#include <math.h>

typedef __hip_bfloat16 bf16;
typedef short short8 __attribute__((ext_vector_type(8)));
typedef float floatx4 __attribute__((ext_vector_type(4)));

#define NB 16
#define NC 256
#define NHW 1024
#define NNE 256
#define NP (NB*NC*NHW)

__device__ __forceinline__ unsigned short f2bu(float f){
  bf16 h = (bf16)f; return *(unsigned short*)&h;
}

// ---------------- GroupNorm two-pass (+Swish) -> packed bf16 x_p[b][cc][px][32] ----------------
template<bool SWISH>
__global__ void gn_t_kernel(const float* __restrict__ src, const float* __restrict__ gamma,
                            const float* __restrict__ beta, short* __restrict__ xp){
  int b = blockIdx.x >> 5, g = blockIdx.x & 31;
  const int GSZ = 8*NHW;
  size_t base = ((size_t)b*NC + g*8)*NHW;
  int tid = threadIdx.x;
  float s = 0.f, ss = 0.f;
  for (int i = tid; i < GSZ; i += 256){
    float v = src[base+i];
    s += v; ss += v*v;
  }
  __shared__ float rs[256], rq[256];
  rs[tid] = s; rq[tid] = ss;
  __syncthreads();
  for (int off=128; off>0; off>>=1){
    if (tid < off){ rs[tid]+=rs[tid+off]; rq[tid]+=rq[tid+off]; }
    __syncthreads();
  }
  float mean = rs[0] * (1.f/GSZ);
  float var  = rq[0] * (1.f/GSZ) - mean*mean;
  float inv  = rsqrtf(var + 1e-5f);
  float gm[8], bt[8];
  #pragma unroll
  for (int j=0;j<8;j++){ gm[j] = gamma[g*8+j]*inv; bt[j] = beta[g*8+j]; }
  short* dst = xp + (((size_t)b*8 + (g>>2))*NHW)*32 + (g&3)*8;
  for (int px = tid; px < NHW; px += 256){
    short8 pk;
    #pragma unroll
    for (int j=0;j<8;j++){
      float v = (src[base + j*NHW + px] - mean)*gm[j] + bt[j];
      if (SWISH) v = v / (1.f + __expf(-v));
      pk[j] = (short)f2bu(v);
    }
    *(short8*)(dst + (size_t)px*32) = pk;
  }
}

// ---------------- GroupNorm single-pass from precomputed stats ----------------
template<bool SWISH>
__global__ void gn_post_kernel(const float* __restrict__ src, const float* __restrict__ st,
                               const float* __restrict__ gamma, const float* __restrict__ beta,
                               short* __restrict__ xp){
  int b = blockIdx.x >> 5, g = blockIdx.x & 31;
  size_t base = ((size_t)b*NC + g*8)*NHW;
  int tid = threadIdx.x;
  float s  = st[(b*32+g)*2+0];
  float ss = st[(b*32+g)*2+1];
  float mean = s * (1.f/8192.f);
  float var  = ss * (1.f/8192.f) - mean*mean;
  float inv  = rsqrtf(var + 1e-5f);
  float gm[8], bt[8];
  #pragma unroll
  for (int j=0;j<8;j++){ gm[j] = gamma[g*8+j]*inv; bt[j] = beta[g*8+j]; }
  short* dst = xp + (((size_t)b*8 + (g>>2))*NHW)*32 + (g&3)*8;
  for (int px = tid; px < NHW; px += 256){
    short8 pk;
    #pragma unroll
    for (int j=0;j<8;j++){
      float v = (src[base + j*NHW + px] - mean)*gm[j] + bt[j];
      if (SWISH) v = v / (1.f + __expf(-v));
      pk[j] = (short)f2bu(v);
    }
    *(short8*)(dst + (size_t)px*32) = pk;
  }
}

// ---------------- conv3 weight prep + stats zero ----------------
__global__ void wprep3_kernel(const float* __restrict__ w1, const float* __restrict__ w2,
                              short* __restrict__ wp1, short* __restrict__ wp2,
                              float* __restrict__ st){
  int co = blockIdx.x & 255;
  const float* w = (blockIdx.x < 256) ? w1 : w2;
  short* wp = (blockIdx.x < 256) ? wp1 : wp2;
  int tid = threadIdx.x;
  if (blockIdx.x == 0){
    for (int i=tid;i<2048;i+=256) st[i] = 0.f;
  }
  __shared__ float tmp[2304];
  for (int i=tid;i<2304;i+=256) tmp[i] = w[(size_t)co*2304 + i];   // [ci][tap]
  __syncthreads();
  for (int j=tid;j<2304;j+=256){
    int tap = j>>8, ci = j&255;
    wp[(((size_t)tap*8 + (ci>>5))*NC + co)*32 + (ci&31)] = (short)f2bu(tmp[ci*9 + tap]);
  }
}

// ---------------- 1x1 weight prep: qkv(768) + cfunc(256) + outw(256) ----------------
__global__ void wprep1_kernel(const float* __restrict__ wq, const float* __restrict__ wc,
                              const float* __restrict__ wo,
                              short* __restrict__ wqp, short* __restrict__ wcp,
                              short* __restrict__ wop){
  int blk = blockIdx.x, tid = threadIdx.x;
  if (blk < 768){
    float v = wq[(size_t)blk*256 + tid];
    wqp[(((size_t)(tid>>5))*768 + blk)*32 + (tid&31)] = (short)f2bu(v);
  } else if (blk < 1024){
    int co = blk - 768;
    float v = wc[(size_t)co*256 + tid];
    wcp[(((size_t)(tid>>5))*256 + co)*32 + (tid&31)] = (short)f2bu(v);
  } else {
    int co = blk - 1024;
    float v = wo[(size_t)co*256 + tid];
    wop[(((size_t)(tid>>5))*256 + co)*32 + (tid&31)] = (short)f2bu(v);
  }
}

// ---------------- c_in fp32 [b][ci][hw] -> cp[b][cc][px][32] bf16 ----------------
__global__ void cvtc_kernel(const float* __restrict__ c_in, short* __restrict__ cp){
  int pxc = blockIdx.x, cc = blockIdx.y, b = blockIdx.z, tid = threadIdx.x;
  __shared__ float ld[32][257];
  size_t gbase = ((size_t)b*NC + cc*32)*NHW + pxc*256;
  for (int j=0;j<32;j++) ld[j][tid] = c_in[gbase + (size_t)j*NHW + tid];
  __syncthreads();
  short* dst = cp + (((size_t)b*8 + cc)*NHW + pxc*256)*32;
  for (int it=0;it<4;it++){
    int pxl = it*64 + (tid>>2), ckl = tid&3;
    short8 pk;
    #pragma unroll
    for (int e=0;e<8;e++) pk[e] = (short)f2bu(ld[ckl*8+e][pxl]);
    *(short8*)(dst + (size_t)pxl*32 + ckl*8) = pk;
  }
}

// ---------------- FeatureWiseAffine bias: na[b][c] ----------------
__global__ void noise_kernel(const float* __restrict__ emb, const float* __restrict__ w,
                             const float* __restrict__ bias, float* __restrict__ na){
  int b = blockIdx.x, c = threadIdx.x;
  __shared__ float e[NNE];
  e[c] = emb[b*NNE + c];
  __syncthreads();
  float acc = bias[c];
  for (int k=0;k<NNE;k++) acc += e[k]*w[c*NNE+k];
  na[b*NC + c] = acc;
}

// ---------------- MFMA conv3x3 (+fused group-stats atomics) ----------------
#define XSTR 264
__global__ __launch_bounds__(256)
void conv3_mfma_kernel(const short* __restrict__ xp, const short* __restrict__ wp,
                       const float* __restrict__ bias, const float* __restrict__ bias_bc,
                       const float* __restrict__ addf, float* __restrict__ out,
                       float* __restrict__ st){
  const int b = blockIdx.y, y0 = blockIdx.x*2;
  const int tid = threadIdx.x, wave = tid>>6, lane = tid&63;
  const int quad = lane>>4, lm = lane&15;
  __shared__ short Xs[4*34*XSTR];

  { // zero halo columns
    int r = tid>>6, side = (tid>>5)&1, ck = tid&31;
    short8 z = {0,0,0,0,0,0,0,0};
    *(short8*)&Xs[((r*34) + side*33)*XSTR + ck*8] = z;
  }
  for (int it=0; it<16; ++it){
    int idx = it*256 + tid;
    int r = idx>>10, rem = idx&1023;
    int cc = rem>>7, x = (rem>>2)&31, ckl = rem&3;
    int y = y0 - 1 + r;
    short8 v = {0,0,0,0,0,0,0,0};
    if ((unsigned)y < 32u)
      v = *(const short8*)(xp + (((size_t)b*8 + cc)*NHW + y*32 + x)*32 + ckl*8);
    *(short8*)&Xs[(r*34 + x + 1)*XSTR + (cc*4 + ckl)*8] = v;
  }
  __syncthreads();

  floatx4 acc[4][4];
  #pragma unroll
  for (int mt=0;mt<4;mt++)
    #pragma unroll
    for (int nt=0;nt<4;nt++) acc[mt][nt] = (floatx4){0.f,0.f,0.f,0.f};

  const int co_w = wave*64;
  for (int tap=0; tap<9; ++tap){
    const int dy = tap/3, dxp = tap - dy*3;
    const int bB = (lm + dxp)*XSTR + quad*8;
    #pragma unroll
    for (int kk=0;kk<8;kk++){
      short8 af[4];
      #pragma unroll
      for (int mt=0;mt<4;mt++)
        af[mt] = *(const short8*)(wp + (((size_t)tap*8 + kk)*NC + co_w + mt*16 + lm)*32 + quad*8);
      short8 bfr[4];
      #pragma unroll
      for (int nt=0;nt<4;nt++){
        int addr = ((nt>>1)+dy)*(34*XSTR) + (nt&1)*(16*XSTR) + bB + kk*32;
        bfr[nt] = *(const short8*)&Xs[addr];
      }
      #pragma unroll
      for (int mt=0;mt<4;mt++)
        #pragma unroll
        for (int nt=0;nt<4;nt++)
          acc[mt][nt] = __builtin_amdgcn_mfma_f32_16x16x32_bf16(af[mt], bfr[nt], acc[mt][nt], 0,0,0);
    }
  }

  const int hw0 = blockIdx.x*64;
  #pragma unroll
  for (int mt=0;mt<4;mt++){
    #pragma unroll
    for (int r=0;r<4;r++){
      int co = co_w + mt*16 + quad*4 + r;
      float bb = bias[co] + (bias_bc ? bias_bc[b*NC + co] : 0.f);
      size_t ob = ((size_t)b*NC + co)*NHW + hw0;
      float sl = 0.f, sq = 0.f;
      #pragma unroll
      for (int nt=0;nt<4;nt++){
        size_t oi = ob + nt*16 + lm;
        float v = acc[mt][nt][r] + bb;
        if (addf) v += addf[oi];
        out[oi] = v;
        sl += v; sq += v*v;
      }
      // reduce over the 16 lm lanes, then atomically fold into group stats
      #pragma unroll
      for (int o=1;o<16;o<<=1){
        sl += __shfl_xor(sl, o, 64);
        sq += __shfl_xor(sq, o, 64);
      }
      if (lm == 0){
        int g = co >> 3;
        atomicAdd(&st[(b*32+g)*2+0], sl);
        atomicAdd(&st[(b*32+g)*2+1], sq);
      }
    }
  }
}

// ---------------- MFMA GEMM: cfunc(c) + bias + x -> fp32 [b][co][hw] ----------------
__global__ __launch_bounds__(256)
void gemm_cfunc_kernel(const short* __restrict__ cp, const short* __restrict__ wcp,
                       const float* __restrict__ bias, const float* __restrict__ xres,
                       float* __restrict__ out){
  const int b = blockIdx.z;
  const int tid = threadIdx.x, wave = tid>>6, lane = tid&63;
  const int quad = lane>>4, lm = lane&15;
  const int M0 = blockIdx.y*128 + (wave>>1)*64;
  const int N0 = blockIdx.x*128 + (wave&1)*64;
  floatx4 acc[4][4];
  #pragma unroll
  for (int mt=0;mt<4;mt++)
    #pragma unroll
    for (int nt=0;nt<4;nt++) acc[mt][nt] = (floatx4){0.f,0.f,0.f,0.f};
  #pragma unroll
  for (int kk=0;kk<8;kk++){
    short8 af[4], bfr[4];
    #pragma unroll
    for (int mt=0;mt<4;mt++)
      af[mt] = *(const short8*)(wcp + ((size_t)kk*256 + M0 + mt*16 + lm)*32 + quad*8);
    #pragma unroll
    for (int nt=0;nt<4;nt++)
      bfr[nt] = *(const short8*)(cp + (((size_t)b*8 + kk)*NHW + N0 + nt*16 + lm)*32 + quad*8);
    #pragma unroll
    for (int mt=0;mt<4;mt++)
      #pragma unroll
      for (int nt=0;nt<4;nt++)
        acc[mt][nt] = __builtin_amdgcn_mfma_f32_16x16x32_bf16(af[mt], bfr[nt], acc[mt][nt], 0,0,0);
  }
  #pragma unroll
  for (int mt=0;mt<4;mt++){
    #pragma unroll
    for (int r=0;r<4;r++){
      int co = M0 + mt*16 + quad*4 + r;
      float bb = bias[co];
      size_t ob = ((size_t)b*NC + co)*NHW + N0;
      #pragma unroll
      for (int nt=0;nt<4;nt++){
        size_t oi = ob + nt*16 + lm;
        out[oi] = acc[mt][nt][r] + bb + xres[oi];
      }
    }
  }
}

// ---------------- MFMA GEMM qkv ----------------
__global__ __launch_bounds__(256)
void gemm_qkv_kernel(const short* __restrict__ ntp, const short* __restrict__ wqp,
                     short* __restrict__ qp, short* __restrict__ kp, short* __restrict__ vp){
  const int b = blockIdx.z;
  const int tid = threadIdx.x, wave = tid>>6, lane = tid&63;
  const int quad = lane>>4, lm = lane&15;
  const int M0 = blockIdx.y*128 + (wave>>1)*64;
  const int N0 = blockIdx.x*128 + (wave&1)*64;
  floatx4 acc[4][4];
  #pragma unroll
  for (int mt=0;mt<4;mt++)
    #pragma unroll
    for (int nt=0;nt<4;nt++) acc[mt][nt] = (floatx4){0.f,0.f,0.f,0.f};
  #pragma unroll
  for (int kk=0;kk<8;kk++){
    short8 af[4], bfr[4];
    #pragma unroll
    for (int mt=0;mt<4;mt++)
      af[mt] = *(const short8*)(wqp + ((size_t)kk*768 + M0 + mt*16 + lm)*32 + quad*8);
    #pragma unroll
    for (int nt=0;nt<4;nt++)
      bfr[nt] = *(const short8*)(ntp + (((size_t)b*8 + kk)*NHW + N0 + nt*16 + lm)*32 + quad*8);
    #pragma unroll
    for (int mt=0;mt<4;mt++)
      #pragma unroll
      for (int nt=0;nt<4;nt++)
        acc[mt][nt] = __builtin_amdgcn_mfma_f32_16x16x32_bf16(af[mt], bfr[nt], acc[mt][nt], 0,0,0);
  }
  #pragma unroll
  for (int mt=0;mt<4;mt++){
    int co_base = M0 + mt*16 + quad*4;
    int sec = co_base >> 8;
    int c = co_base & 255;
    #pragma unroll
    for (int nt=0;nt<4;nt++){
      int s = N0 + nt*16 + lm;
      if (sec < 2){
        unsigned short t0 = f2bu(acc[mt][nt][0]), t1 = f2bu(acc[mt][nt][1]);
        unsigned short t2 = f2bu(acc[mt][nt][2]), t3 = f2bu(acc[mt][nt][3]);
        uint2 w2; w2.x = ((unsigned)t1<<16)|t0; w2.y = ((unsigned)t3<<16)|t2;
        short* dst = (sec==0) ? qp : kp;
        *(uint2*)(dst + (((size_t)b*8 + (c>>5))*NHW + s)*32 + (c&31)) = w2;
      } else {
        #pragma unroll
        for (int r=0;r<4;r++)
          vp[(((size_t)b*32 + (s>>5))*NC + c + r)*32 + (s&31)] = (short)f2bu(acc[mt][nt][r]);
      }
    }
  }
}

// ---------------- MFMA fused attention (XCD-swizzled flat grid; packed bf16 out) ----------------
__global__ __launch_bounds__(256)
void attn_mfma_kernel(const short* __restrict__ qp, const short* __restrict__ kp,
                      const short* __restrict__ vp, short* __restrict__ op){
  const int bx = blockIdx.x;
  const int b = bx & 15;               // id%8 -> XCD: batches {b,b+8} share one XCD's L2
  const int s0 = (bx >> 4) * 16;
  const int tid = threadIdx.x, wave = tid>>6, lane = tid&63;
  const int quad = lane>>4, lm = lane&15;
  __shared__ short P[16][1032];
  __shared__ float redmax[16][4], redsum[16][4];

  short8 aq[8];
  #pragma unroll
  for (int kk=0;kk<8;kk++)
    aq[kk] = *(const short8*)(qp + (((size_t)b*8 + kk)*NHW + s0 + lm)*32 + quad*8);

  floatx4 sc[16];
  #pragma unroll
  for (int ti=0;ti<16;ti++) sc[ti] = (floatx4){0.f,0.f,0.f,0.f};
  const size_t kbq = quad*8;
  const int trow0 = wave*256 + lm;
  short8 kfA[4], kfB[4];
  #pragma unroll
  for (int j=0;j<4;j++)
    kfA[j] = *(const short8*)(kp + (((size_t)b*8 + j)*NHW + trow0)*32 + kbq);
  #pragma unroll
  for (int ti=0;ti<16;ti++){
    #pragma unroll
    for (int j=0;j<4;j++)
      kfB[j] = *(const short8*)(kp + (((size_t)b*8 + 4+j)*NHW + trow0 + ti*16)*32 + kbq);
    #pragma unroll
    for (int j=0;j<4;j++)
      sc[ti] = __builtin_amdgcn_mfma_f32_16x16x32_bf16(aq[j], kfA[j], sc[ti], 0,0,0);
    if (ti < 15){
      #pragma unroll
      for (int j=0;j<4;j++)
        kfA[j] = *(const short8*)(kp + (((size_t)b*8 + j)*NHW + trow0 + (ti+1)*16)*32 + kbq);
    }
    #pragma unroll
    for (int j=0;j<4;j++)
      sc[ti] = __builtin_amdgcn_mfma_f32_16x16x32_bf16(aq[4+j], kfB[j], sc[ti], 0,0,0);
  }

  const float scale = 0.0625f;
  float mx[4] = {-1e30f,-1e30f,-1e30f,-1e30f};
  #pragma unroll
  for (int ti=0;ti<16;ti++)
    #pragma unroll
    for (int r=0;r<4;r++){
      float v = sc[ti][r]*scale;
      sc[ti][r] = v;
      mx[r] = fmaxf(mx[r], v);
    }
  #pragma unroll
  for (int o=1;o<16;o<<=1)
    #pragma unroll
    for (int r=0;r<4;r++) mx[r] = fmaxf(mx[r], __shfl_xor(mx[r], o, 64));
  if (lm==0){
    #pragma unroll
    for (int r=0;r<4;r++) redmax[quad*4+r][wave] = mx[r];
  }
  __syncthreads();
  float fm[4];
  #pragma unroll
  for (int r=0;r<4;r++){
    int row = quad*4+r;
    fm[r] = fmaxf(fmaxf(redmax[row][0],redmax[row][1]),
                  fmaxf(redmax[row][2],redmax[row][3]));
  }
  float sm[4] = {0.f,0.f,0.f,0.f};
  #pragma unroll
  for (int ti=0;ti<16;ti++)
    #pragma unroll
    for (int r=0;r<4;r++){
      float e = __expf(sc[ti][r] - fm[r]);
      sc[ti][r] = e;
      sm[r] += e;
    }
  #pragma unroll
  for (int o=1;o<16;o<<=1)
    #pragma unroll
    for (int r=0;r<4;r++) sm[r] += __shfl_xor(sm[r], o, 64);
  if (lm==0){
    #pragma unroll
    for (int r=0;r<4;r++) redsum[quad*4+r][wave] = sm[r];
  }
  __syncthreads();
  float inv[4];
  #pragma unroll
  for (int r=0;r<4;r++){
    int row = quad*4+r;
    inv[r] = 1.f/(redsum[row][0]+redsum[row][1]+redsum[row][2]+redsum[row][3]);
  }
  #pragma unroll
  for (int ti=0;ti<16;ti++)
    #pragma unroll
    for (int r=0;r<4;r++)
      P[quad*4+r][wave*256 + ti*16 + lm] = (short)f2bu(sc[ti][r]*inv[r]);
  __syncthreads();

  floatx4 oacc[4];
  #pragma unroll
  for (int nt=0;nt<4;nt++) oacc[nt] = (floatx4){0.f,0.f,0.f,0.f};
  const int crow = wave*64 + lm;
  short8 vfA[4], vfB[4], pfA, pfB;
  #pragma unroll
  for (int nt=0;nt<4;nt++)
    vfA[nt] = *(const short8*)(vp + (((size_t)b*32 + 0)*NC + crow + nt*16)*32 + quad*8);
  pfA = *(const short8*)(&P[lm][quad*8]);
  #pragma unroll
  for (int kk=0;kk<32;kk++){
    if (kk & 1){
      if (kk < 31){
        #pragma unroll
        for (int nt=0;nt<4;nt++)
          vfA[nt] = *(const short8*)(vp + (((size_t)b*32 + kk+1)*NC + crow + nt*16)*32 + quad*8);
        pfA = *(const short8*)(&P[lm][(kk+1)*32 + quad*8]);
      }
      #pragma unroll
      for (int nt=0;nt<4;nt++)
        oacc[nt] = __builtin_amdgcn_mfma_f32_16x16x32_bf16(pfB, vfB[nt], oacc[nt], 0,0,0);
    } else {
      #pragma unroll
      for (int nt=0;nt<4;nt++)
        vfB[nt] = *(const short8*)(vp + (((size_t)b*32 + kk+1)*NC + crow + nt*16)*32 + quad*8);
      pfB = *(const short8*)(&P[lm][(kk+1)*32 + quad*8]);
      #pragma unroll
      for (int nt=0;nt<4;nt++)
        oacc[nt] = __builtin_amdgcn_mfma_f32_16x16x32_bf16(pfA, vfA[nt], oacc[nt], 0,0,0);
    }
  }
  // packed bf16 epilogue: o_p[b][cc][s][32]
  #pragma unroll
  for (int nt=0;nt<4;nt++){
    int c = wave*64 + nt*16 + lm;
    int cc = c>>5, cl = c&31;
    #pragma unroll
    for (int r=0;r<4;r++){
      int s = s0 + quad*4 + r;
      op[(((size_t)b*8 + cc)*NHW + s)*32 + cl] = (short)f2bu(oacc[nt][r]);
    }
  }
}

// ---------------- MFMA out-proj: out = W@o + out_b + h ----------------
__global__ __launch_bounds__(256)
void outproj_mfma_kernel(const short* __restrict__ op, const short* __restrict__ wop,
                         const float* __restrict__ obias, const float* __restrict__ h,
                         float* __restrict__ out){
  const int b = blockIdx.z;
  const int tid = threadIdx.x, wave = tid>>6, lane = tid&63;
  const int quad = lane>>4, lm = lane&15;
  const int M0 = blockIdx.y*128 + (wave>>1)*64;
  const int N0 = blockIdx.x*128 + (wave&1)*64;
  floatx4 acc[4][4];
  #pragma unroll
  for (int mt=0;mt<4;mt++)
    #pragma unroll
    for (int nt=0;nt<4;nt++) acc[mt][nt] = (floatx4){0.f,0.f,0.f,0.f};
  #pragma unroll
  for (int kk=0;kk<8;kk++){
    short8 af[4], bfr[4];
    #pragma unroll
    for (int mt=0;mt<4;mt++)
      af[mt] = *(const short8*)(wop + ((size_t)kk*256 + M0 + mt*16 + lm)*32 + quad*8);
    #pragma unroll
    for (int nt=0;nt<4;nt++)
      bfr[nt] = *(const short8*)(op + (((size_t)b*8 + kk)*NHW + N0 + nt*16 + lm)*32 + quad*8);
    #pragma unroll
    for (int mt=0;mt<4;mt++)
      #pragma unroll
      for (int nt=0;nt<4;nt++)
        acc[mt][nt] = __builtin_amdgcn_mfma_f32_16x16x32_bf16(af[mt], bfr[nt], acc[mt][nt], 0,0,0);
  }
  #pragma unroll
  for (int mt=0;mt<4;mt++){
    #pragma unroll
    for (int r=0;r<4;r++){
      int co = M0 + mt*16 + quad*4 + r;
      float bb = obias[co];
      size_t ob = ((size_t)b*NC + co)*NHW + N0;
      #pragma unroll
      for (int nt=0;nt<4;nt++){
        size_t oi = ob + nt*16 + lm;
        out[oi] = acc[mt][nt][r] + bb + h[oi];
      }
    }
  }
}

extern "C" void kernel_launch(void* const* d_in, const int* in_sizes, int n_in,
                              void* d_out, int out_size, void* d_ws, size_t ws_size,
                              hipStream_t stream){
  const float* x        = (const float*)d_in[0];
  const float* time_emb = (const float*)d_in[1];
  const float* c_in     = (const float*)d_in[2];
  const float* gn1_g    = (const float*)d_in[3];
  const float* gn1_b    = (const float*)d_in[4];
  const float* conv1_w  = (const float*)d_in[5];
  const float* conv1_b  = (const float*)d_in[6];
  const float* noise_w  = (const float*)d_in[7];
  const float* noise_b  = (const float*)d_in[8];
  const float* gn2_g    = (const float*)d_in[9];
  const float* gn2_b    = (const float*)d_in[10];
  const float* conv2_w  = (const float*)d_in[11];
  const float* conv2_b  = (const float*)d_in[12];
  const float* cfunc_w  = (const float*)d_in[13];
  const float* cfunc_b  = (const float*)d_in[14];
  const float* agn_g    = (const float*)d_in[15];
  const float* agn_b    = (const float*)d_in[16];
  const float* qkv_w    = (const float*)d_in[17];
  const float* out_w    = (const float*)d_in[18];
  const float* out_b    = (const float*)d_in[19];
  float* outp = (float*)d_out;

  // ---- workspace layout (~67 MB) ----
  float* ws = (float*)d_ws;
  float* buf_h = ws;                       // NP fp32
  float* buf_t = buf_h + NP;               // NP fp32 (early: cp bf16 alias; late: o_p bf16 alias)
  short* xpb   = (short*)(buf_t + NP);     // NP bf16
  short* qp    = xpb + NP;                 // NP bf16
  short* kp    = qp + NP;                  // NP bf16
  short* vp    = kp + NP;                  // NP bf16
  short* wp1   = vp + NP;                  // 589824
  short* wp2   = wp1 + 589824;             // 589824
  short* wqp   = wp2 + 589824;             // 196608
  short* wcp   = wqp + 196608;             // 65536
  short* wop   = wcp + 65536;              // 65536
  float* na    = (float*)(wop + 65536);    // NB*NC
  float* st    = na + NB*NC;               // 2048 floats: st2(1024) + st3(1024)
  float* st2   = st;
  float* st3   = st + 1024;
  short* cp    = (short*)buf_t;            // alias (dead after gemm_cfunc)
  short* op    = (short*)buf_t;            // alias (written by attn, after cp is dead)

  // ---- prep ----
  wprep3_kernel<<<512, 256, 0, stream>>>(conv1_w, conv2_w, wp1, wp2, st);
  wprep1_kernel<<<1280, 256, 0, stream>>>(qkv_w, cfunc_w, out_w, wqp, wcp, wop);
  cvtc_kernel<<<dim3(4,8,NB), 256, 0, stream>>>(c_in, cp);
  noise_kernel<<<NB, 256, 0, stream>>>(time_emb, noise_w, noise_b, na);
  // ---- ResnetBlock ----
  gn_t_kernel<true><<<NB*32, 256, 0, stream>>>(x, gn1_g, gn1_b, xpb);
  conv3_mfma_kernel<<<dim3(16, NB), 256, 0, stream>>>(xpb, wp1, conv1_b, na, nullptr, buf_h, st2);
  gn_post_kernel<true><<<NB*32, 256, 0, stream>>>(buf_h, st2, gn2_g, gn2_b, xpb);
  gemm_cfunc_kernel<<<dim3(8,2,NB), 256, 0, stream>>>(cp, wcp, cfunc_b, x, buf_h);
  conv3_mfma_kernel<<<dim3(16, NB), 256, 0, stream>>>(xpb, wp2, conv2_b, nullptr, buf_h, buf_h, st3);
  // ---- Attention ----
  gn_post_kernel<false><<<NB*32, 256, 0, stream>>>(buf_h, st3, agn_g, agn_b, xpb);
  gemm_qkv_kernel<<<dim3(8,6,NB), 256, 0, stream>>>(xpb, wqp, qp, kp, vp);
  attn_mfma_kernel<<<1024, 256, 0, stream>>>(qp, kp, vp, op);
  outproj_mfma_kernel<<<dim3(8,2,NB), 256, 0, stream>>>(op, wop, out_b, buf_h, outp);
}

// Round 8
// 383.668 us; speedup vs baseline: 4.9417x; 1.2437x over previous
//
#include <hip/hip_runtime.h>
#include <hip/hip_bf16.h>
#include <math.h>

typedef __hip_bfloat16 bf16;
typedef short short8 __attribute__((ext_vector_type(8)));
typedef float floatx4 __attribute__((ext_vector_type(4)));

#define NB 16
#define NC 256
#define NHW 1024
#define NNE 256
#define NP (NB*NC*NHW)

__device__ __forceinline__ unsigned short f2bu(float f){
  bf16 h = (bf16)f; return *(unsigned short*)&h;
}

// ---------------- GroupNorm two-pass (+Swish) -> packed bf16 x_p[b][cc][px][32] ----------------
template<bool SWISH>
__global__ void gn_t_kernel(const float* __restrict__ src, const float* __restrict__ gamma,
                            const float* __restrict__ beta, short* __restrict__ xp){
  int b = blockIdx.x >> 5, g = blockIdx.x & 31;
  const int GSZ = 8*NHW;
  size_t base = ((size_t)b*NC + g*8)*NHW;
  int tid = threadIdx.x;
  float s = 0.f, ss = 0.f;
  for (int i = tid; i < GSZ; i += 256){
    float v = src[base+i];
    s += v; ss += v*v;
  }
  __shared__ float rs[256], rq[256];
  rs[tid] = s; rq[tid] = ss;
  __syncthreads();
  for (int off=128; off>0; off>>=1){
    if (tid < off){ rs[tid]+=rs[tid+off]; rq[tid]+=rq[tid+off]; }
    __syncthreads();
  }
  float mean = rs[0] * (1.f/GSZ);
  float var  = rq[0] * (1.f/GSZ) - mean*mean;
  float inv  = rsqrtf(var + 1e-5f);
  float gm[8], bt[8];
  #pragma unroll
  for (int j=0;j<8;j++){ gm[j] = gamma[g*8+j]*inv; bt[j] = beta[g*8+j]; }
  short* dst = xp + (((size_t)b*8 + (g>>2))*NHW)*32 + (g&3)*8;
  for (int px = tid; px < NHW; px += 256){
    short8 pk;
    #pragma unroll
    for (int j=0;j<8;j++){
      float v = (src[base + j*NHW + px] - mean)*gm[j] + bt[j];
      if (SWISH) v = v / (1.f + __expf(-v));
      pk[j] = (short)f2bu(v);
    }
    *(short8*)(dst + (size_t)px*32) = pk;
  }
}

// ---------------- GroupNorm single-pass from precomputed stats ----------------
template<bool SWISH>
__global__ void gn_post_kernel(const float* __restrict__ src, const float* __restrict__ st,
                               const float* __restrict__ gamma, const float* __restrict__ beta,
                               short* __restrict__ xp){
  int b = blockIdx.x >> 5, g = blockIdx.x & 31;
  size_t base = ((size_t)b*NC + g*8)*NHW;
  int tid = threadIdx.x;
  float s  = st[(b*32+g)*2+0];
  float ss = st[(b*32+g)*2+1];
  float mean = s * (1.f/8192.f);
  float var  = ss * (1.f/8192.f) - mean*mean;
  float inv  = rsqrtf(var + 1e-5f);
  float gm[8], bt[8];
  #pragma unroll
  for (int j=0;j<8;j++){ gm[j] = gamma[g*8+j]*inv; bt[j] = beta[g*8+j]; }
  short* dst = xp + (((size_t)b*8 + (g>>2))*NHW)*32 + (g&3)*8;
  for (int px = tid; px < NHW; px += 256){
    short8 pk;
    #pragma unroll
    for (int j=0;j<8;j++){
      float v = (src[base + j*NHW + px] - mean)*gm[j] + bt[j];
      if (SWISH) v = v / (1.f + __expf(-v));
      pk[j] = (short)f2bu(v);
    }
    *(short8*)(dst + (size_t)px*32) = pk;
  }
}

// ---------------- conv3 weight prep + stats zero ----------------
__global__ void wprep3_kernel(const float* __restrict__ w1, const float* __restrict__ w2,
                              short* __restrict__ wp1, short* __restrict__ wp2,
                              float* __restrict__ st){
  int co = blockIdx.x & 255;
  const float* w = (blockIdx.x < 256) ? w1 : w2;
  short* wp = (blockIdx.x < 256) ? wp1 : wp2;
  int tid = threadIdx.x;
  if (blockIdx.x == 0){
    for (int i=tid;i<2048;i+=256) st[i] = 0.f;
  }
  __shared__ float tmp[2304];
  for (int i=tid;i<2304;i+=256) tmp[i] = w[(size_t)co*2304 + i];   // [ci][tap]
  __syncthreads();
  for (int j=tid;j<2304;j+=256){
    int tap = j>>8, ci = j&255;
    wp[(((size_t)tap*8 + (ci>>5))*NC + co)*32 + (ci&31)] = (short)f2bu(tmp[ci*9 + tap]);
  }
}

// ---------------- 1x1 weight prep: qkv(768) + cfunc(256) + outw(256) ----------------
__global__ void wprep1_kernel(const float* __restrict__ wq, const float* __restrict__ wc,
                              const float* __restrict__ wo,
                              short* __restrict__ wqp, short* __restrict__ wcp,
                              short* __restrict__ wop){
  int blk = blockIdx.x, tid = threadIdx.x;
  if (blk < 768){
    float v = wq[(size_t)blk*256 + tid];
    wqp[(((size_t)(tid>>5))*768 + blk)*32 + (tid&31)] = (short)f2bu(v);
  } else if (blk < 1024){
    int co = blk - 768;
    float v = wc[(size_t)co*256 + tid];
    wcp[(((size_t)(tid>>5))*256 + co)*32 + (tid&31)] = (short)f2bu(v);
  } else {
    int co = blk - 1024;
    float v = wo[(size_t)co*256 + tid];
    wop[(((size_t)(tid>>5))*256 + co)*32 + (tid&31)] = (short)f2bu(v);
  }
}

// ---------------- c_in fp32 [b][ci][hw] -> cp[b][cc][px][32] bf16 ----------------
__global__ void cvtc_kernel(const float* __restrict__ c_in, short* __restrict__ cp){
  int pxc = blockIdx.x, cc = blockIdx.y, b = blockIdx.z, tid = threadIdx.x;
  __shared__ float ld[32][257];
  size_t gbase = ((size_t)b*NC + cc*32)*NHW + pxc*256;
  for (int j=0;j<32;j++) ld[j][tid] = c_in[gbase + (size_t)j*NHW + tid];
  __syncthreads();
  short* dst = cp + (((size_t)b*8 + cc)*NHW + pxc*256)*32;
  for (int it=0;it<4;it++){
    int pxl = it*64 + (tid>>2), ckl = tid&3;
    short8 pk;
    #pragma unroll
    for (int e=0;e<8;e++) pk[e] = (short)f2bu(ld[ckl*8+e][pxl]);
    *(short8*)(dst + (size_t)pxl*32 + ckl*8) = pk;
  }
}

// ---------------- FeatureWiseAffine bias: na[b][c] ----------------
__global__ void noise_kernel(const float* __restrict__ emb, const float* __restrict__ w,
                             const float* __restrict__ bias, float* __restrict__ na){
  int b = blockIdx.x, c = threadIdx.x;
  __shared__ float e[NNE];
  e[c] = emb[b*NNE + c];
  __syncthreads();
  float acc = bias[c];
  for (int k=0;k<NNE;k++) acc += e[k]*w[c*NNE+k];
  na[b*NC + c] = acc;
}

// ---------------- MFMA conv3x3, distance-4 software pipeline ----------------
#define XSTR 264
__global__ __launch_bounds__(256,1)
void conv3_mfma_kernel(const short* __restrict__ xp, const short* __restrict__ wp,
                       const float* __restrict__ bias, const float* __restrict__ bias_bc,
                       const float* __restrict__ addf, float* __restrict__ out,
                       float* __restrict__ st){
  const int b = blockIdx.y, y0 = blockIdx.x*2;
  const int tid = threadIdx.x, wave = tid>>6, lane = tid&63;
  const int quad = lane>>4, lm = lane&15;
  __shared__ short Xs[4*34*XSTR];

  { // zero halo columns
    int r = tid>>6, side = (tid>>5)&1, ck = tid&31;
    short8 z = {0,0,0,0,0,0,0,0};
    *(short8*)&Xs[((r*34) + side*33)*XSTR + ck*8] = z;
  }
  for (int it=0; it<16; ++it){
    int idx = it*256 + tid;
    int r = idx>>10, rem = idx&1023;
    int cc = rem>>7, x = (rem>>2)&31, ckl = rem&3;
    int y = y0 - 1 + r;
    short8 v = {0,0,0,0,0,0,0,0};
    if ((unsigned)y < 32u)
      v = *(const short8*)(xp + (((size_t)b*8 + cc)*NHW + y*32 + x)*32 + ckl*8);
    *(short8*)&Xs[(r*34 + x + 1)*XSTR + (cc*4 + ckl)*8] = v;
  }
  __syncthreads();

  floatx4 acc[4][4];
  #pragma unroll
  for (int mt=0;mt<4;mt++)
    #pragma unroll
    for (int nt=0;nt<4;nt++) acc[mt][nt] = (floatx4){0.f,0.f,0.f,0.f};

  const int co_w = wave*64;
  const int aoff = (co_w + lm)*32 + quad*8;

  // j = tap*8 + kk, 0..71. Weight addr collapses to j*NC*32.
  auto ldA = [&](int j, short8 a[4]){
    const short* p = wp + (size_t)j*NC*32 + aoff;
    #pragma unroll
    for (int mt=0;mt<4;mt++) a[mt] = *(const short8*)(p + mt*(16*32));
  };
  auto ldB = [&](int j, short8 bf[4]){
    int tap = j>>3, kk = j&7;
    int dy = (tap*11)>>5;            // tap/3 for tap 0..9
    int dxp = tap - dy*3;
    int base = (lm+dxp)*XSTR + quad*8 + kk*32 + dy*(34*XSTR);
    #pragma unroll
    for (int nt=0;nt<4;nt++)
      bf[nt] = *(const short8*)&Xs[base + (nt>>1)*(34*XSTR) + (nt&1)*(16*XSTR)];
  };

  short8 A[4][4], Bf[4][4];
  ldA(0,A[0]); ldB(0,Bf[0]);
  ldA(1,A[1]); ldB(1,Bf[1]);
  ldA(2,A[2]); ldB(2,Bf[2]);
  ldA(3,A[3]); ldB(3,Bf[3]);
  for (int it=0; it<72; it+=4){
    #pragma unroll
    for (int u=0;u<4;u++){
      #pragma unroll
      for (int mt=0;mt<4;mt++)
        #pragma unroll
        for (int nt=0;nt<4;nt++)
          acc[mt][nt] = __builtin_amdgcn_mfma_f32_16x16x32_bf16(A[u][mt], Bf[u][nt], acc[mt][nt], 0,0,0);
      int j = it + 4 + u; if (j > 71) j = 71;
      ldA(j, A[u]); ldB(j, Bf[u]);
    }
  }

  // epilogue + per-group stats (64 atomics/block)
  const int hw0 = blockIdx.x*64;
  float gs[4], gq[4];
  #pragma unroll
  for (int mt=0;mt<4;mt++){ gs[mt]=0.f; gq[mt]=0.f; }
  #pragma unroll
  for (int mt=0;mt<4;mt++){
    #pragma unroll
    for (int r=0;r<4;r++){
      int co = co_w + mt*16 + quad*4 + r;
      float bb = bias[co] + (bias_bc ? bias_bc[b*NC + co] : 0.f);
      size_t ob = ((size_t)b*NC + co)*NHW + hw0;
      #pragma unroll
      for (int nt=0;nt<4;nt++){
        size_t oi = ob + nt*16 + lm;
        float v = acc[mt][nt][r] + bb;
        if (addf) v += addf[oi];
        out[oi] = v;
        gs[mt] += v; gq[mt] += v*v;
      }
    }
  }
  #pragma unroll
  for (int mt=0;mt<4;mt++){
    float s = gs[mt], q = gq[mt];
    #pragma unroll
    for (int o=1;o<32;o<<=1){ s += __shfl_xor(s, o, 64); q += __shfl_xor(q, o, 64); }
    if ((lane&31) == 0){
      int g = (co_w>>3) + mt*2 + (quad>>1);
      atomicAdd(&st[(b*32+g)*2+0], s);
      atomicAdd(&st[(b*32+g)*2+1], q);
    }
  }
}

// ---------------- MFMA GEMM: cfunc(c) + bias + x -> fp32 [b][co][hw] ----------------
__global__ __launch_bounds__(256)
void gemm_cfunc_kernel(const short* __restrict__ cp, const short* __restrict__ wcp,
                       const float* __restrict__ bias, const float* __restrict__ xres,
                       float* __restrict__ out){
  const int b = blockIdx.z;
  const int tid = threadIdx.x, wave = tid>>6, lane = tid&63;
  const int quad = lane>>4, lm = lane&15;
  const int M0 = blockIdx.y*128 + (wave>>1)*64;
  const int N0 = blockIdx.x*128 + (wave&1)*64;
  floatx4 acc[4][4];
  #pragma unroll
  for (int mt=0;mt<4;mt++)
    #pragma unroll
    for (int nt=0;nt<4;nt++) acc[mt][nt] = (floatx4){0.f,0.f,0.f,0.f};
  #pragma unroll
  for (int kk=0;kk<8;kk++){
    short8 af[4], bfr[4];
    #pragma unroll
    for (int mt=0;mt<4;mt++)
      af[mt] = *(const short8*)(wcp + ((size_t)kk*256 + M0 + mt*16 + lm)*32 + quad*8);
    #pragma unroll
    for (int nt=0;nt<4;nt++)
      bfr[nt] = *(const short8*)(cp + (((size_t)b*8 + kk)*NHW + N0 + nt*16 + lm)*32 + quad*8);
    #pragma unroll
    for (int mt=0;mt<4;mt++)
      #pragma unroll
      for (int nt=0;nt<4;nt++)
        acc[mt][nt] = __builtin_amdgcn_mfma_f32_16x16x32_bf16(af[mt], bfr[nt], acc[mt][nt], 0,0,0);
  }
  #pragma unroll
  for (int mt=0;mt<4;mt++){
    #pragma unroll
    for (int r=0;r<4;r++){
      int co = M0 + mt*16 + quad*4 + r;
      float bb = bias[co];
      size_t ob = ((size_t)b*NC + co)*NHW + N0;
      #pragma unroll
      for (int nt=0;nt<4;nt++){
        size_t oi = ob + nt*16 + lm;
        out[oi] = acc[mt][nt][r] + bb + xres[oi];
      }
    }
  }
}

// ---------------- MFMA GEMM qkv ----------------
__global__ __launch_bounds__(256)
void gemm_qkv_kernel(const short* __restrict__ ntp, const short* __restrict__ wqp,
                     short* __restrict__ qp, short* __restrict__ kp, short* __restrict__ vp){
  const int b = blockIdx.z;
  const int tid = threadIdx.x, wave = tid>>6, lane = tid&63;
  const int quad = lane>>4, lm = lane&15;
  const int M0 = blockIdx.y*128 + (wave>>1)*64;
  const int N0 = blockIdx.x*128 + (wave&1)*64;
  floatx4 acc[4][4];
  #pragma unroll
  for (int mt=0;mt<4;mt++)
    #pragma unroll
    for (int nt=0;nt<4;nt++) acc[mt][nt] = (floatx4){0.f,0.f,0.f,0.f};
  #pragma unroll
  for (int kk=0;kk<8;kk++){
    short8 af[4], bfr[4];
    #pragma unroll
    for (int mt=0;mt<4;mt++)
      af[mt] = *(const short8*)(wqp + ((size_t)kk*768 + M0 + mt*16 + lm)*32 + quad*8);
    #pragma unroll
    for (int nt=0;nt<4;nt++)
      bfr[nt] = *(const short8*)(ntp + (((size_t)b*8 + kk)*NHW + N0 + nt*16 + lm)*32 + quad*8);
    #pragma unroll
    for (int mt=0;mt<4;mt++)
      #pragma unroll
      for (int nt=0;nt<4;nt++)
        acc[mt][nt] = __builtin_amdgcn_mfma_f32_16x16x32_bf16(af[mt], bfr[nt], acc[mt][nt], 0,0,0);
  }
  #pragma unroll
  for (int mt=0;mt<4;mt++){
    int co_base = M0 + mt*16 + quad*4;
    int sec = co_base >> 8;
    int c = co_base & 255;
    #pragma unroll
    for (int nt=0;nt<4;nt++){
      int s = N0 + nt*16 + lm;
      if (sec < 2){
        unsigned short t0 = f2bu(acc[mt][nt][0]), t1 = f2bu(acc[mt][nt][1]);
        unsigned short t2 = f2bu(acc[mt][nt][2]), t3 = f2bu(acc[mt][nt][3]);
        uint2 w2; w2.x = ((unsigned)t1<<16)|t0; w2.y = ((unsigned)t3<<16)|t2;
        short* dst = (sec==0) ? qp : kp;
        *(uint2*)(dst + (((size_t)b*8 + (c>>5))*NHW + s)*32 + (c&31)) = w2;
      } else {
        #pragma unroll
        for (int r=0;r<4;r++)
          vp[(((size_t)b*32 + (s>>5))*NC + c + r)*32 + (s&31)] = (short)f2bu(acc[mt][nt][r]);
      }
    }
  }
}

// ---------------- MFMA fused attention (XCD-swizzled flat grid; packed bf16 out) ----------------
__global__ __launch_bounds__(256)
void attn_mfma_kernel(const short* __restrict__ qp, const short* __restrict__ kp,
                      const short* __restrict__ vp, short* __restrict__ op){
  const int bx = blockIdx.x;
  const int b = bx & 15;
  const int s0 = (bx >> 4) * 16;
  const int tid = threadIdx.x, wave = tid>>6, lane = tid&63;
  const int quad = lane>>4, lm = lane&15;
  __shared__ short P[16][1032];
  __shared__ float redmax[16][4], redsum[16][4];

  short8 aq[8];
  #pragma unroll
  for (int kk=0;kk<8;kk++)
    aq[kk] = *(const short8*)(qp + (((size_t)b*8 + kk)*NHW + s0 + lm)*32 + quad*8);

  floatx4 sc[16];
  #pragma unroll
  for (int ti=0;ti<16;ti++) sc[ti] = (floatx4){0.f,0.f,0.f,0.f};
  const size_t kbq = quad*8;
  const int trow0 = wave*256 + lm;
  short8 kfA[4], kfB[4];
  #pragma unroll
  for (int j=0;j<4;j++)
    kfA[j] = *(const short8*)(kp + (((size_t)b*8 + j)*NHW + trow0)*32 + kbq);
  #pragma unroll
  for (int ti=0;ti<16;ti++){
    #pragma unroll
    for (int j=0;j<4;j++)
      kfB[j] = *(const short8*)(kp + (((size_t)b*8 + 4+j)*NHW + trow0 + ti*16)*32 + kbq);
    #pragma unroll
    for (int j=0;j<4;j++)
      sc[ti] = __builtin_amdgcn_mfma_f32_16x16x32_bf16(aq[j], kfA[j], sc[ti], 0,0,0);
    if (ti < 15){
      #pragma unroll
      for (int j=0;j<4;j++)
        kfA[j] = *(const short8*)(kp + (((size_t)b*8 + j)*NHW + trow0 + (ti+1)*16)*32 + kbq);
    }
    #pragma unroll
    for (int j=0;j<4;j++)
      sc[ti] = __builtin_amdgcn_mfma_f32_16x16x32_bf16(aq[4+j], kfB[j], sc[ti], 0,0,0);
  }

  const float scale = 0.0625f;
  float mx[4] = {-1e30f,-1e30f,-1e30f,-1e30f};
  #pragma unroll
  for (int ti=0;ti<16;ti++)
    #pragma unroll
    for (int r=0;r<4;r++){
      float v = sc[ti][r]*scale;
      sc[ti][r] = v;
      mx[r] = fmaxf(mx[r], v);
    }
  #pragma unroll
  for (int o=1;o<16;o<<=1)
    #pragma unroll
    for (int r=0;r<4;r++) mx[r] = fmaxf(mx[r], __shfl_xor(mx[r], o, 64));
  if (lm==0){
    #pragma unroll
    for (int r=0;r<4;r++) redmax[quad*4+r][wave] = mx[r];
  }
  __syncthreads();
  float fm[4];
  #pragma unroll
  for (int r=0;r<4;r++){
    int row = quad*4+r;
    fm[r] = fmaxf(fmaxf(redmax[row][0],redmax[row][1]),
                  fmaxf(redmax[row][2],redmax[row][3]));
  }
  float sm[4] = {0.f,0.f,0.f,0.f};
  #pragma unroll
  for (int ti=0;ti<16;ti++)
    #pragma unroll
    for (int r=0;r<4;r++){
      float e = __expf(sc[ti][r] - fm[r]);
      sc[ti][r] = e;
      sm[r] += e;
    }
  #pragma unroll
  for (int o=1;o<16;o<<=1)
    #pragma unroll
    for (int r=0;r<4;r++) sm[r] += __shfl_xor(sm[r], o, 64);
  if (lm==0){
    #pragma unroll
    for (int r=0;r<4;r++) redsum[quad*4+r][wave] = sm[r];
  }
  __syncthreads();
  float inv[4];
  #pragma unroll
  for (int r=0;r<4;r++){
    int row = quad*4+r;
    inv[r] = 1.f/(redsum[row][0]+redsum[row][1]+redsum[row][2]+redsum[row][3]);
  }
  #pragma unroll
  for (int ti=0;ti<16;ti++)
    #pragma unroll
    for (int r=0;r<4;r++)
      P[quad*4+r][wave*256 + ti*16 + lm] = (short)f2bu(sc[ti][r]*inv[r]);
  __syncthreads();

  floatx4 oacc[4];
  #pragma unroll
  for (int nt=0;nt<4;nt++) oacc[nt] = (floatx4){0.f,0.f,0.f,0.f};
  const int crow = wave*64 + lm;
  short8 vfA[4], vfB[4], pfA, pfB;
  #pragma unroll
  for (int nt=0;nt<4;nt++)
    vfA[nt] = *(const short8*)(vp + (((size_t)b*32 + 0)*NC + crow + nt*16)*32 + quad*8);
  pfA = *(const short8*)(&P[lm][quad*8]);
  #pragma unroll
  for (int kk=0;kk<32;kk++){
    if (kk & 1){
      if (kk < 31){
        #pragma unroll
        for (int nt=0;nt<4;nt++)
          vfA[nt] = *(const short8*)(vp + (((size_t)b*32 + kk+1)*NC + crow + nt*16)*32 + quad*8);
        pfA = *(const short8*)(&P[lm][(kk+1)*32 + quad*8]);
      }
      #pragma unroll
      for (int nt=0;nt<4;nt++)
        oacc[nt] = __builtin_amdgcn_mfma_f32_16x16x32_bf16(pfB, vfB[nt], oacc[nt], 0,0,0);
    } else {
      #pragma unroll
      for (int nt=0;nt<4;nt++)
        vfB[nt] = *(const short8*)(vp + (((size_t)b*32 + kk+1)*NC + crow + nt*16)*32 + quad*8);
      pfB = *(const short8*)(&P[lm][(kk+1)*32 + quad*8]);
      #pragma unroll
      for (int nt=0;nt<4;nt++)
        oacc[nt] = __builtin_amdgcn_mfma_f32_16x16x32_bf16(pfA, vfA[nt], oacc[nt], 0,0,0);
    }
  }
  #pragma unroll
  for (int nt=0;nt<4;nt++){
    int c = wave*64 + nt*16 + lm;
    int cc = c>>5, cl = c&31;
    #pragma unroll
    for (int r=0;r<4;r++){
      int s = s0 + quad*4 + r;
      op[(((size_t)b*8 + cc)*NHW + s)*32 + cl] = (short)f2bu(oacc[nt][r]);
    }
  }
}

// ---------------- MFMA out-proj: out = W@o + out_b + h ----------------
__global__ __launch_bounds__(256)
void outproj_mfma_kernel(const short* __restrict__ op, const short* __restrict__ wop,
                         const float* __restrict__ obias, const float* __restrict__ h,
                         float* __restrict__ out){
  const int b = blockIdx.z;
  const int tid = threadIdx.x, wave = tid>>6, lane = tid&63;
  const int quad = lane>>4, lm = lane&15;
  const int M0 = blockIdx.y*128 + (wave>>1)*64;
  const int N0 = blockIdx.x*128 + (wave&1)*64;
  floatx4 acc[4][4];
  #pragma unroll
  for (int mt=0;mt<4;mt++)
    #pragma unroll
    for (int nt=0;nt<4;nt++) acc[mt][nt] = (floatx4){0.f,0.f,0.f,0.f};
  #pragma unroll
  for (int kk=0;kk<8;kk++){
    short8 af[4], bfr[4];
    #pragma unroll
    for (int mt=0;mt<4;mt++)
      af[mt] = *(const short8*)(wop + ((size_t)kk*256 + M0 + mt*16 + lm)*32 + quad*8);
    #pragma unroll
    for (int nt=0;nt<4;nt++)
      bfr[nt] = *(const short8*)(op + (((size_t)b*8 + kk)*NHW + N0 + nt*16 + lm)*32 + quad*8);
    #pragma unroll
    for (int mt=0;mt<4;mt++)
      #pragma unroll
      for (int nt=0;nt<4;nt++)
        acc[mt][nt] = __builtin_amdgcn_mfma_f32_16x16x32_bf16(af[mt], bfr[nt], acc[mt][nt], 0,0,0);
  }
  #pragma unroll
  for (int mt=0;mt<4;mt++){
    #pragma unroll
    for (int r=0;r<4;r++){
      int co = M0 + mt*16 + quad*4 + r;
      float bb = obias[co];
      size_t ob = ((size_t)b*NC + co)*NHW + N0;
      #pragma unroll
      for (int nt=0;nt<4;nt++){
        size_t oi = ob + nt*16 + lm;
        out[oi] = acc[mt][nt][r] + bb + h[oi];
      }
    }
  }
}

extern "C" void kernel_launch(void* const* d_in, const int* in_sizes, int n_in,
                              void* d_out, int out_size, void* d_ws, size_t ws_size,
                              hipStream_t stream){
  const float* x        = (const float*)d_in[0];
  const float* time_emb = (const float*)d_in[1];
  const float* c_in     = (const float*)d_in[2];
  const float* gn1_g    = (const float*)d_in[3];
  const float* gn1_b    = (const float*)d_in[4];
  const float* conv1_w  = (const float*)d_in[5];
  const float* conv1_b  = (const float*)d_in[6];
  const float* noise_w  = (const float*)d_in[7];
  const float* noise_b  = (const float*)d_in[8];
  const float* gn2_g    = (const float*)d_in[9];
  const float* gn2_b    = (const float*)d_in[10];
  const float* conv2_w  = (const float*)d_in[11];
  const float* conv2_b  = (const float*)d_in[12];
  const float* cfunc_w  = (const float*)d_in[13];
  const float* cfunc_b  = (const float*)d_in[14];
  const float* agn_g    = (const float*)d_in[15];
  const float* agn_b    = (const float*)d_in[16];
  const float* qkv_w    = (const float*)d_in[17];
  const float* out_w    = (const float*)d_in[18];
  const float* out_b    = (const float*)d_in[19];
  float* outp = (float*)d_out;

  // ---- workspace layout (~67 MB) ----
  float* ws = (float*)d_ws;
  float* buf_h = ws;                       // NP fp32
  float* buf_t = buf_h + NP;               // NP fp32 (early: cp bf16 alias; late: o_p bf16 alias)
  short* xpb   = (short*)(buf_t + NP);     // NP bf16
  short* qp    = xpb + NP;                 // NP bf16
  short* kp    = qp + NP;                  // NP bf16
  short* vp    = kp + NP;                  // NP bf16
  short* wp1   = vp + NP;                  // 589824
  short* wp2   = wp1 + 589824;             // 589824
  short* wqp   = wp2 + 589824;             // 196608
  short* wcp   = wqp + 196608;             // 65536
  short* wop   = wcp + 65536;              // 65536
  float* na    = (float*)(wop + 65536);    // NB*NC
  float* st    = na + NB*NC;               // 2048 floats
  float* st2   = st;
  float* st3   = st + 1024;
  short* cp    = (short*)buf_t;            // alias (dead after gemm_cfunc)
  short* op    = (short*)buf_t;            // alias (written by attn after cp dead)

  // ---- prep ----
  wprep3_kernel<<<512, 256, 0, stream>>>(conv1_w, conv2_w, wp1, wp2, st);
  wprep1_kernel<<<1280, 256, 0, stream>>>(qkv_w, cfunc_w, out_w, wqp, wcp, wop);
  cvtc_kernel<<<dim3(4,8,NB), 256, 0, stream>>>(c_in, cp);
  noise_kernel<<<NB, 256, 0, stream>>>(time_emb, noise_w, noise_b, na);
  // ---- ResnetBlock ----
  gn_t_kernel<true><<<NB*32, 256, 0, stream>>>(x, gn1_g, gn1_b, xpb);
  conv3_mfma_kernel<<<dim3(16, NB), 256, 0, stream>>>(xpb, wp1, conv1_b, na, nullptr, buf_h, st2);
  gn_post_kernel<true><<<NB*32, 256, 0, stream>>>(buf_h, st2, gn2_g, gn2_b, xpb);
  gemm_cfunc_kernel<<<dim3(8,2,NB), 256, 0, stream>>>(cp, wcp, cfunc_b, x, buf_h);
  conv3_mfma_kernel<<<dim3(16, NB), 256, 0, stream>>>(xpb, wp2, conv2_b, nullptr, buf_h, buf_h, st3);
  // ---- Attention ----
  gn_post_kernel<false><<<NB*32, 256, 0, stream>>>(buf_h, st3, agn_g, agn_b, xpb);
  gemm_qkv_kernel<<<dim3(8,6,NB), 256, 0, stream>>>(xpb, wqp, qp, kp, vp);
  attn_mfma_kernel<<<1024, 256, 0, stream>>>(qp, kp, vp, op);
  outproj_mfma_kernel<<<dim3(8,2,NB), 256, 0, stream>>>(op, wop, out_b, buf_h, outp);
}

// Round 9
// 375.493 us; speedup vs baseline: 5.0492x; 1.0218x over previous
//
#include <hip/hip_runtime.h>
#include <hip/hip_bf16.h>
#include <math.h>

typedef __hip_bfloat16 bf16;
typedef short short8 __attribute__((ext_vector_type(8)));
typedef float floatx4 __attribute__((ext_vector_type(4)));

#define NB 16
#define NC 256
#define NHW 1024
#define NNE 256
#define NP (NB*NC*NHW)

__device__ __forceinline__ unsigned short f2bu(float f){
  bf16 h = (bf16)f; return *(unsigned short*)&h;
}

// ---------------- GroupNorm two-pass (+Swish) -> packed bf16 x_p[b][cc][px][32] ----------------
template<bool SWISH>
__global__ void gn_t_kernel(const float* __restrict__ src, const float* __restrict__ gamma,
                            const float* __restrict__ beta, short* __restrict__ xp){
  int b = blockIdx.x >> 5, g = blockIdx.x & 31;
  const int GSZ = 8*NHW;
  size_t base = ((size_t)b*NC + g*8)*NHW;
  int tid = threadIdx.x;
  float s = 0.f, ss = 0.f;
  for (int i = tid; i < GSZ; i += 256){
    float v = src[base+i];
    s += v; ss += v*v;
  }
  __shared__ float rs[256], rq[256];
  rs[tid] = s; rq[tid] = ss;
  __syncthreads();
  for (int off=128; off>0; off>>=1){
    if (tid < off){ rs[tid]+=rs[tid+off]; rq[tid]+=rq[tid+off]; }
    __syncthreads();
  }
  float mean = rs[0] * (1.f/GSZ);
  float var  = rq[0] * (1.f/GSZ) - mean*mean;
  float inv  = rsqrtf(var + 1e-5f);
  float gm[8], bt[8];
  #pragma unroll
  for (int j=0;j<8;j++){ gm[j] = gamma[g*8+j]*inv; bt[j] = beta[g*8+j]; }
  short* dst = xp + (((size_t)b*8 + (g>>2))*NHW)*32 + (g&3)*8;
  for (int px = tid; px < NHW; px += 256){
    short8 pk;
    #pragma unroll
    for (int j=0;j<8;j++){
      float v = (src[base + j*NHW + px] - mean)*gm[j] + bt[j];
      if (SWISH) v = v / (1.f + __expf(-v));
      pk[j] = (short)f2bu(v);
    }
    *(short8*)(dst + (size_t)px*32) = pk;
  }
}

// ---------------- GroupNorm single-pass from precomputed stats ----------------
template<bool SWISH>
__global__ void gn_post_kernel(const float* __restrict__ src, const float* __restrict__ st,
                               const float* __restrict__ gamma, const float* __restrict__ beta,
                               short* __restrict__ xp){
  int b = blockIdx.x >> 5, g = blockIdx.x & 31;
  size_t base = ((size_t)b*NC + g*8)*NHW;
  int tid = threadIdx.x;
  float s  = st[(b*32+g)*2+0];
  float ss = st[(b*32+g)*2+1];
  float mean = s * (1.f/8192.f);
  float var  = ss * (1.f/8192.f) - mean*mean;
  float inv  = rsqrtf(var + 1e-5f);
  float gm[8], bt[8];
  #pragma unroll
  for (int j=0;j<8;j++){ gm[j] = gamma[g*8+j]*inv; bt[j] = beta[g*8+j]; }
  short* dst = xp + (((size_t)b*8 + (g>>2))*NHW)*32 + (g&3)*8;
  for (int px = tid; px < NHW; px += 256){
    short8 pk;
    #pragma unroll
    for (int j=0;j<8;j++){
      float v = (src[base + j*NHW + px] - mean)*gm[j] + bt[j];
      if (SWISH) v = v / (1.f + __expf(-v));
      pk[j] = (short)f2bu(v);
    }
    *(short8*)(dst + (size_t)px*32) = pk;
  }
}

// ---------------- conv3 weight prep + stats zero ----------------
__global__ void wprep3_kernel(const float* __restrict__ w1, const float* __restrict__ w2,
                              short* __restrict__ wp1, short* __restrict__ wp2,
                              float* __restrict__ st){
  int co = blockIdx.x & 255;
  const float* w = (blockIdx.x < 256) ? w1 : w2;
  short* wp = (blockIdx.x < 256) ? wp1 : wp2;
  int tid = threadIdx.x;
  if (blockIdx.x == 0){
    for (int i=tid;i<2048;i+=256) st[i] = 0.f;
  }
  __shared__ float tmp[2304];
  for (int i=tid;i<2304;i+=256) tmp[i] = w[(size_t)co*2304 + i];   // [ci][tap]
  __syncthreads();
  for (int j=tid;j<2304;j+=256){
    int tap = j>>8, ci = j&255;
    wp[(((size_t)tap*8 + (ci>>5))*NC + co)*32 + (ci&31)] = (short)f2bu(tmp[ci*9 + tap]);
  }
}

// ---------------- 1x1 weight prep: qkv(768) + cfunc(256) + outw(256) ----------------
__global__ void wprep1_kernel(const float* __restrict__ wq, const float* __restrict__ wc,
                              const float* __restrict__ wo,
                              short* __restrict__ wqp, short* __restrict__ wcp,
                              short* __restrict__ wop){
  int blk = blockIdx.x, tid = threadIdx.x;
  if (blk < 768){
    float v = wq[(size_t)blk*256 + tid];
    wqp[(((size_t)(tid>>5))*768 + blk)*32 + (tid&31)] = (short)f2bu(v);
  } else if (blk < 1024){
    int co = blk - 768;
    float v = wc[(size_t)co*256 + tid];
    wcp[(((size_t)(tid>>5))*256 + co)*32 + (tid&31)] = (short)f2bu(v);
  } else {
    int co = blk - 1024;
    float v = wo[(size_t)co*256 + tid];
    wop[(((size_t)(tid>>5))*256 + co)*32 + (tid&31)] = (short)f2bu(v);
  }
}

// ---------------- c_in fp32 [b][ci][hw] -> cp[b][cc][px][32] bf16 ----------------
__global__ void cvtc_kernel(const float* __restrict__ c_in, short* __restrict__ cp){
  int pxc = blockIdx.x, cc = blockIdx.y, b = blockIdx.z, tid = threadIdx.x;
  __shared__ float ld[32][257];
  size_t gbase = ((size_t)b*NC + cc*32)*NHW + pxc*256;
  for (int j=0;j<32;j++) ld[j][tid] = c_in[gbase + (size_t)j*NHW + tid];
  __syncthreads();
  short* dst = cp + (((size_t)b*8 + cc)*NHW + pxc*256)*32;
  for (int it=0;it<4;it++){
    int pxl = it*64 + (tid>>2), ckl = tid&3;
    short8 pk;
    #pragma unroll
    for (int e=0;e<8;e++) pk[e] = (short)f2bu(ld[ckl*8+e][pxl]);
    *(short8*)(dst + (size_t)pxl*32 + ckl*8) = pk;
  }
}

// ---------------- FeatureWiseAffine bias: na[b][c] ----------------
__global__ void noise_kernel(const float* __restrict__ emb, const float* __restrict__ w,
                             const float* __restrict__ bias, float* __restrict__ na){
  int b = blockIdx.x, c = threadIdx.x;
  __shared__ float e[NNE];
  e[c] = emb[b*NNE + c];
  __syncthreads();
  float acc = bias[c];
  for (int k=0;k<NNE;k++) acc += e[k]*w[c*NNE+k];
  na[b*NC + c] = acc;
}

// ---------------- MFMA conv3x3, distance-4 software pipeline ----------------
#define XSTR 264
__global__ __launch_bounds__(256,1)
void conv3_mfma_kernel(const short* __restrict__ xp, const short* __restrict__ wp,
                       const float* __restrict__ bias, const float* __restrict__ bias_bc,
                       const float* __restrict__ addf, float* __restrict__ out,
                       float* __restrict__ st){
  const int b = blockIdx.y, y0 = blockIdx.x*2;
  const int tid = threadIdx.x, wave = tid>>6, lane = tid&63;
  const int quad = lane>>4, lm = lane&15;
  __shared__ short Xs[4*34*XSTR];

  { // zero halo columns
    int r = tid>>6, side = (tid>>5)&1, ck = tid&31;
    short8 z = {0,0,0,0,0,0,0,0};
    *(short8*)&Xs[((r*34) + side*33)*XSTR + ck*8] = z;
  }
  for (int it=0; it<16; ++it){
    int idx = it*256 + tid;
    int r = idx>>10, rem = idx&1023;
    int cc = rem>>7, x = (rem>>2)&31, ckl = rem&3;
    int y = y0 - 1 + r;
    short8 v = {0,0,0,0,0,0,0,0};
    if ((unsigned)y < 32u)
      v = *(const short8*)(xp + (((size_t)b*8 + cc)*NHW + y*32 + x)*32 + ckl*8);
    *(short8*)&Xs[(r*34 + x + 1)*XSTR + (cc*4 + ckl)*8] = v;
  }
  __syncthreads();

  floatx4 acc[4][4];
  #pragma unroll
  for (int mt=0;mt<4;mt++)
    #pragma unroll
    for (int nt=0;nt<4;nt++) acc[mt][nt] = (floatx4){0.f,0.f,0.f,0.f};

  const int co_w = wave*64;
  const int aoff = (co_w + lm)*32 + quad*8;

  auto ldA = [&](int j, short8 a[4]){
    const short* p = wp + (size_t)j*NC*32 + aoff;
    #pragma unroll
    for (int mt=0;mt<4;mt++) a[mt] = *(const short8*)(p + mt*(16*32));
  };
  auto ldB = [&](int j, short8 bf[4]){
    int tap = j>>3, kk = j&7;
    int dy = (tap*11)>>5;
    int dxp = tap - dy*3;
    int base = (lm+dxp)*XSTR + quad*8 + kk*32 + dy*(34*XSTR);
    #pragma unroll
    for (int nt=0;nt<4;nt++)
      bf[nt] = *(const short8*)&Xs[base + (nt>>1)*(34*XSTR) + (nt&1)*(16*XSTR)];
  };

  short8 A[4][4], Bf[4][4];
  ldA(0,A[0]); ldB(0,Bf[0]);
  ldA(1,A[1]); ldB(1,Bf[1]);
  ldA(2,A[2]); ldB(2,Bf[2]);
  ldA(3,A[3]); ldB(3,Bf[3]);
  for (int it=0; it<72; it+=4){
    #pragma unroll
    for (int u=0;u<4;u++){
      #pragma unroll
      for (int mt=0;mt<4;mt++)
        #pragma unroll
        for (int nt=0;nt<4;nt++)
          acc[mt][nt] = __builtin_amdgcn_mfma_f32_16x16x32_bf16(A[u][mt], Bf[u][nt], acc[mt][nt], 0,0,0);
      int j = it + 4 + u; if (j > 71) j = 71;
      ldA(j, A[u]); ldB(j, Bf[u]);
    }
  }

  const int hw0 = blockIdx.x*64;
  float gs[4], gq[4];
  #pragma unroll
  for (int mt=0;mt<4;mt++){ gs[mt]=0.f; gq[mt]=0.f; }
  #pragma unroll
  for (int mt=0;mt<4;mt++){
    #pragma unroll
    for (int r=0;r<4;r++){
      int co = co_w + mt*16 + quad*4 + r;
      float bb = bias[co] + (bias_bc ? bias_bc[b*NC + co] : 0.f);
      size_t ob = ((size_t)b*NC + co)*NHW + hw0;
      #pragma unroll
      for (int nt=0;nt<4;nt++){
        size_t oi = ob + nt*16 + lm;
        float v = acc[mt][nt][r] + bb;
        if (addf) v += addf[oi];
        out[oi] = v;
        gs[mt] += v; gq[mt] += v*v;
      }
    }
  }
  #pragma unroll
  for (int mt=0;mt<4;mt++){
    float s = gs[mt], q = gq[mt];
    #pragma unroll
    for (int o=1;o<32;o<<=1){ s += __shfl_xor(s, o, 64); q += __shfl_xor(q, o, 64); }
    if ((lane&31) == 0){
      int g = (co_w>>3) + mt*2 + (quad>>1);
      atomicAdd(&st[(b*32+g)*2+0], s);
      atomicAdd(&st[(b*32+g)*2+1], q);
    }
  }
}

// ---------------- MFMA GEMM: cfunc(c) + bias + x -> fp32 [b][co][hw] ----------------
__global__ __launch_bounds__(256)
void gemm_cfunc_kernel(const short* __restrict__ cp, const short* __restrict__ wcp,
                       const float* __restrict__ bias, const float* __restrict__ xres,
                       float* __restrict__ out){
  const int b = blockIdx.z;
  const int tid = threadIdx.x, wave = tid>>6, lane = tid&63;
  const int quad = lane>>4, lm = lane&15;
  const int M0 = blockIdx.y*128 + (wave>>1)*64;
  const int N0 = blockIdx.x*128 + (wave&1)*64;
  floatx4 acc[4][4];
  #pragma unroll
  for (int mt=0;mt<4;mt++)
    #pragma unroll
    for (int nt=0;nt<4;nt++) acc[mt][nt] = (floatx4){0.f,0.f,0.f,0.f};
  #pragma unroll
  for (int kk=0;kk<8;kk++){
    short8 af[4], bfr[4];
    #pragma unroll
    for (int mt=0;mt<4;mt++)
      af[mt] = *(const short8*)(wcp + ((size_t)kk*256 + M0 + mt*16 + lm)*32 + quad*8);
    #pragma unroll
    for (int nt=0;nt<4;nt++)
      bfr[nt] = *(const short8*)(cp + (((size_t)b*8 + kk)*NHW + N0 + nt*16 + lm)*32 + quad*8);
    #pragma unroll
    for (int mt=0;mt<4;mt++)
      #pragma unroll
      for (int nt=0;nt<4;nt++)
        acc[mt][nt] = __builtin_amdgcn_mfma_f32_16x16x32_bf16(af[mt], bfr[nt], acc[mt][nt], 0,0,0);
  }
  #pragma unroll
  for (int mt=0;mt<4;mt++){
    #pragma unroll
    for (int r=0;r<4;r++){
      int co = M0 + mt*16 + quad*4 + r;
      float bb = bias[co];
      size_t ob = ((size_t)b*NC + co)*NHW + N0;
      #pragma unroll
      for (int nt=0;nt<4;nt++){
        size_t oi = ob + nt*16 + lm;
        out[oi] = acc[mt][nt][r] + bb + xres[oi];
      }
    }
  }
}

// ---------------- MFMA GEMM qkv ----------------
__global__ __launch_bounds__(256)
void gemm_qkv_kernel(const short* __restrict__ ntp, const short* __restrict__ wqp,
                     short* __restrict__ qp, short* __restrict__ kp, short* __restrict__ vp){
  const int b = blockIdx.z;
  const int tid = threadIdx.x, wave = tid>>6, lane = tid&63;
  const int quad = lane>>4, lm = lane&15;
  const int M0 = blockIdx.y*128 + (wave>>1)*64;
  const int N0 = blockIdx.x*128 + (wave&1)*64;
  floatx4 acc[4][4];
  #pragma unroll
  for (int mt=0;mt<4;mt++)
    #pragma unroll
    for (int nt=0;nt<4;nt++) acc[mt][nt] = (floatx4){0.f,0.f,0.f,0.f};
  #pragma unroll
  for (int kk=0;kk<8;kk++){
    short8 af[4], bfr[4];
    #pragma unroll
    for (int mt=0;mt<4;mt++)
      af[mt] = *(const short8*)(wqp + ((size_t)kk*768 + M0 + mt*16 + lm)*32 + quad*8);
    #pragma unroll
    for (int nt=0;nt<4;nt++)
      bfr[nt] = *(const short8*)(ntp + (((size_t)b*8 + kk)*NHW + N0 + nt*16 + lm)*32 + quad*8);
    #pragma unroll
    for (int mt=0;mt<4;mt++)
      #pragma unroll
      for (int nt=0;nt<4;nt++)
        acc[mt][nt] = __builtin_amdgcn_mfma_f32_16x16x32_bf16(af[mt], bfr[nt], acc[mt][nt], 0,0,0);
  }
  #pragma unroll
  for (int mt=0;mt<4;mt++){
    int co_base = M0 + mt*16 + quad*4;
    int sec = co_base >> 8;
    int c = co_base & 255;
    #pragma unroll
    for (int nt=0;nt<4;nt++){
      int s = N0 + nt*16 + lm;
      if (sec < 2){
        unsigned short t0 = f2bu(acc[mt][nt][0]), t1 = f2bu(acc[mt][nt][1]);
        unsigned short t2 = f2bu(acc[mt][nt][2]), t3 = f2bu(acc[mt][nt][3]);
        uint2 w2; w2.x = ((unsigned)t1<<16)|t0; w2.y = ((unsigned)t3<<16)|t2;
        short* dst = (sec==0) ? qp : kp;
        *(uint2*)(dst + (((size_t)b*8 + (c>>5))*NHW + s)*32 + (c&31)) = w2;
      } else {
        #pragma unroll
        for (int r=0;r<4;r++)
          vp[(((size_t)b*32 + (s>>5))*NC + c + r)*32 + (s&31)] = (short)f2bu(acc[mt][nt][r]);
      }
    }
  }
}

// ---------------- MFMA fused attention: depth-3 register pipelines both phases ----------------
__global__ __launch_bounds__(256)
void attn_mfma_kernel(const short* __restrict__ qp, const short* __restrict__ kp,
                      const short* __restrict__ vp, short* __restrict__ op){
  const int bx = blockIdx.x;
  const int b = bx & 15;               // XCD swizzle: batches {b,b+8} share an XCD's L2
  const int s0 = (bx >> 4) * 16;
  const int tid = threadIdx.x, wave = tid>>6, lane = tid&63;
  const int quad = lane>>4, lm = lane&15;
  __shared__ short P[16][1032];
  __shared__ float redmax[16][4], redsum[16][4];

  short8 aq[8];
  #pragma unroll
  for (int kk=0;kk<8;kk++)
    aq[kk] = *(const short8*)(qp + (((size_t)b*8 + kk)*NHW + s0 + lm)*32 + quad*8);

  floatx4 sc[16];
  #pragma unroll
  for (int ti=0;ti<16;ti++) sc[ti] = (floatx4){0.f,0.f,0.f,0.f};

  // phase 1: 32 groups g = ti*2 + h; frag = K[t=trow0+ti*16][ch=(h*4+j)*32+quad*8]
  const int trow0 = wave*256 + lm;
  short8 kf[3][4];
  #pragma unroll
  for (int g=0;g<3;g++)
    #pragma unroll
    for (int j=0;j<4;j++)
      kf[g][j] = *(const short8*)(kp + (((size_t)b*8 + (g&1)*4 + j)*NHW + trow0 + (g>>1)*16)*32 + quad*8);
  #pragma unroll
  for (int g=0;g<32;g++){
    const int u = g%3, ti = g>>1, h = g&1;
    #pragma unroll
    for (int j=0;j<4;j++)
      sc[ti] = __builtin_amdgcn_mfma_f32_16x16x32_bf16(aq[h*4+j], kf[u][j], sc[ti], 0,0,0);
    if (g < 29){
      const int gn = g+3, tin = gn>>1, hn = gn&1;
      #pragma unroll
      for (int j=0;j<4;j++)
        kf[u][j] = *(const short8*)(kp + (((size_t)b*8 + hn*4 + j)*NHW + trow0 + tin*16)*32 + quad*8);
    }
  }

  const float scale = 0.0625f;
  float mx[4] = {-1e30f,-1e30f,-1e30f,-1e30f};
  #pragma unroll
  for (int ti=0;ti<16;ti++)
    #pragma unroll
    for (int r=0;r<4;r++){
      float v = sc[ti][r]*scale;
      sc[ti][r] = v;
      mx[r] = fmaxf(mx[r], v);
    }
  #pragma unroll
  for (int o=1;o<16;o<<=1)
    #pragma unroll
    for (int r=0;r<4;r++) mx[r] = fmaxf(mx[r], __shfl_xor(mx[r], o, 64));
  if (lm==0){
    #pragma unroll
    for (int r=0;r<4;r++) redmax[quad*4+r][wave] = mx[r];
  }
  __syncthreads();
  float fm[4];
  #pragma unroll
  for (int r=0;r<4;r++){
    int row = quad*4+r;
    fm[r] = fmaxf(fmaxf(redmax[row][0],redmax[row][1]),
                  fmaxf(redmax[row][2],redmax[row][3]));
  }
  float sm[4] = {0.f,0.f,0.f,0.f};
  #pragma unroll
  for (int ti=0;ti<16;ti++)
    #pragma unroll
    for (int r=0;r<4;r++){
      float e = __expf(sc[ti][r] - fm[r]);
      sc[ti][r] = e;
      sm[r] += e;
    }
  #pragma unroll
  for (int o=1;o<16;o<<=1)
    #pragma unroll
    for (int r=0;r<4;r++) sm[r] += __shfl_xor(sm[r], o, 64);
  if (lm==0){
    #pragma unroll
    for (int r=0;r<4;r++) redsum[quad*4+r][wave] = sm[r];
  }
  __syncthreads();
  float inv[4];
  #pragma unroll
  for (int r=0;r<4;r++){
    int row = quad*4+r;
    inv[r] = 1.f/(redsum[row][0]+redsum[row][1]+redsum[row][2]+redsum[row][3]);
  }
  #pragma unroll
  for (int ti=0;ti<16;ti++)
    #pragma unroll
    for (int r=0;r<4;r++)
      P[quad*4+r][wave*256 + ti*16 + lm] = (short)f2bu(sc[ti][r]*inv[r]);
  __syncthreads();

  // phase 2: 32 steps kk; depth-3 pipeline over (P-frag, 4 V-frags)
  floatx4 oacc[4];
  #pragma unroll
  for (int nt=0;nt<4;nt++) oacc[nt] = (floatx4){0.f,0.f,0.f,0.f};
  const int crow = wave*64 + lm;
  short8 vf[3][4], pf[3];
  #pragma unroll
  for (int u=0;u<3;u++){
    pf[u] = *(const short8*)(&P[lm][u*32 + quad*8]);
    #pragma unroll
    for (int nt=0;nt<4;nt++)
      vf[u][nt] = *(const short8*)(vp + (((size_t)b*32 + u)*NC + crow + nt*16)*32 + quad*8);
  }
  #pragma unroll
  for (int kk=0;kk<32;kk++){
    const int u = kk%3;
    #pragma unroll
    for (int nt=0;nt<4;nt++)
      oacc[nt] = __builtin_amdgcn_mfma_f32_16x16x32_bf16(pf[u], vf[u][nt], oacc[nt], 0,0,0);
    if (kk < 29){
      pf[u] = *(const short8*)(&P[lm][(kk+3)*32 + quad*8]);
      #pragma unroll
      for (int nt=0;nt<4;nt++)
        vf[u][nt] = *(const short8*)(vp + (((size_t)b*32 + kk+3)*NC + crow + nt*16)*32 + quad*8);
    }
  }
  // packed bf16 epilogue: o_p[b][cc][s][32]
  #pragma unroll
  for (int nt=0;nt<4;nt++){
    int c = wave*64 + nt*16 + lm;
    int cc = c>>5, cl = c&31;
    #pragma unroll
    for (int r=0;r<4;r++){
      int s = s0 + quad*4 + r;
      op[(((size_t)b*8 + cc)*NHW + s)*32 + cl] = (short)f2bu(oacc[nt][r]);
    }
  }
}

// ---------------- MFMA out-proj: out = W@o + out_b + h ----------------
__global__ __launch_bounds__(256)
void outproj_mfma_kernel(const short* __restrict__ op, const short* __restrict__ wop,
                         const float* __restrict__ obias, const float* __restrict__ h,
                         float* __restrict__ out){
  const int b = blockIdx.z;
  const int tid = threadIdx.x, wave = tid>>6, lane = tid&63;
  const int quad = lane>>4, lm = lane&15;
  const int M0 = blockIdx.y*128 + (wave>>1)*64;
  const int N0 = blockIdx.x*128 + (wave&1)*64;
  floatx4 acc[4][4];
  #pragma unroll
  for (int mt=0;mt<4;mt++)
    #pragma unroll
    for (int nt=0;nt<4;nt++) acc[mt][nt] = (floatx4){0.f,0.f,0.f,0.f};
  #pragma unroll
  for (int kk=0;kk<8;kk++){
    short8 af[4], bfr[4];
    #pragma unroll
    for (int mt=0;mt<4;mt++)
      af[mt] = *(const short8*)(wop + ((size_t)kk*256 + M0 + mt*16 + lm)*32 + quad*8);
    #pragma unroll
    for (int nt=0;nt<4;nt++)
      bfr[nt] = *(const short8*)(op + (((size_t)b*8 + kk)*NHW + N0 + nt*16 + lm)*32 + quad*8);
    #pragma unroll
    for (int mt=0;mt<4;mt++)
      #pragma unroll
      for (int nt=0;nt<4;nt++)
        acc[mt][nt] = __builtin_amdgcn_mfma_f32_16x16x32_bf16(af[mt], bfr[nt], acc[mt][nt], 0,0,0);
  }
  #pragma unroll
  for (int mt=0;mt<4;mt++){
    #pragma unroll
    for (int r=0;r<4;r++){
      int co = M0 + mt*16 + quad*4 + r;
      float bb = obias[co];
      size_t ob = ((size_t)b*NC + co)*NHW + N0;
      #pragma unroll
      for (int nt=0;nt<4;nt++){
        size_t oi = ob + nt*16 + lm;
        out[oi] = acc[mt][nt][r] + bb + h[oi];
      }
    }
  }
}

extern "C" void kernel_launch(void* const* d_in, const int* in_sizes, int n_in,
                              void* d_out, int out_size, void* d_ws, size_t ws_size,
                              hipStream_t stream){
  const float* x        = (const float*)d_in[0];
  const float* time_emb = (const float*)d_in[1];
  const float* c_in     = (const float*)d_in[2];
  const float* gn1_g    = (const float*)d_in[3];
  const float* gn1_b    = (const float*)d_in[4];
  const float* conv1_w  = (const float*)d_in[5];
  const float* conv1_b  = (const float*)d_in[6];
  const float* noise_w  = (const float*)d_in[7];
  const float* noise_b  = (const float*)d_in[8];
  const float* gn2_g    = (const float*)d_in[9];
  const float* gn2_b    = (const float*)d_in[10];
  const float* conv2_w  = (const float*)d_in[11];
  const float* conv2_b  = (const float*)d_in[12];
  const float* cfunc_w  = (const float*)d_in[13];
  const float* cfunc_b  = (const float*)d_in[14];
  const float* agn_g    = (const float*)d_in[15];
  const float* agn_b    = (const float*)d_in[16];
  const float* qkv_w    = (const float*)d_in[17];
  const float* out_w    = (const float*)d_in[18];
  const float* out_b    = (const float*)d_in[19];
  float* outp = (float*)d_out;

  // ---- workspace layout (~67 MB) ----
  float* ws = (float*)d_ws;
  float* buf_h = ws;                       // NP fp32
  float* buf_t = buf_h + NP;               // NP fp32 (early: cp bf16 alias; late: o_p bf16 alias)
  short* xpb   = (short*)(buf_t + NP);     // NP bf16
  short* qp    = xpb + NP;                 // NP bf16
  short* kp    = qp + NP;                  // NP bf16
  short* vp    = kp + NP;                  // NP bf16
  short* wp1   = vp + NP;                  // 589824
  short* wp2   = wp1 + 589824;             // 589824
  short* wqp   = wp2 + 589824;             // 196608
  short* wcp   = wqp + 196608;             // 65536
  short* wop   = wcp + 65536;              // 65536
  float* na    = (float*)(wop + 65536);    // NB*NC
  float* st    = na + NB*NC;               // 2048 floats
  float* st2   = st;
  float* st3   = st + 1024;
  short* cp    = (short*)buf_t;            // alias (dead after gemm_cfunc)
  short* op    = (short*)buf_t;            // alias (written by attn after cp dead)

  // ---- prep ----
  wprep3_kernel<<<512, 256, 0, stream>>>(conv1_w, conv2_w, wp1, wp2, st);
  wprep1_kernel<<<1280, 256, 0, stream>>>(qkv_w, cfunc_w, out_w, wqp, wcp, wop);
  cvtc_kernel<<<dim3(4,8,NB), 256, 0, stream>>>(c_in, cp);
  noise_kernel<<<NB, 256, 0, stream>>>(time_emb, noise_w, noise_b, na);
  // ---- ResnetBlock ----
  gn_t_kernel<true><<<NB*32, 256, 0, stream>>>(x, gn1_g, gn1_b, xpb);
  conv3_mfma_kernel<<<dim3(16, NB), 256, 0, stream>>>(xpb, wp1, conv1_b, na, nullptr, buf_h, st2);
  gn_post_kernel<true><<<NB*32, 256, 0, stream>>>(buf_h, st2, gn2_g, gn2_b, xpb);
  gemm_cfunc_kernel<<<dim3(8,2,NB), 256, 0, stream>>>(cp, wcp, cfunc_b, x, buf_h);
  conv3_mfma_kernel<<<dim3(16, NB), 256, 0, stream>>>(xpb, wp2, conv2_b, nullptr, buf_h, buf_h, st3);
  // ---- Attention ----
  gn_post_kernel<false><<<NB*32, 256, 0, stream>>>(buf_h, st3, agn_g, agn_b, xpb);
  gemm_qkv_kernel<<<dim3(8,6,NB), 256, 0, stream>>>(xpb, wqp, qp, kp, vp);
  attn_mfma_kernel<<<1024, 256, 0, stream>>>(qp, kp, vp, op);
  outproj_mfma_kernel<<<dim3(8,2,NB), 256, 0, stream>>>(op, wop, out_b, buf_h, outp);
}

// Round 10
// 373.495 us; speedup vs baseline: 5.0763x; 1.0053x over previous
//
#include <hip/hip_runtime.h>
#include <hip/hip_bf16.h>
#include <math.h>

typedef __hip_bfloat16 bf16;
typedef short short8 __attribute__((ext_vector_type(8)));
typedef float floatx4 __attribute__((ext_vector_type(4)));

#define NB 16
#define NC 256
#define NHW 1024
#define NNE 256
#define NP (NB*NC*NHW)

__device__ __forceinline__ unsigned short f2bu(float f){
  bf16 h = (bf16)f; return *(unsigned short*)&h;
}

// ---------------- GroupNorm two-pass (+Swish) -> packed bf16 x_p[b][cc][px][32] ----------------
template<bool SWISH>
__global__ void gn_t_kernel(const float* __restrict__ src, const float* __restrict__ gamma,
                            const float* __restrict__ beta, short* __restrict__ xp){
  int b = blockIdx.x >> 5, g = blockIdx.x & 31;
  const int GSZ = 8*NHW;
  size_t base = ((size_t)b*NC + g*8)*NHW;
  int tid = threadIdx.x;
  float s = 0.f, ss = 0.f;
  for (int i = tid; i < GSZ; i += 256){
    float v = src[base+i];
    s += v; ss += v*v;
  }
  __shared__ float rs[256], rq[256];
  rs[tid] = s; rq[tid] = ss;
  __syncthreads();
  for (int off=128; off>0; off>>=1){
    if (tid < off){ rs[tid]+=rs[tid+off]; rq[tid]+=rq[tid+off]; }
    __syncthreads();
  }
  float mean = rs[0] * (1.f/GSZ);
  float var  = rq[0] * (1.f/GSZ) - mean*mean;
  float inv  = rsqrtf(var + 1e-5f);
  float gm[8], bt[8];
  #pragma unroll
  for (int j=0;j<8;j++){ gm[j] = gamma[g*8+j]*inv; bt[j] = beta[g*8+j]; }
  short* dst = xp + (((size_t)b*8 + (g>>2))*NHW)*32 + (g&3)*8;
  for (int px = tid; px < NHW; px += 256){
    short8 pk;
    #pragma unroll
    for (int j=0;j<8;j++){
      float v = (src[base + j*NHW + px] - mean)*gm[j] + bt[j];
      if (SWISH) v = v / (1.f + __expf(-v));
      pk[j] = (short)f2bu(v);
    }
    *(short8*)(dst + (size_t)px*32) = pk;
  }
}

// ---------------- GroupNorm single-pass from precomputed stats ----------------
template<bool SWISH>
__global__ void gn_post_kernel(const float* __restrict__ src, const float* __restrict__ st,
                               const float* __restrict__ gamma, const float* __restrict__ beta,
                               short* __restrict__ xp){
  int b = blockIdx.x >> 5, g = blockIdx.x & 31;
  size_t base = ((size_t)b*NC + g*8)*NHW;
  int tid = threadIdx.x;
  float s  = st[(b*32+g)*2+0];
  float ss = st[(b*32+g)*2+1];
  float mean = s * (1.f/8192.f);
  float var  = ss * (1.f/8192.f) - mean*mean;
  float inv  = rsqrtf(var + 1e-5f);
  float gm[8], bt[8];
  #pragma unroll
  for (int j=0;j<8;j++){ gm[j] = gamma[g*8+j]*inv; bt[j] = beta[g*8+j]; }
  short* dst = xp + (((size_t)b*8 + (g>>2))*NHW)*32 + (g&3)*8;
  for (int px = tid; px < NHW; px += 256){
    short8 pk;
    #pragma unroll
    for (int j=0;j<8;j++){
      float v = (src[base + j*NHW + px] - mean)*gm[j] + bt[j];
      if (SWISH) v = v / (1.f + __expf(-v));
      pk[j] = (short)f2bu(v);
    }
    *(short8*)(dst + (size_t)px*32) = pk;
  }
}

// ---------------- conv3 weight prep + stats zero ----------------
__global__ void wprep3_kernel(const float* __restrict__ w1, const float* __restrict__ w2,
                              short* __restrict__ wp1, short* __restrict__ wp2,
                              float* __restrict__ st){
  int co = blockIdx.x & 255;
  const float* w = (blockIdx.x < 256) ? w1 : w2;
  short* wp = (blockIdx.x < 256) ? wp1 : wp2;
  int tid = threadIdx.x;
  if (blockIdx.x == 0){
    for (int i=tid;i<2048;i+=256) st[i] = 0.f;
  }
  __shared__ float tmp[2304];
  for (int i=tid;i<2304;i+=256) tmp[i] = w[(size_t)co*2304 + i];   // [ci][tap]
  __syncthreads();
  for (int j=tid;j<2304;j+=256){
    int tap = j>>8, ci = j&255;
    wp[(((size_t)tap*8 + (ci>>5))*NC + co)*32 + (ci&31)] = (short)f2bu(tmp[ci*9 + tap]);
  }
}

// ---------------- 1x1 weight prep: qkv(768) + cfunc(256) + outw(256) ----------------
__global__ void wprep1_kernel(const float* __restrict__ wq, const float* __restrict__ wc,
                              const float* __restrict__ wo,
                              short* __restrict__ wqp, short* __restrict__ wcp,
                              short* __restrict__ wop){
  int blk = blockIdx.x, tid = threadIdx.x;
  if (blk < 768){
    float v = wq[(size_t)blk*256 + tid];
    wqp[(((size_t)(tid>>5))*768 + blk)*32 + (tid&31)] = (short)f2bu(v);
  } else if (blk < 1024){
    int co = blk - 768;
    float v = wc[(size_t)co*256 + tid];
    wcp[(((size_t)(tid>>5))*256 + co)*32 + (tid&31)] = (short)f2bu(v);
  } else {
    int co = blk - 1024;
    float v = wo[(size_t)co*256 + tid];
    wop[(((size_t)(tid>>5))*256 + co)*32 + (tid&31)] = (short)f2bu(v);
  }
}

// ---------------- c_in fp32 [b][ci][hw] -> cp[b][cc][px][32] bf16 ----------------
__global__ void cvtc_kernel(const float* __restrict__ c_in, short* __restrict__ cp){
  int pxc = blockIdx.x, cc = blockIdx.y, b = blockIdx.z, tid = threadIdx.x;
  __shared__ float ld[32][257];
  size_t gbase = ((size_t)b*NC + cc*32)*NHW + pxc*256;
  for (int j=0;j<32;j++) ld[j][tid] = c_in[gbase + (size_t)j*NHW + tid];
  __syncthreads();
  short* dst = cp + (((size_t)b*8 + cc)*NHW + pxc*256)*32;
  for (int it=0;it<4;it++){
    int pxl = it*64 + (tid>>2), ckl = tid&3;
    short8 pk;
    #pragma unroll
    for (int e=0;e<8;e++) pk[e] = (short)f2bu(ld[ckl*8+e][pxl]);
    *(short8*)(dst + (size_t)pxl*32 + ckl*8) = pk;
  }
}

// ---------------- FeatureWiseAffine bias: na[b][c] ----------------
__global__ void noise_kernel(const float* __restrict__ emb, const float* __restrict__ w,
                             const float* __restrict__ bias, float* __restrict__ na){
  int b = blockIdx.x, c = threadIdx.x;
  __shared__ float e[NNE];
  e[c] = emb[b*NNE + c];
  __syncthreads();
  float acc = bias[c];
  for (int k=0;k<NNE;k++) acc += e[k]*w[c*NNE+k];
  na[b*NC + c] = acc;
}

// ---------------- MFMA conv3x3, distance-4 software pipeline ----------------
#define XSTR 264
__global__ __launch_bounds__(256,1)
void conv3_mfma_kernel(const short* __restrict__ xp, const short* __restrict__ wp,
                       const float* __restrict__ bias, const float* __restrict__ bias_bc,
                       const float* __restrict__ addf, float* __restrict__ out,
                       float* __restrict__ st){
  const int b = blockIdx.y, y0 = blockIdx.x*2;
  const int tid = threadIdx.x, wave = tid>>6, lane = tid&63;
  const int quad = lane>>4, lm = lane&15;
  __shared__ short Xs[4*34*XSTR];

  { // zero halo columns
    int r = tid>>6, side = (tid>>5)&1, ck = tid&31;
    short8 z = {0,0,0,0,0,0,0,0};
    *(short8*)&Xs[((r*34) + side*33)*XSTR + ck*8] = z;
  }
  for (int it=0; it<16; ++it){
    int idx = it*256 + tid;
    int r = idx>>10, rem = idx&1023;
    int cc = rem>>7, x = (rem>>2)&31, ckl = rem&3;
    int y = y0 - 1 + r;
    short8 v = {0,0,0,0,0,0,0,0};
    if ((unsigned)y < 32u)
      v = *(const short8*)(xp + (((size_t)b*8 + cc)*NHW + y*32 + x)*32 + ckl*8);
    *(short8*)&Xs[(r*34 + x + 1)*XSTR + (cc*4 + ckl)*8] = v;
  }
  __syncthreads();

  floatx4 acc[4][4];
  #pragma unroll
  for (int mt=0;mt<4;mt++)
    #pragma unroll
    for (int nt=0;nt<4;nt++) acc[mt][nt] = (floatx4){0.f,0.f,0.f,0.f};

  const int co_w = wave*64;
  const int aoff = (co_w + lm)*32 + quad*8;

  auto ldA = [&](int j, short8 a[4]){
    const short* p = wp + (size_t)j*NC*32 + aoff;
    #pragma unroll
    for (int mt=0;mt<4;mt++) a[mt] = *(const short8*)(p + mt*(16*32));
  };
  auto ldB = [&](int j, short8 bf[4]){
    int tap = j>>3, kk = j&7;
    int dy = (tap*11)>>5;
    int dxp = tap - dy*3;
    int base = (lm+dxp)*XSTR + quad*8 + kk*32 + dy*(34*XSTR);
    #pragma unroll
    for (int nt=0;nt<4;nt++)
      bf[nt] = *(const short8*)&Xs[base + (nt>>1)*(34*XSTR) + (nt&1)*(16*XSTR)];
  };

  short8 A[4][4], Bf[4][4];
  ldA(0,A[0]); ldB(0,Bf[0]);
  ldA(1,A[1]); ldB(1,Bf[1]);
  ldA(2,A[2]); ldB(2,Bf[2]);
  ldA(3,A[3]); ldB(3,Bf[3]);
  for (int it=0; it<72; it+=4){
    #pragma unroll
    for (int u=0;u<4;u++){
      #pragma unroll
      for (int mt=0;mt<4;mt++)
        #pragma unroll
        for (int nt=0;nt<4;nt++)
          acc[mt][nt] = __builtin_amdgcn_mfma_f32_16x16x32_bf16(A[u][mt], Bf[u][nt], acc[mt][nt], 0,0,0);
      int j = it + 4 + u; if (j > 71) j = 71;
      ldA(j, A[u]); ldB(j, Bf[u]);
    }
  }

  const int hw0 = blockIdx.x*64;
  float gs[4], gq[4];
  #pragma unroll
  for (int mt=0;mt<4;mt++){ gs[mt]=0.f; gq[mt]=0.f; }
  #pragma unroll
  for (int mt=0;mt<4;mt++){
    #pragma unroll
    for (int r=0;r<4;r++){
      int co = co_w + mt*16 + quad*4 + r;
      float bb = bias[co] + (bias_bc ? bias_bc[b*NC + co] : 0.f);
      size_t ob = ((size_t)b*NC + co)*NHW + hw0;
      #pragma unroll
      for (int nt=0;nt<4;nt++){
        size_t oi = ob + nt*16 + lm;
        float v = acc[mt][nt][r] + bb;
        if (addf) v += addf[oi];
        out[oi] = v;
        gs[mt] += v; gq[mt] += v*v;
      }
    }
  }
  #pragma unroll
  for (int mt=0;mt<4;mt++){
    float s = gs[mt], q = gq[mt];
    #pragma unroll
    for (int o=1;o<32;o<<=1){ s += __shfl_xor(s, o, 64); q += __shfl_xor(q, o, 64); }
    if ((lane&31) == 0){
      int g = (co_w>>3) + mt*2 + (quad>>1);
      atomicAdd(&st[(b*32+g)*2+0], s);
      atomicAdd(&st[(b*32+g)*2+1], q);
    }
  }
}

// ---------------- MFMA GEMM: cfunc(c) + bias + x -> fp32 [b][co][hw] ----------------
__global__ __launch_bounds__(256)
void gemm_cfunc_kernel(const short* __restrict__ cp, const short* __restrict__ wcp,
                       const float* __restrict__ bias, const float* __restrict__ xres,
                       float* __restrict__ out){
  const int b = blockIdx.z;
  const int tid = threadIdx.x, wave = tid>>6, lane = tid&63;
  const int quad = lane>>4, lm = lane&15;
  const int M0 = blockIdx.y*128 + (wave>>1)*64;
  const int N0 = blockIdx.x*128 + (wave&1)*64;
  floatx4 acc[4][4];
  #pragma unroll
  for (int mt=0;mt<4;mt++)
    #pragma unroll
    for (int nt=0;nt<4;nt++) acc[mt][nt] = (floatx4){0.f,0.f,0.f,0.f};
  #pragma unroll
  for (int kk=0;kk<8;kk++){
    short8 af[4], bfr[4];
    #pragma unroll
    for (int mt=0;mt<4;mt++)
      af[mt] = *(const short8*)(wcp + ((size_t)kk*256 + M0 + mt*16 + lm)*32 + quad*8);
    #pragma unroll
    for (int nt=0;nt<4;nt++)
      bfr[nt] = *(const short8*)(cp + (((size_t)b*8 + kk)*NHW + N0 + nt*16 + lm)*32 + quad*8);
    #pragma unroll
    for (int mt=0;mt<4;mt++)
      #pragma unroll
      for (int nt=0;nt<4;nt++)
        acc[mt][nt] = __builtin_amdgcn_mfma_f32_16x16x32_bf16(af[mt], bfr[nt], acc[mt][nt], 0,0,0);
  }
  #pragma unroll
  for (int mt=0;mt<4;mt++){
    #pragma unroll
    for (int r=0;r<4;r++){
      int co = M0 + mt*16 + quad*4 + r;
      float bb = bias[co];
      size_t ob = ((size_t)b*NC + co)*NHW + N0;
      #pragma unroll
      for (int nt=0;nt<4;nt++){
        size_t oi = ob + nt*16 + lm;
        out[oi] = acc[mt][nt][r] + bb + xres[oi];
      }
    }
  }
}

// ---------------- MFMA GEMM qkv ----------------
__global__ __launch_bounds__(256)
void gemm_qkv_kernel(const short* __restrict__ ntp, const short* __restrict__ wqp,
                     short* __restrict__ qp, short* __restrict__ kp, short* __restrict__ vp){
  const int b = blockIdx.z;
  const int tid = threadIdx.x, wave = tid>>6, lane = tid&63;
  const int quad = lane>>4, lm = lane&15;
  const int M0 = blockIdx.y*128 + (wave>>1)*64;
  const int N0 = blockIdx.x*128 + (wave&1)*64;
  floatx4 acc[4][4];
  #pragma unroll
  for (int mt=0;mt<4;mt++)
    #pragma unroll
    for (int nt=0;nt<4;nt++) acc[mt][nt] = (floatx4){0.f,0.f,0.f,0.f};
  #pragma unroll
  for (int kk=0;kk<8;kk++){
    short8 af[4], bfr[4];
    #pragma unroll
    for (int mt=0;mt<4;mt++)
      af[mt] = *(const short8*)(wqp + ((size_t)kk*768 + M0 + mt*16 + lm)*32 + quad*8);
    #pragma unroll
    for (int nt=0;nt<4;nt++)
      bfr[nt] = *(const short8*)(ntp + (((size_t)b*8 + kk)*NHW + N0 + nt*16 + lm)*32 + quad*8);
    #pragma unroll
    for (int mt=0;mt<4;mt++)
      #pragma unroll
      for (int nt=0;nt<4;nt++)
        acc[mt][nt] = __builtin_amdgcn_mfma_f32_16x16x32_bf16(af[mt], bfr[nt], acc[mt][nt], 0,0,0);
  }
  #pragma unroll
  for (int mt=0;mt<4;mt++){
    int co_base = M0 + mt*16 + quad*4;
    int sec = co_base >> 8;
    int c = co_base & 255;
    #pragma unroll
    for (int nt=0;nt<4;nt++){
      int s = N0 + nt*16 + lm;
      if (sec < 2){
        unsigned short t0 = f2bu(acc[mt][nt][0]), t1 = f2bu(acc[mt][nt][1]);
        unsigned short t2 = f2bu(acc[mt][nt][2]), t3 = f2bu(acc[mt][nt][3]);
        uint2 w2; w2.x = ((unsigned)t1<<16)|t0; w2.y = ((unsigned)t3<<16)|t2;
        short* dst = (sec==0) ? qp : kp;
        *(uint2*)(dst + (((size_t)b*8 + (c>>5))*NHW + s)*32 + (c&31)) = w2;
      } else {
        #pragma unroll
        for (int r=0;r<4;r++)
          vp[(((size_t)b*32 + (s>>5))*NC + c + r)*32 + (s&31)] = (short)f2bu(acc[mt][nt][r]);
      }
    }
  }
}

// ---------------- MFMA fused attention: 32 q-rows/block, 2 m-tiles per wave ----------------
__global__ __launch_bounds__(256)
void attn_mfma_kernel(const short* __restrict__ qp, const short* __restrict__ kp,
                      const short* __restrict__ vp, short* __restrict__ op){
  const int bx = blockIdx.x;
  const int b = bx & 15;               // XCD swizzle: batches {b,b+8} share an XCD's L2
  const int s0 = (bx >> 4) * 32;
  const int tid = threadIdx.x, wave = tid>>6, lane = tid&63;
  const int quad = lane>>4, lm = lane&15;
  __shared__ short P[32][1032];        // 66 KB
  __shared__ float redmax[32][4], redsum[32][4];

  // Q A-frags: 2 row-tiles x full K=256
  short8 aq[2][8];
  #pragma unroll
  for (int m=0;m<2;m++)
    #pragma unroll
    for (int kk=0;kk<8;kk++)
      aq[m][kk] = *(const short8*)(qp + (((size_t)b*8 + kk)*NHW + s0 + m*16 + lm)*32 + quad*8);

  floatx4 sc[2][16];
  #pragma unroll
  for (int m=0;m<2;m++)
    #pragma unroll
    for (int ti=0;ti<16;ti++) sc[m][ti] = (floatx4){0.f,0.f,0.f,0.f};

  // phase 1: 32 groups g = ti*2+h; each K-frag feeds 2 MFMAs (m-tiles)
  const int trow0 = wave*256 + lm;
  short8 kf[2][4];
  #pragma unroll
  for (int u=0;u<2;u++)
    #pragma unroll
    for (int j=0;j<4;j++)
      kf[u][j] = *(const short8*)(kp + (((size_t)b*8 + (u&1)*4 + j)*NHW + trow0 + (u>>1)*16)*32 + quad*8);
  #pragma unroll
  for (int g=0;g<32;g++){
    const int u = g&1, ti = g>>1, h = g&1;
    #pragma unroll
    for (int j=0;j<4;j++){
      sc[0][ti] = __builtin_amdgcn_mfma_f32_16x16x32_bf16(aq[0][h*4+j], kf[u][j], sc[0][ti], 0,0,0);
      sc[1][ti] = __builtin_amdgcn_mfma_f32_16x16x32_bf16(aq[1][h*4+j], kf[u][j], sc[1][ti], 0,0,0);
    }
    if (g < 30){
      const int gn = g+2, tin = gn>>1, hn = gn&1;
      #pragma unroll
      for (int j=0;j<4;j++)
        kf[u][j] = *(const short8*)(kp + (((size_t)b*8 + hn*4 + j)*NHW + trow0 + tin*16)*32 + quad*8);
    }
  }

  const float scale = 0.0625f;
  float mx[2][4];
  #pragma unroll
  for (int m=0;m<2;m++)
    #pragma unroll
    for (int r=0;r<4;r++) mx[m][r] = -1e30f;
  #pragma unroll
  for (int m=0;m<2;m++)
    #pragma unroll
    for (int ti=0;ti<16;ti++)
      #pragma unroll
      for (int r=0;r<4;r++){
        float v = sc[m][ti][r]*scale;
        sc[m][ti][r] = v;
        mx[m][r] = fmaxf(mx[m][r], v);
      }
  #pragma unroll
  for (int o=1;o<16;o<<=1)
    #pragma unroll
    for (int m=0;m<2;m++)
      #pragma unroll
      for (int r=0;r<4;r++) mx[m][r] = fmaxf(mx[m][r], __shfl_xor(mx[m][r], o, 64));
  if (lm==0){
    #pragma unroll
    for (int m=0;m<2;m++)
      #pragma unroll
      for (int r=0;r<4;r++) redmax[m*16 + quad*4 + r][wave] = mx[m][r];
  }
  __syncthreads();
  float fm[2][4];
  #pragma unroll
  for (int m=0;m<2;m++)
    #pragma unroll
    for (int r=0;r<4;r++){
      int row = m*16 + quad*4 + r;
      fm[m][r] = fmaxf(fmaxf(redmax[row][0],redmax[row][1]),
                       fmaxf(redmax[row][2],redmax[row][3]));
    }
  float sm[2][4];
  #pragma unroll
  for (int m=0;m<2;m++)
    #pragma unroll
    for (int r=0;r<4;r++) sm[m][r] = 0.f;
  #pragma unroll
  for (int m=0;m<2;m++)
    #pragma unroll
    for (int ti=0;ti<16;ti++)
      #pragma unroll
      for (int r=0;r<4;r++){
        float e = __expf(sc[m][ti][r] - fm[m][r]);
        sc[m][ti][r] = e;
        sm[m][r] += e;
      }
  #pragma unroll
  for (int o=1;o<16;o<<=1)
    #pragma unroll
    for (int m=0;m<2;m++)
      #pragma unroll
      for (int r=0;r<4;r++) sm[m][r] += __shfl_xor(sm[m][r], o, 64);
  if (lm==0){
    #pragma unroll
    for (int m=0;m<2;m++)
      #pragma unroll
      for (int r=0;r<4;r++) redsum[m*16 + quad*4 + r][wave] = sm[m][r];
  }
  __syncthreads();
  float inv[2][4];
  #pragma unroll
  for (int m=0;m<2;m++)
    #pragma unroll
    for (int r=0;r<4;r++){
      int row = m*16 + quad*4 + r;
      inv[m][r] = 1.f/(redsum[row][0]+redsum[row][1]+redsum[row][2]+redsum[row][3]);
    }
  #pragma unroll
  for (int m=0;m<2;m++)
    #pragma unroll
    for (int ti=0;ti<16;ti++)
      #pragma unroll
      for (int r=0;r<4;r++)
        P[m*16 + quad*4 + r][wave*256 + ti*16 + lm] = (short)f2bu(sc[m][ti][r]*inv[m][r]);
  __syncthreads();

  // phase 2: 32 steps; each (pf pair, 4 V-frags) feeds 8 MFMAs
  floatx4 oacc[2][4];
  #pragma unroll
  for (int m=0;m<2;m++)
    #pragma unroll
    for (int nt=0;nt<4;nt++) oacc[m][nt] = (floatx4){0.f,0.f,0.f,0.f};
  const int crow = wave*64 + lm;
  short8 vf[2][4], pf[2][2];
  #pragma unroll
  for (int u=0;u<2;u++){
    #pragma unroll
    for (int m=0;m<2;m++)
      pf[u][m] = *(const short8*)(&P[m*16 + lm][u*32 + quad*8]);
    #pragma unroll
    for (int nt=0;nt<4;nt++)
      vf[u][nt] = *(const short8*)(vp + (((size_t)b*32 + u)*NC + crow + nt*16)*32 + quad*8);
  }
  #pragma unroll
  for (int kk=0;kk<32;kk++){
    const int u = kk&1;
    #pragma unroll
    for (int nt=0;nt<4;nt++){
      oacc[0][nt] = __builtin_amdgcn_mfma_f32_16x16x32_bf16(pf[u][0], vf[u][nt], oacc[0][nt], 0,0,0);
      oacc[1][nt] = __builtin_amdgcn_mfma_f32_16x16x32_bf16(pf[u][1], vf[u][nt], oacc[1][nt], 0,0,0);
    }
    if (kk < 30){
      #pragma unroll
      for (int m=0;m<2;m++)
        pf[u][m] = *(const short8*)(&P[m*16 + lm][(kk+2)*32 + quad*8]);
      #pragma unroll
      for (int nt=0;nt<4;nt++)
        vf[u][nt] = *(const short8*)(vp + (((size_t)b*32 + kk+2)*NC + crow + nt*16)*32 + quad*8);
    }
  }
  // packed bf16 epilogue: o_p[b][cc][s][32]
  #pragma unroll
  for (int nt=0;nt<4;nt++){
    int c = wave*64 + nt*16 + lm;
    int cc = c>>5, cl = c&31;
    #pragma unroll
    for (int m=0;m<2;m++)
      #pragma unroll
      for (int r=0;r<4;r++){
        int s = s0 + m*16 + quad*4 + r;
        op[(((size_t)b*8 + cc)*NHW + s)*32 + cl] = (short)f2bu(oacc[m][nt][r]);
      }
  }
}

// ---------------- MFMA out-proj: out = W@o + out_b + h ----------------
__global__ __launch_bounds__(256)
void outproj_mfma_kernel(const short* __restrict__ op, const short* __restrict__ wop,
                         const float* __restrict__ obias, const float* __restrict__ h,
                         float* __restrict__ out){
  const int b = blockIdx.z;
  const int tid = threadIdx.x, wave = tid>>6, lane = tid&63;
  const int quad = lane>>4, lm = lane&15;
  const int M0 = blockIdx.y*128 + (wave>>1)*64;
  const int N0 = blockIdx.x*128 + (wave&1)*64;
  floatx4 acc[4][4];
  #pragma unroll
  for (int mt=0;mt<4;mt++)
    #pragma unroll
    for (int nt=0;nt<4;nt++) acc[mt][nt] = (floatx4){0.f,0.f,0.f,0.f};
  #pragma unroll
  for (int kk=0;kk<8;kk++){
    short8 af[4], bfr[4];
    #pragma unroll
    for (int mt=0;mt<4;mt++)
      af[mt] = *(const short8*)(wop + ((size_t)kk*256 + M0 + mt*16 + lm)*32 + quad*8);
    #pragma unroll
    for (int nt=0;nt<4;nt++)
      bfr[nt] = *(const short8*)(op + (((size_t)b*8 + kk)*NHW + N0 + nt*16 + lm)*32 + quad*8);
    #pragma unroll
    for (int mt=0;mt<4;mt++)
      #pragma unroll
      for (int nt=0;nt<4;nt++)
        acc[mt][nt] = __builtin_amdgcn_mfma_f32_16x16x32_bf16(af[mt], bfr[nt], acc[mt][nt], 0,0,0);
  }
  #pragma unroll
  for (int mt=0;mt<4;mt++){
    #pragma unroll
    for (int r=0;r<4;r++){
      int co = M0 + mt*16 + quad*4 + r;
      float bb = obias[co];
      size_t ob = ((size_t)b*NC + co)*NHW + N0;
      #pragma unroll
      for (int nt=0;nt<4;nt++){
        size_t oi = ob + nt*16 + lm;
        out[oi] = acc[mt][nt][r] + bb + h[oi];
      }
    }
  }
}

extern "C" void kernel_launch(void* const* d_in, const int* in_sizes, int n_in,
                              void* d_out, int out_size, void* d_ws, size_t ws_size,
                              hipStream_t stream){
  const float* x        = (const float*)d_in[0];
  const float* time_emb = (const float*)d_in[1];
  const float* c_in     = (const float*)d_in[2];
  const float* gn1_g    = (const float*)d_in[3];
  const float* gn1_b    = (const float*)d_in[4];
  const float* conv1_w  = (const float*)d_in[5];
  const float* conv1_b  = (const float*)d_in[6];
  const float* noise_w  = (const float*)d_in[7];
  const float* noise_b  = (const float*)d_in[8];
  const float* gn2_g    = (const float*)d_in[9];
  const float* gn2_b    = (const float*)d_in[10];
  const float* conv2_w  = (const float*)d_in[11];
  const float* conv2_b  = (const float*)d_in[12];
  const float* cfunc_w  = (const float*)d_in[13];
  const float* cfunc_b  = (const float*)d_in[14];
  const float* agn_g    = (const float*)d_in[15];
  const float* agn_b    = (const float*)d_in[16];
  const float* qkv_w    = (const float*)d_in[17];
  const float* out_w    = (const float*)d_in[18];
  const float* out_b    = (const float*)d_in[19];
  float* outp = (float*)d_out;

  // ---- workspace layout (~67 MB) ----
  float* ws = (float*)d_ws;
  float* buf_h = ws;                       // NP fp32
  float* buf_t = buf_h + NP;               // NP fp32 (early: cp bf16 alias; late: o_p bf16 alias)
  short* xpb   = (short*)(buf_t + NP);     // NP bf16
  short* qp    = xpb + NP;                 // NP bf16
  short* kp    = qp + NP;                  // NP bf16
  short* vp    = kp + NP;                  // NP bf16
  short* wp1   = vp + NP;                  // 589824
  short* wp2   = wp1 + 589824;             // 589824
  short* wqp   = wp2 + 589824;             // 196608
  short* wcp   = wqp + 196608;             // 65536
  short* wop   = wcp + 65536;              // 65536
  float* na    = (float*)(wop + 65536);    // NB*NC
  float* st    = na + NB*NC;               // 2048 floats
  float* st2   = st;
  float* st3   = st + 1024;
  short* cp    = (short*)buf_t;            // alias (dead after gemm_cfunc)
  short* op    = (short*)buf_t;            // alias (written by attn after cp dead)

  // ---- prep ----
  wprep3_kernel<<<512, 256, 0, stream>>>(conv1_w, conv2_w, wp1, wp2, st);
  wprep1_kernel<<<1280, 256, 0, stream>>>(qkv_w, cfunc_w, out_w, wqp, wcp, wop);
  cvtc_kernel<<<dim3(4,8,NB), 256, 0, stream>>>(c_in, cp);
  noise_kernel<<<NB, 256, 0, stream>>>(time_emb, noise_w, noise_b, na);
  // ---- ResnetBlock ----
  gn_t_kernel<true><<<NB*32, 256, 0, stream>>>(x, gn1_g, gn1_b, xpb);
  conv3_mfma_kernel<<<dim3(16, NB), 256, 0, stream>>>(xpb, wp1, conv1_b, na, nullptr, buf_h, st2);
  gn_post_kernel<true><<<NB*32, 256, 0, stream>>>(buf_h, st2, gn2_g, gn2_b, xpb);
  gemm_cfunc_kernel<<<dim3(8,2,NB), 256, 0, stream>>>(cp, wcp, cfunc_b, x, buf_h);
  conv3_mfma_kernel<<<dim3(16, NB), 256, 0, stream>>>(xpb, wp2, conv2_b, nullptr, buf_h, buf_h, st3);
  // ---- Attention ----
  gn_post_kernel<false><<<NB*32, 256, 0, stream>>>(buf_h, st3, agn_g, agn_b, xpb);
  gemm_qkv_kernel<<<dim3(8,6,NB), 256, 0, stream>>>(xpb, wqp, qp, kp, vp);
  attn_mfma_kernel<<<512, 256, 0, stream>>>(qp, kp, vp, op);
  outproj_mfma_kernel<<<dim3(8,2,NB), 256, 0, stream>>>(op, wop, out_b, buf_h, outp);
}